// Round 1
// baseline (1269.951 us; speedup 1.0000x reference)
//
#include <hip/hip_runtime.h>
#include <stdint.h>
#include <math.h>

#define DEVINL __device__ __forceinline__

constexpr int SEQ = 2048;
constexpr int DIM = 512;
constexpr int BATCH = 2;
constexpr int NHEAD = 8;
constexpr int HDIM = 64;
constexpr int NROWS = BATCH * SEQ;        // 4096
constexpr int NRAND = (SEQ * SEQ) / 2;    // 2097152 = 2^21
constexpr float NEG_MAX = -3.402823466e38f;   // jnp.finfo(f32).min
constexpr float F32_TINY = 1.1754943508222875e-38f;

// ---------------- threefry2x32 (JAX-compatible, 20 rounds) ----------------
__host__ __device__ inline void tf2x32(uint32_t k0, uint32_t k1,
                                       uint32_t x0, uint32_t x1,
                                       uint32_t* o0, uint32_t* o1) {
  uint32_t ks2 = k0 ^ k1 ^ 0x1BD11BDAu;
  x0 += k0; x1 += k1;
#define TFR(r) { x0 += x1; x1 = (x1 << (r)) | (x1 >> (32 - (r))); x1 ^= x0; }
  TFR(13) TFR(15) TFR(26) TFR(6)
  x0 += k1; x1 += ks2 + 1u;
  TFR(17) TFR(29) TFR(16) TFR(24)
  x0 += ks2; x1 += k0 + 2u;
  TFR(13) TFR(15) TFR(26) TFR(6)
  x0 += k0; x1 += k1 + 3u;
  TFR(17) TFR(29) TFR(16) TFR(24)
  x0 += k1; x1 += ks2 + 4u;
  TFR(13) TFR(15) TFR(26) TFR(6)
  x0 += ks2; x1 += k0 + 5u;
#undef TFR
  *o0 = x0; *o1 = x1;
}

// jax_threefry_partitionable=True (default since jax 0.4.36):
// bits32[i] = o0 ^ o1 of threefry(key, (hi32(i)=0, lo32(i)=i))
DEVINL uint32_t jax_bits32(uint32_t k0, uint32_t k1, uint32_t idx) {
  uint32_t a, b;
  tf2x32(k0, k1, 0u, idx, &a, &b);
  return a ^ b;
}

// ---------------- block reductions ----------------
DEVINL float blockReduceSum(float v) {
  __shared__ float sh[16];
  __syncthreads();
  int lane = threadIdx.x & 63, wid = threadIdx.x >> 6;
  #pragma unroll
  for (int o = 32; o > 0; o >>= 1) v += __shfl_down(v, o);
  if (lane == 0) sh[wid] = v;
  __syncthreads();
  if (threadIdx.x == 0) {
    int nw = ((int)blockDim.x + 63) >> 6;
    float s = 0.f;
    for (int i = 0; i < nw; i++) s += sh[i];
    sh[0] = s;
  }
  __syncthreads();
  return sh[0];
}

DEVINL float blockReduceMin(float v) {
  __shared__ float sh[16];
  __syncthreads();
  int lane = threadIdx.x & 63, wid = threadIdx.x >> 6;
  #pragma unroll
  for (int o = 32; o > 0; o >>= 1) v = fminf(v, __shfl_down(v, o));
  if (lane == 0) sh[wid] = v;
  __syncthreads();
  if (threadIdx.x == 0) {
    int nw = ((int)blockDim.x + 63) >> 6;
    float s = sh[0];
    for (int i = 1; i < nw; i++) s = fminf(s, sh[i]);
    sh[0] = s;
  }
  __syncthreads();
  return sh[0];
}

DEVINL float blockReduceMax(float v) {
  __shared__ float sh[16];
  __syncthreads();
  int lane = threadIdx.x & 63, wid = threadIdx.x >> 6;
  #pragma unroll
  for (int o = 32; o > 0; o >>= 1) v = fmaxf(v, __shfl_down(v, o));
  if (lane == 0) sh[wid] = v;
  __syncthreads();
  if (threadIdx.x == 0) {
    int nw = ((int)blockDim.x + 63) >> 6;
    float s = sh[0];
    for (int i = 1; i < nw; i++) s = fmaxf(s, sh[i]);
    sh[0] = s;
  }
  __syncthreads();
  return sh[0];
}

// ---------------- kernels ----------------

__global__ void init_kernel(uint8_t* colm, int* cnt, int* haskp) {
  int tid = blockIdx.x * blockDim.x + threadIdx.x;
  if (tid < BATCH * SEQ) colm[tid] = 0;
  if (tid < BATCH) { cnt[tid] = 0; haskp[tid] = 0; }
}

// one block per row of 512
__global__ __launch_bounds__(256) void ln_kernel(const float* __restrict__ x,
    const float* __restrict__ g, const float* __restrict__ bb,
    float* __restrict__ out) {
  int row = blockIdx.x;
  const float* xr = x + (size_t)row * DIM;
  int t = threadIdx.x;
  float v0 = xr[t], v1 = xr[t + 256];
  float mu = blockReduceSum(v0 + v1) * (1.0f / 512.0f);
  float d0 = v0 - mu, d1 = v1 - mu;
  float var = blockReduceSum(d0 * d0 + d1 * d1) * (1.0f / 512.0f);
  float inv = 1.0f / sqrtf(var + 1e-5f);
  out[(size_t)row * DIM + t]       = d0 * inv * g[t] + bb[t];
  out[(size_t)row * DIM + t + 256] = d1 * inv * g[t + 256] + bb[t + 256];
}

// C[M][N] = A[M][512] @ W[N][512]^T + bias (+relu / +resid)
__global__ __launch_bounds__(256) void gemm_kernel(
    const float* __restrict__ A, const float* __restrict__ W,
    const float* __restrict__ bias, const float* __restrict__ resid,
    float* __restrict__ C, int N, int relu) {
  __shared__ float As[16][65];
  __shared__ float Ws[16][65];
  int bm = blockIdx.y * 64, bn = blockIdx.x * 64;
  int tid = threadIdx.x;
  int tx = tid & 15, ty = tid >> 4;
  int lm = tid >> 4, lk = tid & 15;
  float acc[4][4] = {{0.f}};
  for (int kk = 0; kk < DIM; kk += 16) {
    #pragma unroll
    for (int i = 0; i < 4; i++) {
      As[lk][lm + i * 16] = A[(size_t)(bm + lm + i * 16) * DIM + kk + lk];
      Ws[lk][lm + i * 16] = W[(size_t)(bn + lm + i * 16) * DIM + kk + lk];
    }
    __syncthreads();
    #pragma unroll
    for (int k = 0; k < 16; k++) {
      float a[4], w[4];
      #pragma unroll
      for (int i = 0; i < 4; i++) a[i] = As[k][ty * 4 + i];
      #pragma unroll
      for (int j = 0; j < 4; j++) w[j] = Ws[k][tx * 4 + j];
      #pragma unroll
      for (int i = 0; i < 4; i++)
        #pragma unroll
        for (int j = 0; j < 4; j++)
          acc[i][j] += a[i] * w[j];
    }
    __syncthreads();
  }
  #pragma unroll
  for (int i = 0; i < 4; i++) {
    int m = bm + ty * 4 + i;
    #pragma unroll
    for (int j = 0; j < 4; j++) {
      int n = bn + tx * 4 + j;
      float v = acc[i][j] + bias[n];
      if (relu) v = fmaxf(v, 0.f);
      if (resid) v += resid[(size_t)m * N + n];
      C[(size_t)m * N + n] = v;
    }
  }
}

// adaptive window: win = clip(rint(64*(0.5+sigmoid(hidden·Ww2 + bw2))), 1, 128)
__global__ void win_kernel(const float* __restrict__ hidden,
                           const float* __restrict__ Ww2,
                           const float* __restrict__ bw2,
                           int* __restrict__ win) {
  int row = blockIdx.x;
  float v = hidden[(size_t)row * 128 + threadIdx.x] * Ww2[threadIdx.x];
  v = blockReduceSum(v);
  if (threadIdx.x == 0) {
    float y = v + bw2[0];
    float sig = 1.0f / (1.0f + expf(-y));
    float adj = 0.5f + sig;
    int w = (int)rintf(64.0f * adj);
    w = w < 1 ? 1 : (w > 128 ? 128 : w);
    win[row] = w;
  }
}

// per (b,t): dm, mag (L2), ch (s=1 mean|diff|), rowvar (ddof=1)
__global__ __launch_bounds__(256) void dmstats_kernel(const float* __restrict__ qn,
    float* __restrict__ dm, float* __restrict__ mag,
    float* __restrict__ ch, float* __restrict__ rowvar) {
  int t = blockIdx.x, b = blockIdx.y;
  const float* x = qn + ((size_t)b * SEQ + t) * DIM;
  int tid = threadIdx.x;
  float sx = 0, sq = 0, sdm = 0, sch = 0;
  float xs[2];
  #pragma unroll
  for (int i = 0; i < 2; i++) {
    int d = tid + i * 256;
    float xv = x[d]; xs[i] = xv;
    sx += xv; sq += xv * xv;
    float acc = 0.f;
    if (t + 1 < SEQ) { float df = fabsf(x[1 * DIM + d] - xv); acc += 0.4f * (df / 1.0f); sch += df; }
    if (t + 2 < SEQ) { float df = fabsf(x[2 * DIM + d] - xv); acc += 0.3f * (df / 2.0f); }
    if (t + 3 < SEQ) { float df = fabsf(x[3 * DIM + d] - xv); acc += 0.2f * (df / 3.0f); }
    if (t + 5 < SEQ) { float df = fabsf(x[5 * DIM + d] - xv); acc += 0.1f * (df / 5.0f); }
    sdm += acc;
  }
  float mu = blockReduceSum(sx) * (1.0f / 512.0f);
  float sv = 0;
  #pragma unroll
  for (int i = 0; i < 2; i++) { float dd = xs[i] - mu; sv += dd * dd; }
  float totsq = blockReduceSum(sq);
  float totdm = blockReduceSum(sdm);
  float totch = blockReduceSum(sch);
  float totsv = blockReduceSum(sv);
  if (tid == 0) {
    size_t idx = (size_t)b * SEQ + t;
    dm[idx] = totdm / 512.0f;
    mag[idx] = sqrtf(totsq);
    ch[idx] = (t + 1 < SEQ) ? (totch / 512.0f) : 0.f;
    rowvar[idx] = totsv / 511.0f;
  }
}

// per batch: thr = mean(dm)+0.5*std(dm,ddof=1); comp = mean(rowvar); impn normalized
__global__ void batchstats_kernel(const float* __restrict__ dm,
    const float* __restrict__ mag, const float* __restrict__ ch,
    const float* __restrict__ rowvar, float* __restrict__ impn,
    float* __restrict__ thr, float* __restrict__ comp) {
  int b = blockIdx.x;
  int tid = threadIdx.x;
  float sdm = 0, srv = 0, lo = INFINITY, hi = -INFINITY;
  for (int t = tid; t < SEQ; t += 256) {
    size_t idx = (size_t)b * SEQ + t;
    sdm += dm[idx];
    srv += rowvar[idx];
    float imp = 0.5f * mag[idx] + 0.5f * ch[idx];
    lo = fminf(lo, imp); hi = fmaxf(hi, imp);
  }
  float meandm = blockReduceSum(sdm) * (1.0f / 2048.0f);
  float compv = blockReduceSum(srv) * (1.0f / 2048.0f);
  lo = blockReduceMin(lo);
  hi = blockReduceMax(hi);
  float sv = 0;
  for (int t = tid; t < SEQ; t += 256) {
    float d2 = dm[(size_t)b * SEQ + t] - meandm;
    sv += d2 * d2;
  }
  float var = blockReduceSum(sv) / 2047.0f;
  for (int t = tid; t < SEQ; t += 256) {
    size_t idx = (size_t)b * SEQ + t;
    float imp = 0.5f * mag[idx] + 0.5f * ch[idx];
    impn[idx] = (imp - lo) / (hi - lo + 1e-6f);
  }
  if (tid == 0) { thr[b] = meandm + 0.5f * sqrtf(var); comp[b] = compv; }
}

__global__ void kp_kernel(const float* __restrict__ dm, const float* __restrict__ thr,
                          uint8_t* __restrict__ kp, int* __restrict__ haskp) {
  int t = blockIdx.x * blockDim.x + threadIdx.x;
  int b = blockIdx.y;
  if (t >= SEQ) return;
  const float* dmb = dm + (size_t)b * SEQ;
  float v = dmb[t];
  float tb = thr[b];
  float prev = (t > 0) ? dmb[t - 1] : -1.0f;
  float next = (t < SEQ - 1) ? dmb[t + 1] : -1.0f;
  bool k = (v > tb) && (v > prev) && (v > next);
  if (t == 0 || t == SEQ - 1) k = k || (v > tb);
  kp[(size_t)b * SEQ + t] = k ? 1 : 0;
  if (k) haskp[b] = 1;
}

// one block per (b,layer) row of 512; Gumbel top-4 -> column flags
__global__ void topk_kernel(const float* __restrict__ impn, uint8_t* __restrict__ colm,
                            uint32_t kg0, uint32_t kg1) {
  int rowid = blockIdx.x;               // 0..7 = b*4+layer
  int b = rowid >> 2, layer = rowid & 3;
  int j = threadIdx.x;                  // 512
  float pv = impn[(size_t)b * SEQ + layer * 512 + j];
  float ssum = blockReduceSum(pv);
  uint32_t bits = jax_bits32(kg0, kg1, (uint32_t)(rowid * 512 + j));
  float f = __uint_as_float((bits >> 9) | 0x3F800000u) - 1.0f;
  float u = fmaxf(F32_TINY, f + F32_TINY);
  float g = -logf(-logf(u));
  float score = logf(pv / (ssum + 1e-6f) + 1e-20f) + g;
  __shared__ float sc[512];
  sc[j] = score;
  __syncthreads();
  if (j == 0) {
    for (int pick = 0; pick < 4; pick++) {
      float bv = sc[0]; int bi = 0;
      for (int q = 1; q < 512; q++) if (sc[q] > bv) { bv = sc[q]; bi = q; }
      colm[(size_t)b * SEQ + layer * 512 + bi] = 1;
      sc[bi] = -INFINITY;
    }
  }
}

DEVINL bool fbcol(int k) {
  return k == 0 || k == 511 || k == 1023 || k == 1535 || k == 2047;
}

__global__ __launch_bounds__(256) void maskbuild_kernel(
    const int* __restrict__ win, const uint8_t* __restrict__ kp,
    const uint8_t* __restrict__ colm, const int* __restrict__ haskp,
    uint8_t* __restrict__ mask, int* __restrict__ cnt) {
  int q = blockIdx.x, b = blockIdx.y;
  int w = win[(size_t)b * SEQ + q];
  int hk = haskp[b];
  bool rowk = hk ? (kp[(size_t)b * SEQ + q] != 0) : fbcol(q);
  uint8_t* mrow = mask + ((size_t)b * SEQ + q) * SEQ;
  const uint8_t* kpb = kp + (size_t)b * SEQ;
  const uint8_t* cob = colm + (size_t)b * SEQ;
  int local = 0;
  #pragma unroll
  for (int i = 0; i < 8; i++) {
    int k = i * 256 + (int)threadIdx.x;
    bool colk = hk ? (kpb[k] != 0) : fbcol(k);
    bool mm = ((k >= q - w) && (k <= q + w)) || rowk || colk || (cob[k] != 0);
    mrow[k] = mm ? 1 : 0;
    local += mm ? 1 : 0;
  }
  float tot = blockReduceSum((float)local);
  if (threadIdx.x == 0) atomicAdd(&cnt[b], (int)tot);
}

__global__ void needed_kernel(const float* __restrict__ comp,
                              const int* __restrict__ cnt, int* __restrict__ needed) {
  if (threadIdx.x == 0 && blockIdx.x == 0) {
    float c0 = comp[0], c1 = comp[1];
    float cmin = fminf(c0, c1), cmax = fmaxf(c0, c1);
    for (int b = 0; b < BATCH; b++) {
      float nc = (comp[b] - cmin) / (cmax - cmin + 1e-6f);
      float ratio = fminf(fmaxf(0.3f * (0.5f + nc), 0.1f), 0.5f);
      float dens = (float)cnt[b] / 4194304.0f;
      float nd = ceilf((ratio - dens) * 4194304.0f);
      int n = (int)nd;
      needed[b] = n > 0 ? n : 0;
    }
  }
}

// adaptive random fill: qr/kr = lower 32-bit draws of randint(key, (2,NRAND), 0, 2048)
__global__ void fill_kernel(uint8_t* __restrict__ mask, const int* __restrict__ needed,
                            uint32_t kq0, uint32_t kq1, uint32_t kk0, uint32_t kk1) {
  int gid = blockIdx.x * blockDim.x + threadIdx.x;   // = b*NRAND + r
  int b = gid >> 21;
  int r = gid & (NRAND - 1);
  if (b >= BATCH) return;
  if (r >= needed[b]) return;
  uint32_t flat = 4194304u + (uint32_t)gid;          // lower-bits half offset
  uint32_t q = jax_bits32(kq0, kq1, flat) & 2047u;
  uint32_t k = jax_bits32(kk0, kk1, flat) & 2047u;
  mask[((size_t)b * SEQ + q) * SEQ + k] = 1;
}

// flash-style masked attention; mask==1 -> score = -FLT_MAX (allowed = ~sparse)
__global__ __launch_bounds__(256) void attn_kernel(
    const float* __restrict__ Qm, const float* __restrict__ Km,
    const float* __restrict__ Vm, const uint8_t* __restrict__ mask,
    float* __restrict__ out) {
  int qt = blockIdx.x, h = blockIdx.y, b = blockIdx.z;
  __shared__ float Qs[32][65], Ks[32][65], Vs[32][65], Ps[32][33];
  int tid = threadIdx.x;
  int row = tid >> 3;
  int cg = (tid & 7) * 4;
  int dg = (tid & 7) * 8;
  for (int idx = tid; idx < 32 * 64; idx += 256) {
    int r = idx >> 6, d = idx & 63;
    Qs[r][d] = Qm[((size_t)b * SEQ + qt * 32 + r) * DIM + h * HDIM + d];
  }
  float m_i = -INFINITY, l_i = 0.f;
  float acc[8];
  #pragma unroll
  for (int i = 0; i < 8; i++) acc[i] = 0.f;
  const uint8_t* mrow = mask + ((size_t)b * SEQ + qt * 32 + row) * SEQ;
  for (int kc = 0; kc < SEQ / 32; kc++) {
    __syncthreads();
    for (int idx = tid; idx < 32 * 64; idx += 256) {
      int r = idx >> 6, d = idx & 63;
      Ks[r][d] = Km[((size_t)b * SEQ + kc * 32 + r) * DIM + h * HDIM + d];
      Vs[r][d] = Vm[((size_t)b * SEQ + kc * 32 + r) * DIM + h * HDIM + d];
    }
    __syncthreads();
    float s0 = 0, s1 = 0, s2 = 0, s3 = 0;
    for (int d = 0; d < 64; d++) {
      float qv = Qs[row][d];
      s0 += qv * Ks[cg + 0][d];
      s1 += qv * Ks[cg + 1][d];
      s2 += qv * Ks[cg + 2][d];
      s3 += qv * Ks[cg + 3][d];
    }
    uint32_t mw = *(const uint32_t*)(mrow + kc * 32 + cg);
    s0 *= 0.125f; s1 *= 0.125f; s2 *= 0.125f; s3 *= 0.125f;
    if (mw & 0x000000ffu) s0 = NEG_MAX;
    if (mw & 0x0000ff00u) s1 = NEG_MAX;
    if (mw & 0x00ff0000u) s2 = NEG_MAX;
    if (mw & 0xff000000u) s3 = NEG_MAX;
    float mx = fmaxf(fmaxf(s0, s1), fmaxf(s2, s3));
    #pragma unroll
    for (int o = 4; o > 0; o >>= 1) mx = fmaxf(mx, __shfl_xor(mx, o));
    float m_new = fmaxf(m_i, mx);
    float p0 = expf(s0 - m_new), p1 = expf(s1 - m_new);
    float p2 = expf(s2 - m_new), p3 = expf(s3 - m_new);
    float ls = p0 + p1 + p2 + p3;
    #pragma unroll
    for (int o = 4; o > 0; o >>= 1) ls += __shfl_xor(ls, o);
    float alpha = expf(m_i - m_new);
    l_i = l_i * alpha + ls;
    m_i = m_new;
    Ps[row][cg + 0] = p0; Ps[row][cg + 1] = p1;
    Ps[row][cg + 2] = p2; Ps[row][cg + 3] = p3;
    #pragma unroll
    for (int i = 0; i < 8; i++) acc[i] *= alpha;
    __syncthreads();
    for (int c = 0; c < 32; c++) {
      float pvv = Ps[row][c];
      #pragma unroll
      for (int i = 0; i < 8; i++) acc[i] += pvv * Vs[c][dg + i];
    }
  }
  float inv = 1.0f / l_i;
  #pragma unroll
  for (int i = 0; i < 8; i++)
    out[((size_t)b * SEQ + qt * 32 + row) * DIM + h * HDIM + dg + i] = acc[i] * inv;
}

// ---------------- launcher ----------------
extern "C" void kernel_launch(void* const* d_in, const int* in_sizes, int n_in,
                              void* d_out, int out_size, void* d_ws, size_t ws_size,
                              hipStream_t stream) {
  (void)in_sizes; (void)n_in; (void)out_size; (void)ws_size;
  const float* queries = (const float*)d_in[0];
  const float* keys    = (const float*)d_in[1];
  const float* values  = (const float*)d_in[2];
  const float* ln_q_g  = (const float*)d_in[3];
  const float* ln_q_b  = (const float*)d_in[4];
  const float* ln_k_g  = (const float*)d_in[5];
  const float* ln_k_b  = (const float*)d_in[6];
  const float* ln_v_g  = (const float*)d_in[7];
  const float* ln_v_b  = (const float*)d_in[8];
  const float* Wq = (const float*)d_in[9];  const float* bq = (const float*)d_in[10];
  const float* Wk = (const float*)d_in[11]; const float* bk = (const float*)d_in[12];
  const float* Wv = (const float*)d_in[13]; const float* bv = (const float*)d_in[14];
  const float* Wo = (const float*)d_in[15]; const float* bo = (const float*)d_in[16];
  const float* Ww1 = (const float*)d_in[17]; const float* bw1 = (const float*)d_in[18];
  const float* Ww2 = (const float*)d_in[19]; const float* bw2 = (const float*)d_in[20];

  char* ws = (char*)d_ws;
  const size_t big = (size_t)NROWS * DIM * sizeof(float);  // 8 MiB
  float* qn = (float*)(ws + 0 * big);
  float* kn = (float*)(ws + 1 * big);
  float* vn = (float*)(ws + 2 * big);
  float* Qm = (float*)(ws + 3 * big);
  float* Km = (float*)(ws + 4 * big);
  float* Vm = (float*)(ws + 5 * big);
  float* hidden  = (float*)(ws + 2 * big);    // aliases vn (dead after V proj)
  uint8_t* mask  = (uint8_t*)(ws + 2 * big);  // aliases vn+hidden (dead by then)
  float* attnout = (float*)(ws + 1 * big);    // aliases kn (dead after K proj)
  char* st = ws + 6 * big;
  float* dm     = (float*)st; st += NROWS * 4;
  float* mag    = (float*)st; st += NROWS * 4;
  float* ch     = (float*)st; st += NROWS * 4;
  float* rowvar = (float*)st; st += NROWS * 4;
  float* impn   = (float*)st; st += NROWS * 4;
  int*   win    = (int*)st;   st += NROWS * 4;
  uint8_t* kp   = (uint8_t*)st; st += NROWS;
  uint8_t* colm = (uint8_t*)st; st += NROWS;
  float* thr    = (float*)st; st += 2 * 4;
  float* comp   = (float*)st; st += 2 * 4;
  int* cnt      = (int*)st;   st += 2 * 4;
  int* haskp    = (int*)st;   st += 2 * 4;
  int* needed   = (int*)st;   st += 2 * 4;

  // JAX fold_in keys (host-side integer math; graph-capture safe)
  uint32_t kg0, kg1, kq0, kq1, kk0, kk1;
  tf2x32(0u, 42u, 0u, 0u, &kg0, &kg1);   // gumbel key
  tf2x32(0u, 42u, 0u, 1u, &kq0, &kq1);   // qr key
  tf2x32(0u, 42u, 0u, 2u, &kk0, &kk1);   // kr key

  init_kernel<<<16, 256, 0, stream>>>(colm, cnt, haskp);
  ln_kernel<<<NROWS, 256, 0, stream>>>(queries, ln_q_g, ln_q_b, qn);
  ln_kernel<<<NROWS, 256, 0, stream>>>(keys,    ln_k_g, ln_k_b, kn);
  ln_kernel<<<NROWS, 256, 0, stream>>>(values,  ln_v_g, ln_v_b, vn);

  dim3 g512(512 / 64, NROWS / 64);
  gemm_kernel<<<g512, 256, 0, stream>>>(qn, Wq, bq, nullptr, Qm, 512, 0);
  gemm_kernel<<<g512, 256, 0, stream>>>(kn, Wk, bk, nullptr, Km, 512, 0);
  gemm_kernel<<<g512, 256, 0, stream>>>(vn, Wv, bv, nullptr, Vm, 512, 0);

  dim3 g128(128 / 64, NROWS / 64);
  gemm_kernel<<<g128, 256, 0, stream>>>(qn, Ww1, bw1, nullptr, hidden, 128, 1);
  win_kernel<<<NROWS, 128, 0, stream>>>(hidden, Ww2, bw2, win);

  dim3 gdm(SEQ, BATCH);
  dmstats_kernel<<<gdm, 256, 0, stream>>>(qn, dm, mag, ch, rowvar);
  batchstats_kernel<<<BATCH, 256, 0, stream>>>(dm, mag, ch, rowvar, impn, thr, comp);
  dim3 gkp(SEQ / 256, BATCH);
  kp_kernel<<<gkp, 256, 0, stream>>>(dm, thr, kp, haskp);
  topk_kernel<<<8, 512, 0, stream>>>(impn, colm, kg0, kg1);

  dim3 gmb(SEQ, BATCH);
  maskbuild_kernel<<<gmb, 256, 0, stream>>>(win, kp, colm, haskp, mask, cnt);
  needed_kernel<<<1, 64, 0, stream>>>(comp, cnt, needed);
  fill_kernel<<<(2 * NRAND) / 256, 256, 0, stream>>>(mask, needed, kq0, kq1, kk0, kk1);

  dim3 gat(SEQ / 32, NHEAD, BATCH);
  attn_kernel<<<gat, 256, 0, stream>>>(Qm, Km, Vm, mask, attnout);

  gemm_kernel<<<g512, 256, 0, stream>>>(attnout, Wo, bo, queries, (float*)d_out, 512, 0);
}

// Round 2
// 511.193 us; speedup vs baseline: 2.4843x; 2.4843x over previous
//
#include <hip/hip_runtime.h>
#include <stdint.h>
#include <math.h>

#define DEVINL __device__ __forceinline__

constexpr int SEQ = 2048;
constexpr int DIM = 512;
constexpr int BATCH = 2;
constexpr int NHEAD = 8;
constexpr int HDIM = 64;
constexpr int NROWS = BATCH * SEQ;        // 4096
constexpr int NRAND = (SEQ * SEQ) / 2;    // 2097152 = 2^21
constexpr float NEG_MAX = -3.402823466e38f;   // jnp.finfo(f32).min
constexpr float F32_TINY = 1.1754943508222875e-38f;

typedef float float4v __attribute__((ext_vector_type(4)));
typedef short short8 __attribute__((ext_vector_type(8)));

DEVINL float4v MFMA(short8 a, short8 b, float4v c) {
  return __builtin_amdgcn_mfma_f32_16x16x32_bf16(a, b, c, 0, 0, 0);
}

// ---------------- bf16 helpers (RNE) ----------------
DEVINL ushort f2bf(float x) {
  uint32_t u = __float_as_uint(x);
  return (ushort)((u + 0x7FFFu + ((u >> 16) & 1u)) >> 16);
}
DEVINL float bf2f(ushort h) { return __uint_as_float(((uint32_t)h) << 16); }

// ---------------- threefry2x32 (JAX-compatible, 20 rounds) ----------------
__host__ __device__ inline void tf2x32(uint32_t k0, uint32_t k1,
                                       uint32_t x0, uint32_t x1,
                                       uint32_t* o0, uint32_t* o1) {
  uint32_t ks2 = k0 ^ k1 ^ 0x1BD11BDAu;
  x0 += k0; x1 += k1;
#define TFR(r) { x0 += x1; x1 = (x1 << (r)) | (x1 >> (32 - (r))); x1 ^= x0; }
  TFR(13) TFR(15) TFR(26) TFR(6)
  x0 += k1; x1 += ks2 + 1u;
  TFR(17) TFR(29) TFR(16) TFR(24)
  x0 += ks2; x1 += k0 + 2u;
  TFR(13) TFR(15) TFR(26) TFR(6)
  x0 += k0; x1 += k1 + 3u;
  TFR(17) TFR(29) TFR(16) TFR(24)
  x0 += k1; x1 += ks2 + 4u;
  TFR(13) TFR(15) TFR(26) TFR(6)
  x0 += ks2; x1 += k0 + 5u;
#undef TFR
  *o0 = x0; *o1 = x1;
}

DEVINL uint32_t jax_bits32(uint32_t k0, uint32_t k1, uint32_t idx) {
  uint32_t a, b;
  tf2x32(k0, k1, 0u, idx, &a, &b);
  return a ^ b;
}

// ---------------- block reductions ----------------
DEVINL float blockReduceSum(float v) {
  __shared__ float sh[16];
  __syncthreads();
  int lane = threadIdx.x & 63, wid = threadIdx.x >> 6;
  #pragma unroll
  for (int o = 32; o > 0; o >>= 1) v += __shfl_down(v, o);
  if (lane == 0) sh[wid] = v;
  __syncthreads();
  if (threadIdx.x == 0) {
    int nw = ((int)blockDim.x + 63) >> 6;
    float s = 0.f;
    for (int i = 0; i < nw; i++) s += sh[i];
    sh[0] = s;
  }
  __syncthreads();
  return sh[0];
}

DEVINL float blockReduceMin(float v) {
  __shared__ float sh[16];
  __syncthreads();
  int lane = threadIdx.x & 63, wid = threadIdx.x >> 6;
  #pragma unroll
  for (int o = 32; o > 0; o >>= 1) v = fminf(v, __shfl_down(v, o));
  if (lane == 0) sh[wid] = v;
  __syncthreads();
  if (threadIdx.x == 0) {
    int nw = ((int)blockDim.x + 63) >> 6;
    float s = sh[0];
    for (int i = 1; i < nw; i++) s = fminf(s, sh[i]);
    sh[0] = s;
  }
  __syncthreads();
  return sh[0];
}

DEVINL float blockReduceMax(float v) {
  __shared__ float sh[16];
  __syncthreads();
  int lane = threadIdx.x & 63, wid = threadIdx.x >> 6;
  #pragma unroll
  for (int o = 32; o > 0; o >>= 1) v = fmaxf(v, __shfl_down(v, o));
  if (lane == 0) sh[wid] = v;
  __syncthreads();
  if (threadIdx.x == 0) {
    int nw = ((int)blockDim.x + 63) >> 6;
    float s = sh[0];
    for (int i = 1; i < nw; i++) s = fmaxf(s, sh[i]);
    sh[0] = s;
  }
  __syncthreads();
  return sh[0];
}

// ---------------- small kernels (UNCHANGED mask pipeline — bit-exact) ----------------

__global__ void init_kernel(uint8_t* colm, int* cnt, int* haskp) {
  int tid = blockIdx.x * blockDim.x + threadIdx.x;
  if (tid < BATCH * SEQ) colm[tid] = 0;
  if (tid < BATCH) { cnt[tid] = 0; haskp[tid] = 0; }
}

__global__ __launch_bounds__(256) void ln_kernel(const float* __restrict__ x,
    const float* __restrict__ g, const float* __restrict__ bb,
    float* __restrict__ out) {
  int row = blockIdx.x;
  const float* xr = x + (size_t)row * DIM;
  int t = threadIdx.x;
  float v0 = xr[t], v1 = xr[t + 256];
  float mu = blockReduceSum(v0 + v1) * (1.0f / 512.0f);
  float d0 = v0 - mu, d1 = v1 - mu;
  float var = blockReduceSum(d0 * d0 + d1 * d1) * (1.0f / 512.0f);
  float inv = 1.0f / sqrtf(var + 1e-5f);
  out[(size_t)row * DIM + t]       = d0 * inv * g[t] + bb[t];
  out[(size_t)row * DIM + t + 256] = d1 * inv * g[t + 256] + bb[t + 256];
}

// f32 tiled GEMM — kept ONLY for the mask-critical hidden projection (N=128, relu)
__global__ __launch_bounds__(256) void gemm_kernel(
    const float* __restrict__ A, const float* __restrict__ W,
    const float* __restrict__ bias, const float* __restrict__ resid,
    float* __restrict__ C, int N, int relu) {
  __shared__ float As[16][65];
  __shared__ float Ws[16][65];
  int bm = blockIdx.y * 64, bn = blockIdx.x * 64;
  int tid = threadIdx.x;
  int tx = tid & 15, ty = tid >> 4;
  int lm = tid >> 4, lk = tid & 15;
  float acc[4][4] = {{0.f}};
  for (int kk = 0; kk < DIM; kk += 16) {
    #pragma unroll
    for (int i = 0; i < 4; i++) {
      As[lk][lm + i * 16] = A[(size_t)(bm + lm + i * 16) * DIM + kk + lk];
      Ws[lk][lm + i * 16] = W[(size_t)(bn + lm + i * 16) * DIM + kk + lk];
    }
    __syncthreads();
    #pragma unroll
    for (int k = 0; k < 16; k++) {
      float a[4], w[4];
      #pragma unroll
      for (int i = 0; i < 4; i++) a[i] = As[k][ty * 4 + i];
      #pragma unroll
      for (int j = 0; j < 4; j++) w[j] = Ws[k][tx * 4 + j];
      #pragma unroll
      for (int i = 0; i < 4; i++)
        #pragma unroll
        for (int j = 0; j < 4; j++)
          acc[i][j] += a[i] * w[j];
    }
    __syncthreads();
  }
  #pragma unroll
  for (int i = 0; i < 4; i++) {
    int m = bm + ty * 4 + i;
    #pragma unroll
    for (int j = 0; j < 4; j++) {
      int n = bn + tx * 4 + j;
      float v = acc[i][j] + bias[n];
      if (relu) v = fmaxf(v, 0.f);
      if (resid) v += resid[(size_t)m * N + n];
      C[(size_t)m * N + n] = v;
    }
  }
}

__global__ void win_kernel(const float* __restrict__ hidden,
                           const float* __restrict__ Ww2,
                           const float* __restrict__ bw2,
                           int* __restrict__ win) {
  int row = blockIdx.x;
  float v = hidden[(size_t)row * 128 + threadIdx.x] * Ww2[threadIdx.x];
  v = blockReduceSum(v);
  if (threadIdx.x == 0) {
    float y = v + bw2[0];
    float sig = 1.0f / (1.0f + expf(-y));
    float adj = 0.5f + sig;
    int w = (int)rintf(64.0f * adj);
    w = w < 1 ? 1 : (w > 128 ? 128 : w);
    win[row] = w;
  }
}

__global__ __launch_bounds__(256) void dmstats_kernel(const float* __restrict__ qn,
    float* __restrict__ dm, float* __restrict__ mag,
    float* __restrict__ ch, float* __restrict__ rowvar) {
  int t = blockIdx.x, b = blockIdx.y;
  const float* x = qn + ((size_t)b * SEQ + t) * DIM;
  int tid = threadIdx.x;
  float sx = 0, sq = 0, sdm = 0, sch = 0;
  float xs[2];
  #pragma unroll
  for (int i = 0; i < 2; i++) {
    int d = tid + i * 256;
    float xv = x[d]; xs[i] = xv;
    sx += xv; sq += xv * xv;
    float acc = 0.f;
    if (t + 1 < SEQ) { float df = fabsf(x[1 * DIM + d] - xv); acc += 0.4f * (df / 1.0f); sch += df; }
    if (t + 2 < SEQ) { float df = fabsf(x[2 * DIM + d] - xv); acc += 0.3f * (df / 2.0f); }
    if (t + 3 < SEQ) { float df = fabsf(x[3 * DIM + d] - xv); acc += 0.2f * (df / 3.0f); }
    if (t + 5 < SEQ) { float df = fabsf(x[5 * DIM + d] - xv); acc += 0.1f * (df / 5.0f); }
    sdm += acc;
  }
  float mu = blockReduceSum(sx) * (1.0f / 512.0f);
  float sv = 0;
  #pragma unroll
  for (int i = 0; i < 2; i++) { float dd = xs[i] - mu; sv += dd * dd; }
  float totsq = blockReduceSum(sq);
  float totdm = blockReduceSum(sdm);
  float totch = blockReduceSum(sch);
  float totsv = blockReduceSum(sv);
  if (tid == 0) {
    size_t idx = (size_t)b * SEQ + t;
    dm[idx] = totdm / 512.0f;
    mag[idx] = sqrtf(totsq);
    ch[idx] = (t + 1 < SEQ) ? (totch / 512.0f) : 0.f;
    rowvar[idx] = totsv / 511.0f;
  }
}

__global__ void batchstats_kernel(const float* __restrict__ dm,
    const float* __restrict__ mag, const float* __restrict__ ch,
    const float* __restrict__ rowvar, float* __restrict__ impn,
    float* __restrict__ thr, float* __restrict__ comp) {
  int b = blockIdx.x;
  int tid = threadIdx.x;
  float sdm = 0, srv = 0, lo = INFINITY, hi = -INFINITY;
  for (int t = tid; t < SEQ; t += 256) {
    size_t idx = (size_t)b * SEQ + t;
    sdm += dm[idx];
    srv += rowvar[idx];
    float imp = 0.5f * mag[idx] + 0.5f * ch[idx];
    lo = fminf(lo, imp); hi = fmaxf(hi, imp);
  }
  float meandm = blockReduceSum(sdm) * (1.0f / 2048.0f);
  float compv = blockReduceSum(srv) * (1.0f / 2048.0f);
  lo = blockReduceMin(lo);
  hi = blockReduceMax(hi);
  float sv = 0;
  for (int t = tid; t < SEQ; t += 256) {
    float d2 = dm[(size_t)b * SEQ + t] - meandm;
    sv += d2 * d2;
  }
  float var = blockReduceSum(sv) / 2047.0f;
  for (int t = tid; t < SEQ; t += 256) {
    size_t idx = (size_t)b * SEQ + t;
    float imp = 0.5f * mag[idx] + 0.5f * ch[idx];
    impn[idx] = (imp - lo) / (hi - lo + 1e-6f);
  }
  if (tid == 0) { thr[b] = meandm + 0.5f * sqrtf(var); comp[b] = compv; }
}

__global__ void kp_kernel(const float* __restrict__ dm, const float* __restrict__ thr,
                          uint8_t* __restrict__ kp, int* __restrict__ haskp) {
  int t = blockIdx.x * blockDim.x + threadIdx.x;
  int b = blockIdx.y;
  if (t >= SEQ) return;
  const float* dmb = dm + (size_t)b * SEQ;
  float v = dmb[t];
  float tb = thr[b];
  float prev = (t > 0) ? dmb[t - 1] : -1.0f;
  float next = (t < SEQ - 1) ? dmb[t + 1] : -1.0f;
  bool k = (v > tb) && (v > prev) && (v > next);
  if (t == 0 || t == SEQ - 1) k = k || (v > tb);
  kp[(size_t)b * SEQ + t] = k ? 1 : 0;
  if (k) haskp[b] = 1;
}

__global__ void topk_kernel(const float* __restrict__ impn, uint8_t* __restrict__ colm,
                            uint32_t kg0, uint32_t kg1) {
  int rowid = blockIdx.x;
  int b = rowid >> 2, layer = rowid & 3;
  int j = threadIdx.x;
  float pv = impn[(size_t)b * SEQ + layer * 512 + j];
  float ssum = blockReduceSum(pv);
  uint32_t bits = jax_bits32(kg0, kg1, (uint32_t)(rowid * 512 + j));
  float f = __uint_as_float((bits >> 9) | 0x3F800000u) - 1.0f;
  float u = fmaxf(F32_TINY, f + F32_TINY);
  float g = -logf(-logf(u));
  float score = logf(pv / (ssum + 1e-6f) + 1e-20f) + g;
  __shared__ float sc[512];
  sc[j] = score;
  __syncthreads();
  if (j == 0) {
    for (int pick = 0; pick < 4; pick++) {
      float bv = sc[0]; int bi = 0;
      for (int q = 1; q < 512; q++) if (sc[q] > bv) { bv = sc[q]; bi = q; }
      colm[(size_t)b * SEQ + layer * 512 + bi] = 1;
      sc[bi] = -INFINITY;
    }
  }
}

DEVINL bool fbcol(int k) {
  return k == 0 || k == 511 || k == 1023 || k == 1535 || k == 2047;
}

__global__ __launch_bounds__(256) void maskbuild_kernel(
    const int* __restrict__ win, const uint8_t* __restrict__ kp,
    const uint8_t* __restrict__ colm, const int* __restrict__ haskp,
    uint8_t* __restrict__ mask, int* __restrict__ cnt) {
  int q = blockIdx.x, b = blockIdx.y;
  int w = win[(size_t)b * SEQ + q];
  int hk = haskp[b];
  bool rowk = hk ? (kp[(size_t)b * SEQ + q] != 0) : fbcol(q);
  uint8_t* mrow = mask + ((size_t)b * SEQ + q) * SEQ;
  const uint8_t* kpb = kp + (size_t)b * SEQ;
  const uint8_t* cob = colm + (size_t)b * SEQ;
  int local = 0;
  #pragma unroll
  for (int i = 0; i < 8; i++) {
    int k = i * 256 + (int)threadIdx.x;
    bool colk = hk ? (kpb[k] != 0) : fbcol(k);
    bool mm = ((k >= q - w) && (k <= q + w)) || rowk || colk || (cob[k] != 0);
    mrow[k] = mm ? 1 : 0;
    local += mm ? 1 : 0;
  }
  float tot = blockReduceSum((float)local);
  if (threadIdx.x == 0) atomicAdd(&cnt[b], (int)tot);
}

__global__ void needed_kernel(const float* __restrict__ comp,
                              const int* __restrict__ cnt, int* __restrict__ needed) {
  if (threadIdx.x == 0 && blockIdx.x == 0) {
    float c0 = comp[0], c1 = comp[1];
    float cmin = fminf(c0, c1), cmax = fmaxf(c0, c1);
    for (int b = 0; b < BATCH; b++) {
      float nc = (comp[b] - cmin) / (cmax - cmin + 1e-6f);
      float ratio = fminf(fmaxf(0.3f * (0.5f + nc), 0.1f), 0.5f);
      float dens = (float)cnt[b] / 4194304.0f;
      float nd = ceilf((ratio - dens) * 4194304.0f);
      int n = (int)nd;
      needed[b] = n > 0 ? n : 0;
    }
  }
}

__global__ void fill_kernel(uint8_t* __restrict__ mask, const int* __restrict__ needed,
                            uint32_t kq0, uint32_t kq1, uint32_t kk0, uint32_t kk1) {
  int gid = blockIdx.x * blockDim.x + threadIdx.x;
  int b = gid >> 21;
  int r = gid & (NRAND - 1);
  if (b >= BATCH) return;
  if (r >= needed[b]) return;
  uint32_t flat = 4194304u + (uint32_t)gid;
  uint32_t q = jax_bits32(kq0, kq1, flat) & 2047u;
  uint32_t k = jax_bits32(kk0, kk1, flat) & 2047u;
  mask[((size_t)b * SEQ + q) * SEQ + k] = 1;
}

// ---------------- split-bf16 MFMA GEMM ----------------
// C[M][512] = A[M][512] @ W[512][512]^T + bias (+resid), fp32 in/out.
// hi/lo split: x*y ~= xh*yh + xh*yl + xl*yh  (error ~2^-16 relative).
// LDS tiles in fragment-linear layout: 16B block per (row-tile, k-chunk, row%16).

DEVINL void stage_split(const float* __restrict__ g, ushort* hi, ushort* lo, int blk) {
  float4 v0 = ((const float4*)g)[0];
  float4 v1 = ((const float4*)g)[1];
  float xv[8] = {v0.x, v0.y, v0.z, v0.w, v1.x, v1.y, v1.z, v1.w};
  short8 hv, lv;
  #pragma unroll
  for (int j = 0; j < 8; j++) {
    ushort hh = f2bf(xv[j]);
    hv[j] = (short)hh;
    lv[j] = (short)f2bf(xv[j] - bf2f(hh));
  }
  ((short8*)hi)[blk] = hv;
  ((short8*)lo)[blk] = lv;
}

DEVINL void mfma_gemm_body(const float* __restrict__ A, const float* __restrict__ W,
                           const float* __restrict__ bias, const float* __restrict__ resid,
                           float* __restrict__ C) {
  __shared__ __align__(16) ushort Ahi[4096], Alo[4096], Whi[4096], Wlo[4096];
  int tid = threadIdx.x;
  int wave = tid >> 6, lane = tid & 63;
  int mm = lane & 15, qr = lane >> 4;
  int wm = (wave >> 1) * 64, wn = (wave & 1) * 64;
  int bm = blockIdx.y * 128, bn = blockIdx.x * 128;
  float4v acc[4][4] = {};
  int sr = tid >> 2, sc8 = tid & 3;
  for (int kk = 0; kk < 512; kk += 32) {
    __syncthreads();
    #pragma unroll
    for (int half = 0; half < 2; half++) {
      int rr = sr + half * 64;
      int blk = ((rr >> 4) * 4 + sc8) * 16 + (rr & 15);
      stage_split(A + (size_t)(bm + rr) * 512 + kk + sc8 * 8, Ahi, Alo, blk);
      stage_split(W + (size_t)(bn + rr) * 512 + kk + sc8 * 8, Whi, Wlo, blk);
    }
    __syncthreads();
    short8 ah[4], al[4], bh[4], bl[4];
    #pragma unroll
    for (int mt = 0; mt < 4; mt++) {
      int blk = (((wm >> 4) + mt) * 4 + qr) * 16 + mm;
      ah[mt] = ((short8*)Ahi)[blk];
      al[mt] = ((short8*)Alo)[blk];
    }
    #pragma unroll
    for (int nt = 0; nt < 4; nt++) {
      int blk = (((wn >> 4) + nt) * 4 + qr) * 16 + mm;
      bh[nt] = ((short8*)Whi)[blk];
      bl[nt] = ((short8*)Wlo)[blk];
    }
    #pragma unroll
    for (int mt = 0; mt < 4; mt++)
      #pragma unroll
      for (int nt = 0; nt < 4; nt++) {
        acc[mt][nt] = MFMA(al[mt], bh[nt], acc[mt][nt]);
        acc[mt][nt] = MFMA(ah[mt], bl[nt], acc[mt][nt]);
        acc[mt][nt] = MFMA(ah[mt], bh[nt], acc[mt][nt]);
      }
  }
  #pragma unroll
  for (int mt = 0; mt < 4; mt++)
    #pragma unroll
    for (int nt = 0; nt < 4; nt++) {
      int n = bn + wn + nt * 16 + mm;
      float bsv = bias[n];
      #pragma unroll
      for (int reg = 0; reg < 4; reg++) {
        int m = bm + wm + mt * 16 + qr * 4 + reg;
        float v = acc[mt][nt][reg] + bsv;
        if (resid) v += resid[(size_t)m * 512 + n];
        C[(size_t)m * 512 + n] = v;
      }
    }
}

// fused Q/K/V projections (z selects operand set)
__global__ __launch_bounds__(256) void mfma_gemm3(
    const float* A0, const float* W0, const float* b0, float* C0,
    const float* A1, const float* W1, const float* b1, float* C1,
    const float* A2, const float* W2, const float* b2, float* C2) {
  const float* A; const float* W; const float* bias; float* C;
  if (blockIdx.z == 0)      { A = A0; W = W0; bias = b0; C = C0; }
  else if (blockIdx.z == 1) { A = A1; W = W1; bias = b1; C = C1; }
  else                      { A = A2; W = W2; bias = b2; C = C2; }
  mfma_gemm_body(A, W, bias, nullptr, C);
}

__global__ __launch_bounds__(256) void mfma_gemm_resid(
    const float* A, const float* W, const float* bias,
    const float* resid, float* C) {
  mfma_gemm_body(A, W, bias, resid, C);
}

// ---------------- MFMA flash attention ----------------
// 64 q-rows per block (wave w -> rows w*16..w*16+15), 64-key tiles, 32 iters.
// QK^T in split-bf16 (3 MFMA terms), PV in single bf16. Mask via __ballot bit-rows.
__global__ __launch_bounds__(256) void attn_mfma(
    const float* __restrict__ Qb, const float* __restrict__ Kb,
    const float* __restrict__ Vb, const uint8_t* __restrict__ mask,
    float* __restrict__ out) {
  int qt = blockIdx.x, h = blockIdx.y, b = blockIdx.z;
  __shared__ __align__(16) ushort Khi[4096], Klo[4096], Vs[4096];
  __shared__ __align__(16) ushort Ps[4][1024];
  int tid = threadIdx.x, wave = tid >> 6, lane = tid & 63;
  int mm = lane & 15, qr = lane >> 4;
  int q0 = qt * 64;

  // persistent Q fragments (hi/lo x 2 d-chunks of 32)
  short8 aqh[2], aql[2];
  {
    const float* qp = Qb + ((size_t)(b * SEQ + q0 + wave * 16 + mm)) * 512 + h * 64 + qr * 8;
    #pragma unroll
    for (int dc = 0; dc < 2; dc++) {
      float4 v0 = ((const float4*)(qp + dc * 32))[0];
      float4 v1 = ((const float4*)(qp + dc * 32))[1];
      float xv[8] = {v0.x, v0.y, v0.z, v0.w, v1.x, v1.y, v1.z, v1.w};
      #pragma unroll
      for (int j = 0; j < 8; j++) {
        ushort hh = f2bf(xv[j]);
        aqh[dc][j] = (short)hh;
        aql[dc][j] = (short)f2bf(xv[j] - bf2f(hh));
      }
    }
  }
  float4v accO[4] = {};
  float m_i[4], l_i[4];
  #pragma unroll
  for (int r = 0; r < 4; r++) { m_i[r] = -INFINITY; l_i[r] = 0.f; }
  const uint8_t* mbase = mask + ((size_t)b * SEQ + q0 + wave * 16) * SEQ;

  for (int kc = 0; kc < 32; kc++) {
    __syncthreads();
    // --- stage K tile (hi/lo split), frag-linear ---
    {
      int r = tid >> 2;
      const float* gk = Kb + ((size_t)(b * SEQ + kc * 64 + r)) * 512 + h * 64;
      #pragma unroll
      for (int half = 0; half < 2; half++) {
        int c8 = (tid & 3) + half * 4;
        int blk = (((r >> 4) * 2 + (c8 >> 2)) * 4 + (c8 & 3)) * 16 + (r & 15);
        stage_split(gk + c8 * 8, Khi, Klo, blk);
      }
    }
    // --- stage V tile transposed (single bf16), frag-linear ---
    {
      int d = tid & 63, kg = tid >> 6;
      const float* gv = Vb + ((size_t)(b * SEQ + kc * 64 + kg * 16)) * 512 + h * 64 + d;
      #pragma unroll
      for (int h2 = 0; h2 < 2; h2++) {
        short8 v8;
        #pragma unroll
        for (int j = 0; j < 8; j++) v8[j] = (short)f2bf(gv[(size_t)(h2 * 8 + j) * 512]);
        int kc2 = kg >> 1, qv = (kg * 2 + h2) & 3, dt = d >> 4, n = d & 15;
        ((short8*)Vs)[((kc2 * 4 + dt) * 4 + qv) * 16 + n] = v8;
      }
    }
    // --- mask bit-rows via ballot (wave-private; lanes = key cols) ---
    uint64_t mrow[4];
    {
      const uint8_t* mrp = mbase + kc * 64 + lane;
      #pragma unroll
      for (int rr = 0; rr < 16; rr++) {
        uint8_t mv = mrp[(size_t)rr * SEQ];
        uint64_t bm = __ballot(mv != 0);
        if ((rr >> 2) == qr) mrow[rr & 3] = bm;
      }
    }
    __syncthreads();
    // --- QK^T (split bf16) ---
    float4v S[4];
    #pragma unroll
    for (int ct = 0; ct < 4; ct++) {
      float4v s = {};
      #pragma unroll
      for (int dc = 0; dc < 2; dc++) {
        short8 bhf = ((short8*)Khi)[((ct * 2 + dc) * 4 + qr) * 16 + mm];
        short8 blf = ((short8*)Klo)[((ct * 2 + dc) * 4 + qr) * 16 + mm];
        s = MFMA(aql[dc], bhf, s);
        s = MFMA(aqh[dc], blf, s);
        s = MFMA(aqh[dc], bhf, s);
      }
      S[ct] = s;
    }
    // --- scale + mask + online softmax (rows = qr*4+reg, cols = ct*16+mm) ---
    float4v Pv[4];
    #pragma unroll
    for (int reg = 0; reg < 4; reg++) {
      float sv[4];
      float mx = -INFINITY;
      #pragma unroll
      for (int ct = 0; ct < 4; ct++) {
        float s = S[ct][reg] * 0.125f;
        if ((mrow[reg] >> (ct * 16 + mm)) & 1ull) s = NEG_MAX;
        sv[ct] = s;
        mx = fmaxf(mx, s);
      }
      #pragma unroll
      for (int o = 1; o < 16; o <<= 1) mx = fmaxf(mx, __shfl_xor(mx, o));
      float mn = fmaxf(m_i[reg], mx);
      float ps = 0.f;
      #pragma unroll
      for (int ct = 0; ct < 4; ct++) {
        float p = __expf(sv[ct] - mn);
        Pv[ct][reg] = p;
        ps += p;
      }
      #pragma unroll
      for (int o = 1; o < 16; o <<= 1) ps += __shfl_xor(ps, o);
      float alpha = __expf(m_i[reg] - mn);
      l_i[reg] = l_i[reg] * alpha + ps;
      m_i[reg] = mn;
      #pragma unroll
      for (int dt = 0; dt < 4; dt++) accO[dt][reg] *= alpha;
    }
    // --- write P to wave-private LDS (bf16, XOR-swizzled blocks) ---
    ushort* pw = &Ps[wave][0];
    #pragma unroll
    for (int ct = 0; ct < 4; ct++) {
      int kc2 = ct >> 1;
      int qf = (2 * ct + (mm >> 3)) & 3;
      int j = mm & 7;
      #pragma unroll
      for (int reg = 0; reg < 4; reg++) {
        int blk = kc2 * 64 + qf * 16 + (qr * 4 + reg);
        blk ^= (blk >> 3) & 3;
        pw[blk * 8 + j] = f2bf(Pv[ct][reg]);
      }
    }
    // --- PV (single bf16) ---
    #pragma unroll
    for (int kc2 = 0; kc2 < 2; kc2++) {
      int blk = kc2 * 64 + qr * 16 + mm;
      blk ^= (blk >> 3) & 3;
      short8 ap = *(const short8*)(pw + blk * 8);
      #pragma unroll
      for (int dt = 0; dt < 4; dt++) {
        short8 bv = ((short8*)Vs)[((kc2 * 4 + dt) * 4 + qr) * 16 + mm];
        accO[dt] = MFMA(ap, bv, accO[dt]);
      }
    }
  }
  // --- epilogue ---
  float inv[4];
  #pragma unroll
  for (int reg = 0; reg < 4; reg++) inv[reg] = 1.0f / l_i[reg];
  #pragma unroll
  for (int dt = 0; dt < 4; dt++)
    #pragma unroll
    for (int reg = 0; reg < 4; reg++) {
      size_t row = (size_t)b * SEQ + q0 + wave * 16 + qr * 4 + reg;
      out[row * 512 + h * 64 + dt * 16 + mm] = accO[dt][reg] * inv[reg];
    }
}

// ---------------- launcher ----------------
extern "C" void kernel_launch(void* const* d_in, const int* in_sizes, int n_in,
                              void* d_out, int out_size, void* d_ws, size_t ws_size,
                              hipStream_t stream) {
  (void)in_sizes; (void)n_in; (void)out_size; (void)ws_size;
  const float* queries = (const float*)d_in[0];
  const float* keys    = (const float*)d_in[1];
  const float* values  = (const float*)d_in[2];
  const float* ln_q_g  = (const float*)d_in[3];
  const float* ln_q_b  = (const float*)d_in[4];
  const float* ln_k_g  = (const float*)d_in[5];
  const float* ln_k_b  = (const float*)d_in[6];
  const float* ln_v_g  = (const float*)d_in[7];
  const float* ln_v_b  = (const float*)d_in[8];
  const float* Wq = (const float*)d_in[9];  const float* bq = (const float*)d_in[10];
  const float* Wk = (const float*)d_in[11]; const float* bk = (const float*)d_in[12];
  const float* Wv = (const float*)d_in[13]; const float* bv = (const float*)d_in[14];
  const float* Wo = (const float*)d_in[15]; const float* bo = (const float*)d_in[16];
  const float* Ww1 = (const float*)d_in[17]; const float* bw1 = (const float*)d_in[18];
  const float* Ww2 = (const float*)d_in[19]; const float* bw2 = (const float*)d_in[20];

  char* ws = (char*)d_ws;
  const size_t big = (size_t)NROWS * DIM * sizeof(float);  // 8 MiB
  float* qn = (float*)(ws + 0 * big);
  float* kn = (float*)(ws + 1 * big);   // mask aliases after K-proj
  float* vn = (float*)(ws + 2 * big);   // attnout aliases after V-proj
  float* Qb = (float*)(ws + 3 * big);   // hidden aliases before Q-proj
  float* Kb = (float*)(ws + 4 * big);
  float* Vb = (float*)(ws + 5 * big);
  uint8_t* mask  = (uint8_t*)kn;        // 2*2048*2048 = exactly 8 MiB
  float* attnout = vn;
  float* hidden  = Qb;                  // 4096*128 f32 = 2 MiB (dead before Q-proj)
  char* st = ws + 6 * big;
  float* dm     = (float*)st; st += NROWS * 4;
  float* mag    = (float*)st; st += NROWS * 4;
  float* ch     = (float*)st; st += NROWS * 4;
  float* rowvar = (float*)st; st += NROWS * 4;
  float* impn   = (float*)st; st += NROWS * 4;
  int*   win    = (int*)st;   st += NROWS * 4;
  uint8_t* kp   = (uint8_t*)st; st += NROWS;
  uint8_t* colm = (uint8_t*)st; st += NROWS;
  float* thr    = (float*)st; st += 2 * 4;
  float* comp   = (float*)st; st += 2 * 4;
  int* cnt      = (int*)st;   st += 2 * 4;
  int* haskp    = (int*)st;   st += 2 * 4;
  int* needed   = (int*)st;   st += 2 * 4;

  uint32_t kg0, kg1, kq0, kq1, kk0, kk1;
  tf2x32(0u, 42u, 0u, 0u, &kg0, &kg1);
  tf2x32(0u, 42u, 0u, 1u, &kq0, &kq1);
  tf2x32(0u, 42u, 0u, 2u, &kk0, &kk1);

  init_kernel<<<16, 256, 0, stream>>>(colm, cnt, haskp);
  ln_kernel<<<NROWS, 256, 0, stream>>>(queries, ln_q_g, ln_q_b, qn);
  ln_kernel<<<NROWS, 256, 0, stream>>>(keys,    ln_k_g, ln_k_b, kn);
  ln_kernel<<<NROWS, 256, 0, stream>>>(values,  ln_v_g, ln_v_b, vn);

  // mask-critical path: exact f32, unchanged from passing version
  dim3 g128(128 / 64, NROWS / 64);
  gemm_kernel<<<g128, 256, 0, stream>>>(qn, Ww1, bw1, nullptr, hidden, 128, 1);
  win_kernel<<<NROWS, 128, 0, stream>>>(hidden, Ww2, bw2, win);

  dim3 gdm(SEQ, BATCH);
  dmstats_kernel<<<gdm, 256, 0, stream>>>(qn, dm, mag, ch, rowvar);
  batchstats_kernel<<<BATCH, 256, 0, stream>>>(dm, mag, ch, rowvar, impn, thr, comp);
  dim3 gkp(SEQ / 256, BATCH);
  kp_kernel<<<gkp, 256, 0, stream>>>(dm, thr, kp, haskp);
  topk_kernel<<<8, 512, 0, stream>>>(impn, colm, kg0, kg1);

  // Q/K/V projections: split-bf16 MFMA (hidden already consumed)
  dim3 gqkv(4, 32, 3);
  mfma_gemm3<<<gqkv, 256, 0, stream>>>(qn, Wq, bq, Qb,
                                       kn, Wk, bk, Kb,
                                       vn, Wv, bv, Vb);

  dim3 gmb(SEQ, BATCH);
  maskbuild_kernel<<<gmb, 256, 0, stream>>>(win, kp, colm, haskp, mask, cnt);
  needed_kernel<<<1, 64, 0, stream>>>(comp, cnt, needed);
  fill_kernel<<<(2 * NRAND) / 256, 256, 0, stream>>>(mask, needed, kq0, kq1, kk0, kk1);

  dim3 gat(SEQ / 64, NHEAD, BATCH);
  attn_mfma<<<gat, 256, 0, stream>>>(Qb, Kb, Vb, mask, attnout);

  dim3 go(4, 32);
  mfma_gemm_resid<<<go, 256, 0, stream>>>(attnout, Wo, bo, queries, (float*)d_out);
}

// Round 3
// 431.555 us; speedup vs baseline: 2.9427x; 1.1845x over previous
//
#include <hip/hip_runtime.h>
#include <stdint.h>
#include <math.h>

#define DEVINL __device__ __forceinline__

constexpr int SEQ = 2048;
constexpr int DIM = 512;
constexpr int BATCH = 2;
constexpr int NHEAD = 8;
constexpr int HDIM = 64;
constexpr int NROWS = BATCH * SEQ;        // 4096
constexpr int NRAND = (SEQ * SEQ) / 2;    // 2097152 = 2^21
constexpr float NEG_MAX = -3.402823466e38f;   // jnp.finfo(f32).min
constexpr float F32_TINY = 1.1754943508222875e-38f;

typedef float float4v __attribute__((ext_vector_type(4)));
typedef short short8 __attribute__((ext_vector_type(8)));
typedef unsigned long long u64;

DEVINL float4v MFMA(short8 a, short8 b, float4v c) {
  return __builtin_amdgcn_mfma_f32_16x16x32_bf16(a, b, c, 0, 0, 0);
}

// ---------------- bf16 helpers (RNE) ----------------
DEVINL ushort f2bf(float x) {
  uint32_t u = __float_as_uint(x);
  return (ushort)((u + 0x7FFFu + ((u >> 16) & 1u)) >> 16);
}
DEVINL float bf2f(ushort h) { return __uint_as_float(((uint32_t)h) << 16); }

// ---------------- threefry2x32 (JAX-compatible, 20 rounds) ----------------
__host__ __device__ inline void tf2x32(uint32_t k0, uint32_t k1,
                                       uint32_t x0, uint32_t x1,
                                       uint32_t* o0, uint32_t* o1) {
  uint32_t ks2 = k0 ^ k1 ^ 0x1BD11BDAu;
  x0 += k0; x1 += k1;
#define TFR(r) { x0 += x1; x1 = (x1 << (r)) | (x1 >> (32 - (r))); x1 ^= x0; }
  TFR(13) TFR(15) TFR(26) TFR(6)
  x0 += k1; x1 += ks2 + 1u;
  TFR(17) TFR(29) TFR(16) TFR(24)
  x0 += ks2; x1 += k0 + 2u;
  TFR(13) TFR(15) TFR(26) TFR(6)
  x0 += k0; x1 += k1 + 3u;
  TFR(17) TFR(29) TFR(16) TFR(24)
  x0 += k1; x1 += ks2 + 4u;
  TFR(13) TFR(15) TFR(26) TFR(6)
  x0 += ks2; x1 += k0 + 5u;
#undef TFR
  *o0 = x0; *o1 = x1;
}

DEVINL uint32_t jax_bits32(uint32_t k0, uint32_t k1, uint32_t idx) {
  uint32_t a, b;
  tf2x32(k0, k1, 0u, idx, &a, &b);
  return a ^ b;
}

// ---------------- block reductions ----------------
DEVINL float blockReduceSum(float v) {
  __shared__ float sh[16];
  __syncthreads();
  int lane = threadIdx.x & 63, wid = threadIdx.x >> 6;
  #pragma unroll
  for (int o = 32; o > 0; o >>= 1) v += __shfl_down(v, o);
  if (lane == 0) sh[wid] = v;
  __syncthreads();
  if (threadIdx.x == 0) {
    int nw = ((int)blockDim.x + 63) >> 6;
    float s = 0.f;
    for (int i = 0; i < nw; i++) s += sh[i];
    sh[0] = s;
  }
  __syncthreads();
  return sh[0];
}

DEVINL float blockReduceMin(float v) {
  __shared__ float sh[16];
  __syncthreads();
  int lane = threadIdx.x & 63, wid = threadIdx.x >> 6;
  #pragma unroll
  for (int o = 32; o > 0; o >>= 1) v = fminf(v, __shfl_down(v, o));
  if (lane == 0) sh[wid] = v;
  __syncthreads();
  if (threadIdx.x == 0) {
    int nw = ((int)blockDim.x + 63) >> 6;
    float s = sh[0];
    for (int i = 1; i < nw; i++) s = fminf(s, sh[i]);
    sh[0] = s;
  }
  __syncthreads();
  return sh[0];
}

DEVINL float blockReduceMax(float v) {
  __shared__ float sh[16];
  __syncthreads();
  int lane = threadIdx.x & 63, wid = threadIdx.x >> 6;
  #pragma unroll
  for (int o = 32; o > 0; o >>= 1) v = fmaxf(v, __shfl_down(v, o));
  if (lane == 0) sh[wid] = v;
  __syncthreads();
  if (threadIdx.x == 0) {
    int nw = ((int)blockDim.x + 63) >> 6;
    float s = sh[0];
    for (int i = 1; i < nw; i++) s = fmaxf(s, sh[i]);
    sh[0] = s;
  }
  __syncthreads();
  return sh[0];
}

// ---------------- mask pipeline (bit-exact vs round 1/2) ----------------

__global__ void init_kernel(uint8_t* colm, int* cnt, int* haskp) {
  int tid = blockIdx.x * blockDim.x + threadIdx.x;
  if (tid < BATCH * SEQ) colm[tid] = 0;
  if (tid < BATCH) { cnt[tid] = 0; haskp[tid] = 0; }
}

// fused 3-tensor LayerNorm; grid (NROWS, 3)
__global__ __launch_bounds__(256) void ln3_kernel(
    const float* __restrict__ xq, const float* __restrict__ xk, const float* __restrict__ xv,
    const float* __restrict__ gq, const float* __restrict__ bq2,
    const float* __restrict__ gk, const float* __restrict__ bk2,
    const float* __restrict__ gv, const float* __restrict__ bv2,
    float* __restrict__ oq, float* __restrict__ ok, float* __restrict__ ov) {
  const float *x, *g, *bb; float* out;
  if (blockIdx.y == 0)      { x = xq; g = gq; bb = bq2; out = oq; }
  else if (blockIdx.y == 1) { x = xk; g = gk; bb = bk2; out = ok; }
  else                      { x = xv; g = gv; bb = bv2; out = ov; }
  int row = blockIdx.x;
  const float* xr = x + (size_t)row * DIM;
  int t = threadIdx.x;
  float v0 = xr[t], v1 = xr[t + 256];
  float mu = blockReduceSum(v0 + v1) * (1.0f / 512.0f);
  float d0 = v0 - mu, d1 = v1 - mu;
  float var = blockReduceSum(d0 * d0 + d1 * d1) * (1.0f / 512.0f);
  float inv = 1.0f / sqrtf(var + 1e-5f);
  out[(size_t)row * DIM + t]       = d0 * inv * g[t] + bb[t];
  out[(size_t)row * DIM + t + 256] = d1 * inv * g[t + 256] + bb[t + 256];
}

// f32 GEMM (mask-critical hidden projection only) — float4-LDS, bitwise-identical math
__global__ __launch_bounds__(256) void gemm_f32(
    const float* __restrict__ A, const float* __restrict__ W,
    const float* __restrict__ bias, float* __restrict__ C, int N, int relu) {
  __shared__ float As[16][68];
  __shared__ float Ws[16][68];
  int bm = blockIdx.y * 64, bn = blockIdx.x * 64;
  int tid = threadIdx.x;
  int tx = tid & 15, ty = tid >> 4;
  int lm = tid >> 4, lk = tid & 15;
  float acc[4][4] = {{0.f}};
  for (int kk = 0; kk < DIM; kk += 16) {
    __syncthreads();
    #pragma unroll
    for (int i = 0; i < 4; i++) {
      As[lk][lm + i * 16] = A[(size_t)(bm + lm + i * 16) * DIM + kk + lk];
      Ws[lk][lm + i * 16] = W[(size_t)(bn + lm + i * 16) * DIM + kk + lk];
    }
    __syncthreads();
    #pragma unroll
    for (int k = 0; k < 16; k++) {
      float4 a4 = *(const float4*)&As[k][ty * 4];
      float4 w4 = *(const float4*)&Ws[k][tx * 4];
      float a[4] = {a4.x, a4.y, a4.z, a4.w};
      float w[4] = {w4.x, w4.y, w4.z, w4.w};
      #pragma unroll
      for (int i = 0; i < 4; i++)
        #pragma unroll
        for (int j = 0; j < 4; j++)
          acc[i][j] += a[i] * w[j];
    }
  }
  #pragma unroll
  for (int i = 0; i < 4; i++) {
    int m = bm + ty * 4 + i;
    #pragma unroll
    for (int j = 0; j < 4; j++) {
      int n = bn + tx * 4 + j;
      float v = acc[i][j] + bias[n];
      if (relu) v = fmaxf(v, 0.f);
      C[(size_t)m * N + n] = v;
    }
  }
}

__global__ void win_kernel(const float* __restrict__ hidden,
                           const float* __restrict__ Ww2,
                           const float* __restrict__ bw2,
                           int* __restrict__ win) {
  int row = blockIdx.x;
  float v = hidden[(size_t)row * 128 + threadIdx.x] * Ww2[threadIdx.x];
  v = blockReduceSum(v);
  if (threadIdx.x == 0) {
    float y = v + bw2[0];
    float sig = 1.0f / (1.0f + expf(-y));
    float adj = 0.5f + sig;
    int w = (int)rintf(64.0f * adj);
    w = w < 1 ? 1 : (w > 128 ? 128 : w);
    win[row] = w;
  }
}

__global__ __launch_bounds__(256) void dmstats_kernel(const float* __restrict__ qn,
    float* __restrict__ dm, float* __restrict__ mag,
    float* __restrict__ ch, float* __restrict__ rowvar) {
  int t = blockIdx.x, b = blockIdx.y;
  const float* x = qn + ((size_t)b * SEQ + t) * DIM;
  int tid = threadIdx.x;
  float sx = 0, sq = 0, sdm = 0, sch = 0;
  float xs[2];
  #pragma unroll
  for (int i = 0; i < 2; i++) {
    int d = tid + i * 256;
    float xv = x[d]; xs[i] = xv;
    sx += xv; sq += xv * xv;
    float acc = 0.f;
    if (t + 1 < SEQ) { float df = fabsf(x[1 * DIM + d] - xv); acc += 0.4f * (df / 1.0f); sch += df; }
    if (t + 2 < SEQ) { float df = fabsf(x[2 * DIM + d] - xv); acc += 0.3f * (df / 2.0f); }
    if (t + 3 < SEQ) { float df = fabsf(x[3 * DIM + d] - xv); acc += 0.2f * (df / 3.0f); }
    if (t + 5 < SEQ) { float df = fabsf(x[5 * DIM + d] - xv); acc += 0.1f * (df / 5.0f); }
    sdm += acc;
  }
  float mu = blockReduceSum(sx) * (1.0f / 512.0f);
  float sv = 0;
  #pragma unroll
  for (int i = 0; i < 2; i++) { float dd = xs[i] - mu; sv += dd * dd; }
  float totsq = blockReduceSum(sq);
  float totdm = blockReduceSum(sdm);
  float totch = blockReduceSum(sch);
  float totsv = blockReduceSum(sv);
  if (tid == 0) {
    size_t idx = (size_t)b * SEQ + t;
    dm[idx] = totdm / 512.0f;
    mag[idx] = sqrtf(totsq);
    ch[idx] = (t + 1 < SEQ) ? (totch / 512.0f) : 0.f;
    rowvar[idx] = totsv / 511.0f;
  }
}

__global__ void batchstats_kernel(const float* __restrict__ dm,
    const float* __restrict__ mag, const float* __restrict__ ch,
    const float* __restrict__ rowvar, float* __restrict__ impn,
    float* __restrict__ thr, float* __restrict__ comp) {
  int b = blockIdx.x;
  int tid = threadIdx.x;
  float sdm = 0, srv = 0, lo = INFINITY, hi = -INFINITY;
  for (int t = tid; t < SEQ; t += 256) {
    size_t idx = (size_t)b * SEQ + t;
    sdm += dm[idx];
    srv += rowvar[idx];
    float imp = 0.5f * mag[idx] + 0.5f * ch[idx];
    lo = fminf(lo, imp); hi = fmaxf(hi, imp);
  }
  float meandm = blockReduceSum(sdm) * (1.0f / 2048.0f);
  float compv = blockReduceSum(srv) * (1.0f / 2048.0f);
  lo = blockReduceMin(lo);
  hi = blockReduceMax(hi);
  float sv = 0;
  for (int t = tid; t < SEQ; t += 256) {
    float d2 = dm[(size_t)b * SEQ + t] - meandm;
    sv += d2 * d2;
  }
  float var = blockReduceSum(sv) / 2047.0f;
  for (int t = tid; t < SEQ; t += 256) {
    size_t idx = (size_t)b * SEQ + t;
    float imp = 0.5f * mag[idx] + 0.5f * ch[idx];
    impn[idx] = (imp - lo) / (hi - lo + 1e-6f);
  }
  if (tid == 0) { thr[b] = meandm + 0.5f * sqrtf(var); comp[b] = compv; }
}

__global__ void kp_kernel(const float* __restrict__ dm, const float* __restrict__ thr,
                          uint8_t* __restrict__ kp, int* __restrict__ haskp) {
  int t = blockIdx.x * blockDim.x + threadIdx.x;
  int b = blockIdx.y;
  if (t >= SEQ) return;
  const float* dmb = dm + (size_t)b * SEQ;
  float v = dmb[t];
  float tb = thr[b];
  float prev = (t > 0) ? dmb[t - 1] : -1.0f;
  float next = (t < SEQ - 1) ? dmb[t + 1] : -1.0f;
  bool k = (v > tb) && (v > prev) && (v > next);
  if (t == 0 || t == SEQ - 1) k = k || (v > tb);
  kp[(size_t)b * SEQ + t] = k ? 1 : 0;
  if (k) haskp[b] = 1;
}

// parallel Gumbel top-4 (first-index tie-break matches serial scan)
__global__ void topk_kernel(const float* __restrict__ impn, uint8_t* __restrict__ colm,
                            uint32_t kg0, uint32_t kg1) {
  int rowid = blockIdx.x;
  int b = rowid >> 2, layer = rowid & 3;
  int j = threadIdx.x;
  float pv = impn[(size_t)b * SEQ + layer * 512 + j];
  float ssum = blockReduceSum(pv);
  uint32_t bits = jax_bits32(kg0, kg1, (uint32_t)(rowid * 512 + j));
  float f = __uint_as_float((bits >> 9) | 0x3F800000u) - 1.0f;
  float u = fmaxf(F32_TINY, f + F32_TINY);
  float g = -logf(-logf(u));
  float score = logf(pv / (ssum + 1e-6f) + 1e-20f) + g;
  __shared__ float sc[512];
  sc[j] = score;
  __syncthreads();
  for (int pick = 0; pick < 4; pick++) {
    if (j < 64) {
      float bv = -INFINITY; int bi = 0;
      #pragma unroll
      for (int q = 0; q < 8; q++) {
        int idx = j + q * 64;
        float v = sc[idx];
        if (v > bv) { bv = v; bi = idx; }
      }
      #pragma unroll
      for (int o = 1; o < 64; o <<= 1) {
        float ov = __shfl_xor(bv, o);
        int oi = __shfl_xor(bi, o);
        if (ov > bv || (ov == bv && oi < bi)) { bv = ov; bi = oi; }
      }
      if (j == 0) {
        colm[(size_t)b * SEQ + layer * 512 + bi] = 1;
        sc[bi] = -INFINITY;
      }
    }
    __syncthreads();
  }
}

DEVINL bool fbcol(int k) {
  return k == 0 || k == 511 || k == 1023 || k == 1535 || k == 2047;
}

// mask -> bit words; word idx = (b*32 + kc)*2048 + q, bit = key % 64
__global__ __launch_bounds__(256) void maskbuild_kernel(
    const int* __restrict__ win, const uint8_t* __restrict__ kp,
    const uint8_t* __restrict__ colm, const int* __restrict__ haskp,
    u64* __restrict__ bits, int* __restrict__ cnt) {
  int q = blockIdx.x, b = blockIdx.y;
  int w = win[(size_t)b * SEQ + q];
  int hk = haskp[b];
  bool rowk = hk ? (kp[(size_t)b * SEQ + q] != 0) : fbcol(q);
  const uint8_t* kpb = kp + (size_t)b * SEQ;
  const uint8_t* cob = colm + (size_t)b * SEQ;
  int tid = threadIdx.x, wave = tid >> 6, lane = tid & 63;
  int local = 0;
  #pragma unroll
  for (int i = 0; i < 8; i++) {
    int k = i * 256 + tid;
    bool colk = hk ? (kpb[k] != 0) : fbcol(k);
    bool mmv = ((k >= q - w) && (k <= q + w)) || rowk || colk || (cob[k] != 0);
    u64 word = __ballot(mmv);
    if (lane == 0) bits[((size_t)b * 32 + (i * 4 + wave)) * 2048 + q] = word;
    local += mmv ? 1 : 0;
  }
  float tot = blockReduceSum((float)local);
  if (tid == 0) atomicAdd(&cnt[b], (int)tot);
}

__global__ void needed_kernel(const float* __restrict__ comp,
                              const int* __restrict__ cnt, int* __restrict__ needed) {
  if (threadIdx.x == 0 && blockIdx.x == 0) {
    float c0 = comp[0], c1 = comp[1];
    float cmin = fminf(c0, c1), cmax = fmaxf(c0, c1);
    for (int b = 0; b < BATCH; b++) {
      float nc = (comp[b] - cmin) / (cmax - cmin + 1e-6f);
      float ratio = fminf(fmaxf(0.3f * (0.5f + nc), 0.1f), 0.5f);
      float dens = (float)cnt[b] / 4194304.0f;
      float nd = ceilf((ratio - dens) * 4194304.0f);
      int n = (int)nd;
      needed[b] = n > 0 ? n : 0;
    }
  }
}

__global__ void fill_kernel(u64* __restrict__ bits, const int* __restrict__ needed,
                            uint32_t kq0, uint32_t kq1, uint32_t kk0, uint32_t kk1) {
  int gid = blockIdx.x * blockDim.x + threadIdx.x;
  int b = gid >> 21;
  int r = gid & (NRAND - 1);
  if (b >= BATCH) return;
  if (r >= needed[b]) return;
  uint32_t flat = 4194304u + (uint32_t)gid;
  uint32_t q = jax_bits32(kq0, kq1, flat) & 2047u;
  uint32_t k = jax_bits32(kk0, kk1, flat) & 2047u;
  atomicOr(&bits[((size_t)b * 32 + (k >> 6)) * 2048 + q], 1ull << (k & 63));
}

// ---------------- conversion kernels ----------------
// GEMM A/W fragment-image: per (rowblk(128), kchunk(32)) chunk of 4096 ushorts;
// ushort pos = chunk*4096 + (((rr>>4)*4 + (kin32>>3))*16 + (rr&15))*8 + (k&7)

DEVINL void conv_one(const float* src, ushort* hi, ushort* lo, int nrows, int gid) {
  int row = gid >> 6, c8 = gid & 63;
  if (row >= nrows) return;
  const float* p = src + (size_t)row * 512 + c8 * 8;
  float4 v0 = ((const float4*)p)[0];
  float4 v1 = ((const float4*)p)[1];
  float xv[8] = {v0.x, v0.y, v0.z, v0.w, v1.x, v1.y, v1.z, v1.w};
  short8 hv, lv;
  #pragma unroll
  for (int j = 0; j < 8; j++) {
    ushort hh = f2bf(xv[j]);
    hv[j] = (short)hh;
    lv[j] = (short)f2bf(xv[j] - bf2f(hh));
  }
  int mb = row >> 7, rr = row & 127, kkc = c8 >> 2, qr = c8 & 3;
  size_t pos = ((size_t)(mb * 16 + kkc)) * 4096 + (((rr >> 4) * 4 + qr) * 16 + (rr & 15)) * 8;
  *(short8*)(hi + pos) = hv;
  if (lo) *(short8*)(lo + pos) = lv;
}

__global__ __launch_bounds__(256) void conv_img7(
    const float* s0, ushort* h0, ushort* l0, int n0,
    const float* s1, ushort* h1, ushort* l1, int n1,
    const float* s2, ushort* h2, ushort* l2, int n2,
    const float* s3, ushort* h3, ushort* l3, int n3,
    const float* s4, ushort* h4, ushort* l4, int n4,
    const float* s5, ushort* h5, ushort* l5, int n5,
    const float* s6, ushort* h6, ushort* l6, int n6) {
  const float* src; ushort* hi; ushort* lo; int nrows;
  switch (blockIdx.y) {
    case 0: src = s0; hi = h0; lo = l0; nrows = n0; break;
    case 1: src = s1; hi = h1; lo = l1; nrows = n1; break;
    case 2: src = s2; hi = h2; lo = l2; nrows = n2; break;
    case 3: src = s3; hi = h3; lo = l3; nrows = n3; break;
    case 4: src = s4; hi = h4; lo = l4; nrows = n4; break;
    case 5: src = s5; hi = h5; lo = l5; nrows = n5; break;
    default: src = s6; hi = h6; lo = l6; nrows = n6; break;
  }
  conv_one(src, hi, lo, nrows, blockIdx.x * 256 + threadIdx.x);
}

// K/V attention tile images (layout = attn's frag-linear LDS image per 64-key tile)
__global__ __launch_bounds__(256) void conv_kv(
    const float* __restrict__ Kb, const float* __restrict__ Vb,
    ushort* __restrict__ Khig, ushort* __restrict__ Klog, ushort* __restrict__ Vimg) {
  int gid = blockIdx.x * 256 + threadIdx.x;
  if (blockIdx.y == 0) {
    int row = gid >> 6, c8 = gid & 63;
    int h = c8 >> 3, d8 = c8 & 7;
    const float* p = Kb + (size_t)row * 512 + h * 64 + d8 * 8;
    float4 v0 = ((const float4*)p)[0];
    float4 v1 = ((const float4*)p)[1];
    float xv[8] = {v0.x, v0.y, v0.z, v0.w, v1.x, v1.y, v1.z, v1.w};
    short8 hv, lv;
    #pragma unroll
    for (int j = 0; j < 8; j++) {
      ushort hh = f2bf(xv[j]);
      hv[j] = (short)hh;
      lv[j] = (short)f2bf(xv[j] - bf2f(hh));
    }
    int bb = row >> 11, sq = row & 2047, t = sq >> 6, r = sq & 63;
    size_t pos = ((size_t)((bb * 8 + h) * 32 + t)) * 4096
               + ((((r >> 4) * 2 + (d8 >> 2)) * 4 + (d8 & 3)) * 16 + (r & 15)) * 8;
    *(short8*)(Khig + pos) = hv;
    *(short8*)(Klog + pos) = lv;
  } else {
    int tile = gid >> 9, rem = gid & 511, d = rem >> 3, k8 = rem & 7;
    int bb = tile >> 8, h = (tile >> 5) & 7, t = tile & 31;
    const float* p = Vb + ((size_t)(bb * 2048 + t * 64 + k8 * 8)) * 512 + h * 64 + d;
    short8 hv;
    #pragma unroll
    for (int j = 0; j < 8; j++) hv[j] = (short)f2bf(p[(size_t)j * 512]);
    size_t pos = (size_t)tile * 4096
               + ((((k8 >> 2) * 4 + (d >> 4)) * 4 + (k8 & 3)) * 16 + (d & 15)) * 8;
    *(short8*)(Vimg + pos) = hv;
  }
}

// ---------------- image-staged MFMA GEMM (split or plain bf16) ----------------
DEVINL void gemm_img_body(const ushort* __restrict__ Ahg, const ushort* __restrict__ Alg,
                          const ushort* __restrict__ Whg, const ushort* __restrict__ Wlg,
                          const float* __restrict__ bias, const float* __restrict__ resid,
                          float* __restrict__ C, int split) {
  __shared__ __align__(16) ushort Ah[4096], Wh[4096], Al[4096], Wl[4096];
  int tid = threadIdx.x, wave = tid >> 6, lane = tid & 63;
  int mm = lane & 15, qr = lane >> 4;
  int wm = (wave >> 1) * 64, wn = (wave & 1) * 64;
  int bm = blockIdx.y * 128, bn = blockIdx.x * 128;
  float4v acc[4][4] = {};
  for (int kk = 0; kk < 16; kk++) {
    __syncthreads();
    {
      const short8* ga = (const short8*)(Ahg + ((size_t)((bm >> 7) * 16 + kk)) * 4096);
      const short8* gw = (const short8*)(Whg + ((size_t)((bn >> 7) * 16 + kk)) * 4096);
      ((short8*)Ah)[tid] = ga[tid];
      ((short8*)Ah)[tid + 256] = ga[tid + 256];
      ((short8*)Wh)[tid] = gw[tid];
      ((short8*)Wh)[tid + 256] = gw[tid + 256];
      if (split) {
        const short8* ga2 = (const short8*)(Alg + ((size_t)((bm >> 7) * 16 + kk)) * 4096);
        const short8* gw2 = (const short8*)(Wlg + ((size_t)((bn >> 7) * 16 + kk)) * 4096);
        ((short8*)Al)[tid] = ga2[tid];
        ((short8*)Al)[tid + 256] = ga2[tid + 256];
        ((short8*)Wl)[tid] = gw2[tid];
        ((short8*)Wl)[tid + 256] = gw2[tid + 256];
      }
    }
    __syncthreads();
    short8 ah[4], bh[4];
    #pragma unroll
    for (int mt = 0; mt < 4; mt++)
      ah[mt] = ((short8*)Ah)[(((wm >> 4) + mt) * 4 + qr) * 16 + mm];
    #pragma unroll
    for (int nt = 0; nt < 4; nt++)
      bh[nt] = ((short8*)Wh)[(((wn >> 4) + nt) * 4 + qr) * 16 + mm];
    if (split) {
      short8 al[4], bl[4];
      #pragma unroll
      for (int mt = 0; mt < 4; mt++)
        al[mt] = ((short8*)Al)[(((wm >> 4) + mt) * 4 + qr) * 16 + mm];
      #pragma unroll
      for (int nt = 0; nt < 4; nt++)
        bl[nt] = ((short8*)Wl)[(((wn >> 4) + nt) * 4 + qr) * 16 + mm];
      #pragma unroll
      for (int mt = 0; mt < 4; mt++)
        #pragma unroll
        for (int nt = 0; nt < 4; nt++) {
          acc[mt][nt] = MFMA(al[mt], bh[nt], acc[mt][nt]);
          acc[mt][nt] = MFMA(ah[mt], bl[nt], acc[mt][nt]);
          acc[mt][nt] = MFMA(ah[mt], bh[nt], acc[mt][nt]);
        }
    } else {
      #pragma unroll
      for (int mt = 0; mt < 4; mt++)
        #pragma unroll
        for (int nt = 0; nt < 4; nt++)
          acc[mt][nt] = MFMA(ah[mt], bh[nt], acc[mt][nt]);
    }
  }
  #pragma unroll
  for (int mt = 0; mt < 4; mt++)
    #pragma unroll
    for (int nt = 0; nt < 4; nt++) {
      int n = bn + wn + nt * 16 + mm;
      float bsv = bias[n];
      #pragma unroll
      for (int reg = 0; reg < 4; reg++) {
        int m = bm + wm + mt * 16 + qr * 4 + reg;
        float v = acc[mt][nt][reg] + bsv;
        if (resid) v += resid[(size_t)m * 512 + n];
        C[(size_t)m * 512 + n] = v;
      }
    }
}

__global__ __launch_bounds__(256) void mfma_gemm_img3(
    const ushort* A0h, const ushort* A0l, const ushort* W0h, const ushort* W0l,
    const float* b0, const float* r0, float* C0, int s0,
    const ushort* A1h, const ushort* A1l, const ushort* W1h, const ushort* W1l,
    const float* b1, const float* r1, float* C1, int s1,
    const ushort* A2h, const ushort* A2l, const ushort* W2h, const ushort* W2l,
    const float* b2, const float* r2, float* C2, int s2) {
  if (blockIdx.z == 0)      gemm_img_body(A0h, A0l, W0h, W0l, b0, r0, C0, s0);
  else if (blockIdx.z == 1) gemm_img_body(A1h, A1l, W1h, W1l, b1, r1, C1, s1);
  else                      gemm_img_body(A2h, A2l, W2h, W2l, b2, r2, C2, s2);
}

// ---------------- MFMA flash attention (pre-imaged K/V, bit-mask) ----------------
__global__ __launch_bounds__(256) void attn_mfma(
    const float* __restrict__ Qb, const ushort* __restrict__ Khig,
    const ushort* __restrict__ Klog, const ushort* __restrict__ Vimg,
    const u64* __restrict__ bits, ushort* __restrict__ Oimg) {
  int qt = blockIdx.x, h = blockIdx.y, b = blockIdx.z;
  __shared__ __align__(16) ushort Khi[4096], Klo[4096], Vs[4096];
  __shared__ __align__(16) ushort Ps[4][1024];
  __shared__ u64 Mb[64];
  int tid = threadIdx.x, wave = tid >> 6, lane = tid & 63;
  int mm = lane & 15, qr = lane >> 4;
  int q0 = qt * 64;

  short8 aqh[2], aql[2];
  {
    const float* qp = Qb + ((size_t)(b * SEQ + q0 + wave * 16 + mm)) * 512 + h * 64 + qr * 8;
    #pragma unroll
    for (int dc = 0; dc < 2; dc++) {
      float4 v0 = ((const float4*)(qp + dc * 32))[0];
      float4 v1 = ((const float4*)(qp + dc * 32))[1];
      float xv[8] = {v0.x, v0.y, v0.z, v0.w, v1.x, v1.y, v1.z, v1.w};
      #pragma unroll
      for (int j = 0; j < 8; j++) {
        ushort hh = f2bf(xv[j]);
        aqh[dc][j] = (short)hh;
        aql[dc][j] = (short)f2bf(xv[j] - bf2f(hh));
      }
    }
  }
  float4v accO[4] = {};
  float m_i[4], l_i[4];
  #pragma unroll
  for (int r = 0; r < 4; r++) { m_i[r] = -INFINITY; l_i[r] = 0.f; }
  size_t kvbase = ((size_t)((b * 8 + h) * 32)) * 4096;
  const u64* bitp = bits + (size_t)b * 32 * 2048 + q0;

  for (int kc = 0; kc < 32; kc++) {
    __syncthreads();
    {
      const short8* gk = (const short8*)(Khig + kvbase + (size_t)kc * 4096);
      const short8* gl = (const short8*)(Klog + kvbase + (size_t)kc * 4096);
      const short8* gv = (const short8*)(Vimg + kvbase + (size_t)kc * 4096);
      ((short8*)Khi)[tid] = gk[tid];
      ((short8*)Khi)[tid + 256] = gk[tid + 256];
      ((short8*)Klo)[tid] = gl[tid];
      ((short8*)Klo)[tid + 256] = gl[tid + 256];
      ((short8*)Vs)[tid] = gv[tid];
      ((short8*)Vs)[tid + 256] = gv[tid + 256];
      if (tid < 64) Mb[tid] = bitp[(size_t)kc * 2048 + tid];
    }
    __syncthreads();
    u64 mrow[4];
    #pragma unroll
    for (int reg = 0; reg < 4; reg++) mrow[reg] = Mb[wave * 16 + qr * 4 + reg];
    // QK^T (split bf16)
    float4v S[4];
    #pragma unroll
    for (int ct = 0; ct < 4; ct++) {
      float4v s = {};
      #pragma unroll
      for (int dc = 0; dc < 2; dc++) {
        short8 bhf = ((short8*)Khi)[((ct * 2 + dc) * 4 + qr) * 16 + mm];
        short8 blf = ((short8*)Klo)[((ct * 2 + dc) * 4 + qr) * 16 + mm];
        s = MFMA(aql[dc], bhf, s);
        s = MFMA(aqh[dc], blf, s);
        s = MFMA(aqh[dc], bhf, s);
      }
      S[ct] = s;
    }
    // scale + mask + online softmax
    float4v Pv[4];
    #pragma unroll
    for (int reg = 0; reg < 4; reg++) {
      float sv[4];
      float mx = -INFINITY;
      #pragma unroll
      for (int ct = 0; ct < 4; ct++) {
        float s = S[ct][reg] * 0.125f;
        if ((mrow[reg] >> (ct * 16 + mm)) & 1ull) s = NEG_MAX;
        sv[ct] = s;
        mx = fmaxf(mx, s);
      }
      #pragma unroll
      for (int o = 1; o < 16; o <<= 1) mx = fmaxf(mx, __shfl_xor(mx, o));
      float mn = fmaxf(m_i[reg], mx);
      float ps = 0.f;
      #pragma unroll
      for (int ct = 0; ct < 4; ct++) {
        float p = __expf(sv[ct] - mn);
        Pv[ct][reg] = p;
        ps += p;
      }
      #pragma unroll
      for (int o = 1; o < 16; o <<= 1) ps += __shfl_xor(ps, o);
      float alpha = __expf(m_i[reg] - mn);
      l_i[reg] = l_i[reg] * alpha + ps;
      m_i[reg] = mn;
      #pragma unroll
      for (int dt = 0; dt < 4; dt++) accO[dt][reg] *= alpha;
    }
    // P -> wave-private LDS (bf16, XOR-swizzled)
    ushort* pw = &Ps[wave][0];
    #pragma unroll
    for (int ct = 0; ct < 4; ct++) {
      int kc2 = ct >> 1;
      int qf = (2 * ct + (mm >> 3)) & 3;
      int j = mm & 7;
      #pragma unroll
      for (int reg = 0; reg < 4; reg++) {
        int blk = kc2 * 64 + qf * 16 + (qr * 4 + reg);
        blk ^= (blk >> 3) & 3;
        pw[blk * 8 + j] = f2bf(Pv[ct][reg]);
      }
    }
    // PV (plain bf16)
    #pragma unroll
    for (int kc2 = 0; kc2 < 2; kc2++) {
      int blk = kc2 * 64 + qr * 16 + mm;
      blk ^= (blk >> 3) & 3;
      short8 ap = *(const short8*)(pw + blk * 8);
      #pragma unroll
      for (int dt = 0; dt < 4; dt++) {
        short8 bv = ((short8*)Vs)[((kc2 * 4 + dt) * 4 + qr) * 16 + mm];
        accO[dt] = MFMA(ap, bv, accO[dt]);
      }
    }
  }
  // epilogue: normalize, bf16, scatter directly into O-proj A-image
  float inv[4];
  #pragma unroll
  for (int reg = 0; reg < 4; reg++) inv[reg] = 1.0f / l_i[reg];
  #pragma unroll
  for (int dt = 0; dt < 4; dt++)
    #pragma unroll
    for (int reg = 0; reg < 4; reg++) {
      float v = accO[dt][reg] * inv[reg];
      int rowg = b * SEQ + q0 + wave * 16 + qr * 4 + reg;
      int col = h * 64 + dt * 16 + mm;
      int mb2 = rowg >> 7, rr = rowg & 127;
      int kkc = col >> 5, qrk = (col >> 3) & 3, j = col & 7;
      Oimg[((size_t)(mb2 * 16 + kkc)) * 4096 + (((rr >> 4) * 4 + qrk) * 16 + (rr & 15)) * 8 + j] = f2bf(v);
    }
}

// ---------------- launcher ----------------
extern "C" void kernel_launch(void* const* d_in, const int* in_sizes, int n_in,
                              void* d_out, int out_size, void* d_ws, size_t ws_size,
                              hipStream_t stream) {
  (void)in_sizes; (void)n_in; (void)out_size; (void)ws_size;
  const float* queries = (const float*)d_in[0];
  const float* keys    = (const float*)d_in[1];
  const float* values  = (const float*)d_in[2];
  const float* ln_q_g  = (const float*)d_in[3];
  const float* ln_q_b  = (const float*)d_in[4];
  const float* ln_k_g  = (const float*)d_in[5];
  const float* ln_k_b  = (const float*)d_in[6];
  const float* ln_v_g  = (const float*)d_in[7];
  const float* ln_v_b  = (const float*)d_in[8];
  const float* Wq = (const float*)d_in[9];  const float* bq = (const float*)d_in[10];
  const float* Wk = (const float*)d_in[11]; const float* bk = (const float*)d_in[12];
  const float* Wv = (const float*)d_in[13]; const float* bv = (const float*)d_in[14];
  const float* Wo = (const float*)d_in[15]; const float* bo = (const float*)d_in[16];
  const float* Ww1 = (const float*)d_in[17]; const float* bw1 = (const float*)d_in[18];
  const float* Ww2 = (const float*)d_in[19]; const float* bw2 = (const float*)d_in[20];

  char* ws = (char*)d_ws;
  const size_t MB = 1u << 20;
  float* qn      = (float*)(ws + 0 * MB);    // 8 MB; front 4 MB reused as Oimg
  float* kn      = (float*)(ws + 8 * MB);    // 8 MB; reused as Kb f32
  float* vn      = (float*)(ws + 16 * MB);   // 8 MB; reused as Vb f32
  float* Qb      = (float*)(ws + 24 * MB);   // 8 MB
  ushort* qnh    = (ushort*)(ws + 32 * MB);  // 4 MB each
  ushort* qnl    = (ushort*)(ws + 36 * MB);
  ushort* knh    = (ushort*)(ws + 40 * MB);
  ushort* knl    = (ushort*)(ws + 44 * MB);
  ushort* vnh    = (ushort*)(ws + 48 * MB);
  ushort* Wqh    = (ushort*)(ws + 52 * MB);  // 0.5 MB each
  ushort* Wql    = (ushort*)(ws + 52 * MB + 524288);
  ushort* Wkh    = (ushort*)(ws + 53 * MB);
  ushort* Wkl    = (ushort*)(ws + 53 * MB + 524288);
  ushort* Wvh    = (ushort*)(ws + 54 * MB);
  ushort* Woh    = (ushort*)(ws + 54 * MB + 524288);
  ushort* Kth    = (ushort*)(ws + 55 * MB);  // 4 MB
  ushort* Ktl    = (ushort*)(ws + 59 * MB);  // 4 MB
  ushort* Vt     = (ushort*)(ws + 63 * MB);  // 4 MB
  u64*    bits   = (u64*)(ws + 67 * MB);     // 1 MB
  float*  hidden = (float*)(ws + 68 * MB);   // 2 MB
  char* st = ws + 70 * MB;
  float* dm     = (float*)st; st += NROWS * 4;
  float* mag    = (float*)st; st += NROWS * 4;
  float* ch     = (float*)st; st += NROWS * 4;
  float* rowvar = (float*)st; st += NROWS * 4;
  float* impn   = (float*)st; st += NROWS * 4;
  int*   win    = (int*)st;   st += NROWS * 4;
  uint8_t* kp   = (uint8_t*)st; st += NROWS;
  uint8_t* colm = (uint8_t*)st; st += NROWS;
  float* thr    = (float*)st; st += 2 * 4;
  float* comp   = (float*)st; st += 2 * 4;
  int* cnt      = (int*)st;   st += 2 * 4;
  int* haskp    = (int*)st;   st += 2 * 4;
  int* needed   = (int*)st;   st += 2 * 4;
  float* Kb = kn;               // kn dead after conv_img7
  float* Vb = vn;               // vn dead after conv_img7
  ushort* Oimg = (ushort*)qn;   // qn dead after conv_img7/dmstats/hidden

  uint32_t kg0, kg1, kq0, kq1, kk0, kk1;
  tf2x32(0u, 42u, 0u, 0u, &kg0, &kg1);
  tf2x32(0u, 42u, 0u, 1u, &kq0, &kq1);
  tf2x32(0u, 42u, 0u, 2u, &kk0, &kk1);

  init_kernel<<<16, 256, 0, stream>>>(colm, cnt, haskp);
  dim3 gln(NROWS, 3);
  ln3_kernel<<<gln, 256, 0, stream>>>(queries, keys, values,
                                      ln_q_g, ln_q_b, ln_k_g, ln_k_b, ln_v_g, ln_v_b,
                                      qn, kn, vn);

  // mask-critical path (exact f32, bitwise-identical)
  dim3 g128(2, 64);
  gemm_f32<<<g128, 256, 0, stream>>>(qn, Ww1, bw1, hidden, 128, 1);
  win_kernel<<<NROWS, 128, 0, stream>>>(hidden, Ww2, bw2, win);
  dim3 gdm(SEQ, BATCH);
  dmstats_kernel<<<gdm, 256, 0, stream>>>(qn, dm, mag, ch, rowvar);
  batchstats_kernel<<<BATCH, 256, 0, stream>>>(dm, mag, ch, rowvar, impn, thr, comp);
  dim3 gkp(SEQ / 256, BATCH);
  kp_kernel<<<gkp, 256, 0, stream>>>(dm, thr, kp, haskp);
  topk_kernel<<<8, 512, 0, stream>>>(impn, colm, kg0, kg1);

  // split/plain bf16 images for GEMM operands
  dim3 gc7(1024, 7);
  conv_img7<<<gc7, 256, 0, stream>>>(
      qn, qnh, qnl, NROWS,
      kn, knh, knl, NROWS,
      vn, vnh, (ushort*)nullptr, NROWS,
      Wq, Wqh, Wql, 512,
      Wk, Wkh, Wkl, 512,
      Wv, Wvh, (ushort*)nullptr, 512,
      Wo, Woh, (ushort*)nullptr, 512);

  // Q/K/V projections (Q,K split-3; V plain)
  dim3 gqkv(4, 32, 3);
  mfma_gemm_img3<<<gqkv, 256, 0, stream>>>(
      qnh, qnl, Wqh, Wql, bq, nullptr, Qb, 1,
      knh, knl, Wkh, Wkl, bk, nullptr, Kb, 1,
      vnh, nullptr, Wvh, nullptr, bv, nullptr, Vb, 0);

  dim3 gkv(1024, 2);
  conv_kv<<<gkv, 256, 0, stream>>>(Kb, Vb, Kth, Ktl, Vt);

  dim3 gmb(SEQ, BATCH);
  maskbuild_kernel<<<gmb, 256, 0, stream>>>(win, kp, colm, haskp, bits, cnt);
  needed_kernel<<<1, 64, 0, stream>>>(comp, cnt, needed);
  fill_kernel<<<(2 * NRAND) / 256, 256, 0, stream>>>(bits, needed, kq0, kq1, kk0, kk1);

  dim3 gat(SEQ / 64, NHEAD, BATCH);
  attn_mfma<<<gat, 256, 0, stream>>>(Qb, Kth, Ktl, Vt, bits, Oimg);

  // output projection (plain bf16) + residual
  dim3 go(4, 32, 1);
  mfma_gemm_img3<<<go, 256, 0, stream>>>(
      Oimg, nullptr, Woh, nullptr, bo, queries, (float*)d_out, 0,
      Oimg, nullptr, Woh, nullptr, bo, queries, (float*)d_out, 0,
      Oimg, nullptr, Woh, nullptr, bo, queries, (float*)d_out, 0);
}

// Round 4
// 402.406 us; speedup vs baseline: 3.1559x; 1.0724x over previous
//
#include <hip/hip_runtime.h>
#include <stdint.h>
#include <math.h>

#define DEVINL __device__ __forceinline__

constexpr int SEQ = 2048;
constexpr int DIM = 512;
constexpr int BATCH = 2;
constexpr int NHEAD = 8;
constexpr int HDIM = 64;
constexpr int NROWS = BATCH * SEQ;        // 4096
constexpr int NRAND = (SEQ * SEQ) / 2;    // 2097152 = 2^21
constexpr float NEG_MAX = -3.402823466e38f;   // jnp.finfo(f32).min
constexpr float F32_TINY = 1.1754943508222875e-38f;

typedef float float4v __attribute__((ext_vector_type(4)));
typedef short short8 __attribute__((ext_vector_type(8)));
typedef unsigned long long u64;

DEVINL float4v MFMA(short8 a, short8 b, float4v c) {
  return __builtin_amdgcn_mfma_f32_16x16x32_bf16(a, b, c, 0, 0, 0);
}

// ---------------- bf16 helpers (RNE) ----------------
DEVINL ushort f2bf(float x) {
  uint32_t u = __float_as_uint(x);
  return (ushort)((u + 0x7FFFu + ((u >> 16) & 1u)) >> 16);
}
DEVINL float bf2f(ushort h) { return __uint_as_float(((uint32_t)h) << 16); }

// ---------------- threefry2x32 (JAX-compatible, 20 rounds) ----------------
__host__ __device__ inline void tf2x32(uint32_t k0, uint32_t k1,
                                       uint32_t x0, uint32_t x1,
                                       uint32_t* o0, uint32_t* o1) {
  uint32_t ks2 = k0 ^ k1 ^ 0x1BD11BDAu;
  x0 += k0; x1 += k1;
#define TFR(r) { x0 += x1; x1 = (x1 << (r)) | (x1 >> (32 - (r))); x1 ^= x0; }
  TFR(13) TFR(15) TFR(26) TFR(6)
  x0 += k1; x1 += ks2 + 1u;
  TFR(17) TFR(29) TFR(16) TFR(24)
  x0 += ks2; x1 += k0 + 2u;
  TFR(13) TFR(15) TFR(26) TFR(6)
  x0 += k0; x1 += k1 + 3u;
  TFR(17) TFR(29) TFR(16) TFR(24)
  x0 += k1; x1 += ks2 + 4u;
  TFR(13) TFR(15) TFR(26) TFR(6)
  x0 += ks2; x1 += k0 + 5u;
#undef TFR
  *o0 = x0; *o1 = x1;
}

DEVINL uint32_t jax_bits32(uint32_t k0, uint32_t k1, uint32_t idx) {
  uint32_t a, b;
  tf2x32(k0, k1, 0u, idx, &a, &b);
  return a ^ b;
}

// ---------------- block reductions ----------------
DEVINL float blockReduceSum(float v) {
  __shared__ float sh[16];
  __syncthreads();
  int lane = threadIdx.x & 63, wid = threadIdx.x >> 6;
  #pragma unroll
  for (int o = 32; o > 0; o >>= 1) v += __shfl_down(v, o);
  if (lane == 0) sh[wid] = v;
  __syncthreads();
  if (threadIdx.x == 0) {
    int nw = ((int)blockDim.x + 63) >> 6;
    float s = 0.f;
    for (int i = 0; i < nw; i++) s += sh[i];
    sh[0] = s;
  }
  __syncthreads();
  return sh[0];
}

DEVINL float blockReduceMin(float v) {
  __shared__ float sh[16];
  __syncthreads();
  int lane = threadIdx.x & 63, wid = threadIdx.x >> 6;
  #pragma unroll
  for (int o = 32; o > 0; o >>= 1) v = fminf(v, __shfl_down(v, o));
  if (lane == 0) sh[wid] = v;
  __syncthreads();
  if (threadIdx.x == 0) {
    int nw = ((int)blockDim.x + 63) >> 6;
    float s = sh[0];
    for (int i = 1; i < nw; i++) s = fminf(s, sh[i]);
    sh[0] = s;
  }
  __syncthreads();
  return sh[0];
}

DEVINL float blockReduceMax(float v) {
  __shared__ float sh[16];
  __syncthreads();
  int lane = threadIdx.x & 63, wid = threadIdx.x >> 6;
  #pragma unroll
  for (int o = 32; o > 0; o >>= 1) v = fmaxf(v, __shfl_down(v, o));
  if (lane == 0) sh[wid] = v;
  __syncthreads();
  if (threadIdx.x == 0) {
    int nw = ((int)blockDim.x + 63) >> 6;
    float s = sh[0];
    for (int i = 1; i < nw; i++) s = fmaxf(s, sh[i]);
    sh[0] = s;
  }
  __syncthreads();
  return sh[0];
}

// ---------------- mask pipeline (bit-exact vs rounds 1-3) ----------------

__global__ void init_kernel(uint8_t* colm, int* cnt, int* haskp) {
  int tid = blockIdx.x * blockDim.x + threadIdx.x;
  if (tid < BATCH * SEQ) colm[tid] = 0;
  if (tid < BATCH) { cnt[tid] = 0; haskp[tid] = 0; }
}

__global__ __launch_bounds__(256) void ln3_kernel(
    const float* __restrict__ xq, const float* __restrict__ xk, const float* __restrict__ xv,
    const float* __restrict__ gq, const float* __restrict__ bq2,
    const float* __restrict__ gk, const float* __restrict__ bk2,
    const float* __restrict__ gv, const float* __restrict__ bv2,
    float* __restrict__ oq, float* __restrict__ ok, float* __restrict__ ov) {
  const float *x, *g, *bb; float* out;
  if (blockIdx.y == 0)      { x = xq; g = gq; bb = bq2; out = oq; }
  else if (blockIdx.y == 1) { x = xk; g = gk; bb = bk2; out = ok; }
  else                      { x = xv; g = gv; bb = bv2; out = ov; }
  int row = blockIdx.x;
  const float* xr = x + (size_t)row * DIM;
  int t = threadIdx.x;
  float v0 = xr[t], v1 = xr[t + 256];
  float mu = blockReduceSum(v0 + v1) * (1.0f / 512.0f);
  float d0 = v0 - mu, d1 = v1 - mu;
  float var = blockReduceSum(d0 * d0 + d1 * d1) * (1.0f / 512.0f);
  float inv = 1.0f / sqrtf(var + 1e-5f);
  out[(size_t)row * DIM + t]       = d0 * inv * g[t] + bb[t];
  out[(size_t)row * DIM + t + 256] = d1 * inv * g[t + 256] + bb[t + 256];
}

// f32 GEMM, mask-critical hidden projection. BM=16 retile (512 blocks); the
// per-output k-accumulation order is unchanged -> bitwise identical results.
__global__ __launch_bounds__(256) void gemm_f32(
    const float* __restrict__ A, const float* __restrict__ W,
    const float* __restrict__ bias, float* __restrict__ C, int N, int relu) {
  __shared__ float As[16][17];
  __shared__ float Ws[16][68];
  int bm = blockIdx.y * 16, bn = blockIdx.x * 64;
  int tid = threadIdx.x;
  int tx = tid & 15, ty = tid >> 4;
  int lk = tid & 15, lm = tid >> 4;
  float acc[4] = {0.f, 0.f, 0.f, 0.f};
  for (int kk = 0; kk < DIM; kk += 16) {
    __syncthreads();
    As[lk][lm] = A[(size_t)(bm + lm) * DIM + kk + lk];
    #pragma unroll
    for (int i = 0; i < 4; i++)
      Ws[lk][lm + i * 16] = W[(size_t)(bn + lm + i * 16) * DIM + kk + lk];
    __syncthreads();
    #pragma unroll
    for (int k = 0; k < 16; k++) {
      float a = As[k][ty];
      float4 w4 = *(const float4*)&Ws[k][tx * 4];
      acc[0] += a * w4.x; acc[1] += a * w4.y;
      acc[2] += a * w4.z; acc[3] += a * w4.w;
    }
  }
  int m = bm + ty;
  #pragma unroll
  for (int j = 0; j < 4; j++) {
    int n = bn + tx * 4 + j;
    float v = acc[j] + bias[n];
    if (relu) v = fmaxf(v, 0.f);
    C[(size_t)m * N + n] = v;
  }
}

__global__ void win_kernel(const float* __restrict__ hidden,
                           const float* __restrict__ Ww2,
                           const float* __restrict__ bw2,
                           int* __restrict__ win) {
  int row = blockIdx.x;
  float v = hidden[(size_t)row * 128 + threadIdx.x] * Ww2[threadIdx.x];
  v = blockReduceSum(v);
  if (threadIdx.x == 0) {
    float y = v + bw2[0];
    float sig = 1.0f / (1.0f + expf(-y));
    float adj = 0.5f + sig;
    int w = (int)rintf(64.0f * adj);
    w = w < 1 ? 1 : (w > 128 ? 128 : w);
    win[row] = w;
  }
}

__global__ __launch_bounds__(256) void dmstats_kernel(const float* __restrict__ qn,
    float* __restrict__ dm, float* __restrict__ mag,
    float* __restrict__ ch, float* __restrict__ rowvar) {
  int t = blockIdx.x, b = blockIdx.y;
  const float* x = qn + ((size_t)b * SEQ + t) * DIM;
  int tid = threadIdx.x;
  float sx = 0, sq = 0, sdm = 0, sch = 0;
  float xs[2];
  #pragma unroll
  for (int i = 0; i < 2; i++) {
    int d = tid + i * 256;
    float xv = x[d]; xs[i] = xv;
    sx += xv; sq += xv * xv;
    float acc = 0.f;
    if (t + 1 < SEQ) { float df = fabsf(x[1 * DIM + d] - xv); acc += 0.4f * (df / 1.0f); sch += df; }
    if (t + 2 < SEQ) { float df = fabsf(x[2 * DIM + d] - xv); acc += 0.3f * (df / 2.0f); }
    if (t + 3 < SEQ) { float df = fabsf(x[3 * DIM + d] - xv); acc += 0.2f * (df / 3.0f); }
    if (t + 5 < SEQ) { float df = fabsf(x[5 * DIM + d] - xv); acc += 0.1f * (df / 5.0f); }
    sdm += acc;
  }
  float mu = blockReduceSum(sx) * (1.0f / 512.0f);
  float sv = 0;
  #pragma unroll
  for (int i = 0; i < 2; i++) { float dd = xs[i] - mu; sv += dd * dd; }
  float totsq = blockReduceSum(sq);
  float totdm = blockReduceSum(sdm);
  float totch = blockReduceSum(sch);
  float totsv = blockReduceSum(sv);
  if (tid == 0) {
    size_t idx = (size_t)b * SEQ + t;
    dm[idx] = totdm / 512.0f;
    mag[idx] = sqrtf(totsq);
    ch[idx] = (t + 1 < SEQ) ? (totch / 512.0f) : 0.f;
    rowvar[idx] = totsv / 511.0f;
  }
}

__global__ void batchstats_kernel(const float* __restrict__ dm,
    const float* __restrict__ mag, const float* __restrict__ ch,
    const float* __restrict__ rowvar, float* __restrict__ impn,
    float* __restrict__ thr, float* __restrict__ comp) {
  int b = blockIdx.x;
  int tid = threadIdx.x;
  float sdm = 0, srv = 0, lo = INFINITY, hi = -INFINITY;
  for (int t = tid; t < SEQ; t += 256) {
    size_t idx = (size_t)b * SEQ + t;
    sdm += dm[idx];
    srv += rowvar[idx];
    float imp = 0.5f * mag[idx] + 0.5f * ch[idx];
    lo = fminf(lo, imp); hi = fmaxf(hi, imp);
  }
  float meandm = blockReduceSum(sdm) * (1.0f / 2048.0f);
  float compv = blockReduceSum(srv) * (1.0f / 2048.0f);
  lo = blockReduceMin(lo);
  hi = blockReduceMax(hi);
  float sv = 0;
  for (int t = tid; t < SEQ; t += 256) {
    float d2 = dm[(size_t)b * SEQ + t] - meandm;
    sv += d2 * d2;
  }
  float var = blockReduceSum(sv) / 2047.0f;
  for (int t = tid; t < SEQ; t += 256) {
    size_t idx = (size_t)b * SEQ + t;
    float imp = 0.5f * mag[idx] + 0.5f * ch[idx];
    impn[idx] = (imp - lo) / (hi - lo + 1e-6f);
  }
  if (tid == 0) { thr[b] = meandm + 0.5f * sqrtf(var); comp[b] = compv; }
}

__global__ void kp_kernel(const float* __restrict__ dm, const float* __restrict__ thr,
                          uint8_t* __restrict__ kp, int* __restrict__ haskp) {
  int t = blockIdx.x * blockDim.x + threadIdx.x;
  int b = blockIdx.y;
  if (t >= SEQ) return;
  const float* dmb = dm + (size_t)b * SEQ;
  float v = dmb[t];
  float tb = thr[b];
  float prev = (t > 0) ? dmb[t - 1] : -1.0f;
  float next = (t < SEQ - 1) ? dmb[t + 1] : -1.0f;
  bool k = (v > tb) && (v > prev) && (v > next);
  if (t == 0 || t == SEQ - 1) k = k || (v > tb);
  kp[(size_t)b * SEQ + t] = k ? 1 : 0;
  if (k) haskp[b] = 1;
}

__global__ void topk_kernel(const float* __restrict__ impn, uint8_t* __restrict__ colm,
                            uint32_t kg0, uint32_t kg1) {
  int rowid = blockIdx.x;
  int b = rowid >> 2, layer = rowid & 3;
  int j = threadIdx.x;
  float pv = impn[(size_t)b * SEQ + layer * 512 + j];
  float ssum = blockReduceSum(pv);
  uint32_t bits = jax_bits32(kg0, kg1, (uint32_t)(rowid * 512 + j));
  float f = __uint_as_float((bits >> 9) | 0x3F800000u) - 1.0f;
  float u = fmaxf(F32_TINY, f + F32_TINY);
  float g = -logf(-logf(u));
  float score = logf(pv / (ssum + 1e-6f) + 1e-20f) + g;
  __shared__ float sc[512];
  sc[j] = score;
  __syncthreads();
  for (int pick = 0; pick < 4; pick++) {
    if (j < 64) {
      float bv = -INFINITY; int bi = 0;
      #pragma unroll
      for (int q = 0; q < 8; q++) {
        int idx = j + q * 64;
        float v = sc[idx];
        if (v > bv) { bv = v; bi = idx; }
      }
      #pragma unroll
      for (int o = 1; o < 64; o <<= 1) {
        float ov = __shfl_xor(bv, o);
        int oi = __shfl_xor(bi, o);
        if (ov > bv || (ov == bv && oi < bi)) { bv = ov; bi = oi; }
      }
      if (j == 0) {
        colm[(size_t)b * SEQ + layer * 512 + bi] = 1;
        sc[bi] = -INFINITY;
      }
    }
    __syncthreads();
  }
}

DEVINL bool fbcol(int k) {
  return k == 0 || k == 511 || k == 1023 || k == 1535 || k == 2047;
}

__global__ __launch_bounds__(256) void maskbuild_kernel(
    const int* __restrict__ win, const uint8_t* __restrict__ kp,
    const uint8_t* __restrict__ colm, const int* __restrict__ haskp,
    u64* __restrict__ bits, int* __restrict__ cnt) {
  int q = blockIdx.x, b = blockIdx.y;
  int w = win[(size_t)b * SEQ + q];
  int hk = haskp[b];
  bool rowk = hk ? (kp[(size_t)b * SEQ + q] != 0) : fbcol(q);
  const uint8_t* kpb = kp + (size_t)b * SEQ;
  const uint8_t* cob = colm + (size_t)b * SEQ;
  int tid = threadIdx.x, wave = tid >> 6, lane = tid & 63;
  int local = 0;
  #pragma unroll
  for (int i = 0; i < 8; i++) {
    int k = i * 256 + tid;
    bool colk = hk ? (kpb[k] != 0) : fbcol(k);
    bool mmv = ((k >= q - w) && (k <= q + w)) || rowk || colk || (cob[k] != 0);
    u64 word = __ballot(mmv);
    if (lane == 0) bits[((size_t)b * 32 + (i * 4 + wave)) * 2048 + q] = word;
    local += mmv ? 1 : 0;
  }
  float tot = blockReduceSum((float)local);
  if (tid == 0) atomicAdd(&cnt[b], (int)tot);
}

__global__ void needed_kernel(const float* __restrict__ comp,
                              const int* __restrict__ cnt, int* __restrict__ needed) {
  if (threadIdx.x == 0 && blockIdx.x == 0) {
    float c0 = comp[0], c1 = comp[1];
    float cmin = fminf(c0, c1), cmax = fmaxf(c0, c1);
    for (int b = 0; b < BATCH; b++) {
      float nc = (comp[b] - cmin) / (cmax - cmin + 1e-6f);
      float ratio = fminf(fmaxf(0.3f * (0.5f + nc), 0.1f), 0.5f);
      float dens = (float)cnt[b] / 4194304.0f;
      float nd = ceilf((ratio - dens) * 4194304.0f);
      int n = (int)nd;
      needed[b] = n > 0 ? n : 0;
    }
  }
}

__global__ void fill_kernel(u64* __restrict__ bits, const int* __restrict__ needed,
                            uint32_t kq0, uint32_t kq1, uint32_t kk0, uint32_t kk1) {
  int gid = blockIdx.x * blockDim.x + threadIdx.x;
  int b = gid >> 21;
  int r = gid & (NRAND - 1);
  if (b >= BATCH) return;
  if (r >= needed[b]) return;
  uint32_t flat = 4194304u + (uint32_t)gid;
  uint32_t q = jax_bits32(kq0, kq1, flat) & 2047u;
  uint32_t k = jax_bits32(kk0, kk1, flat) & 2047u;
  atomicOr(&bits[((size_t)b * 32 + (k >> 6)) * 2048 + q], 1ull << (k & 63));
}

// ---------------- conversion: GEMM operand fragment-images ----------------
DEVINL void conv_one(const float* src, ushort* hi, ushort* lo, int nrows, int gid) {
  int row = gid >> 6, c8 = gid & 63;
  if (row >= nrows) return;
  const float* p = src + (size_t)row * 512 + c8 * 8;
  float4 v0 = ((const float4*)p)[0];
  float4 v1 = ((const float4*)p)[1];
  float xv[8] = {v0.x, v0.y, v0.z, v0.w, v1.x, v1.y, v1.z, v1.w};
  short8 hv, lv;
  #pragma unroll
  for (int j = 0; j < 8; j++) {
    ushort hh = f2bf(xv[j]);
    hv[j] = (short)hh;
    lv[j] = (short)f2bf(xv[j] - bf2f(hh));
  }
  int mb = row >> 7, rr = row & 127, kkc = c8 >> 2, qr = c8 & 3;
  size_t pos = ((size_t)(mb * 16 + kkc)) * 4096 + (((rr >> 4) * 4 + qr) * 16 + (rr & 15)) * 8;
  *(short8*)(hi + pos) = hv;
  if (lo) *(short8*)(lo + pos) = lv;
}

__global__ __launch_bounds__(256) void conv_img7(
    const float* s0, ushort* h0, ushort* l0, int n0,
    const float* s1, ushort* h1, ushort* l1, int n1,
    const float* s2, ushort* h2, ushort* l2, int n2,
    const float* s3, ushort* h3, ushort* l3, int n3,
    const float* s4, ushort* h4, ushort* l4, int n4,
    const float* s5, ushort* h5, ushort* l5, int n5,
    const float* s6, ushort* h6, ushort* l6, int n6) {
  const float* src; ushort* hi; ushort* lo; int nrows;
  switch (blockIdx.y) {
    case 0: src = s0; hi = h0; lo = l0; nrows = n0; break;
    case 1: src = s1; hi = h1; lo = l1; nrows = n1; break;
    case 2: src = s2; hi = h2; lo = l2; nrows = n2; break;
    case 3: src = s3; hi = h3; lo = l3; nrows = n3; break;
    case 4: src = s4; hi = h4; lo = l4; nrows = n4; break;
    case 5: src = s5; hi = h5; lo = l5; nrows = n5; break;
    default: src = s6; hi = h6; lo = l6; nrows = n6; break;
  }
  conv_one(src, hi, lo, nrows, blockIdx.x * 256 + threadIdx.x);
}

// ---------------- image-staged MFMA GEMM ----------------
// mode 0: C f32 (+resid). mode 1: write K attn image (hi+lo). mode 2: V image.
DEVINL void gemm_img_body(const ushort* __restrict__ Ahg, const ushort* __restrict__ Alg,
                          const ushort* __restrict__ Whg, const ushort* __restrict__ Wlg,
                          const float* __restrict__ bias, const float* __restrict__ resid,
                          float* __restrict__ C, ushort* __restrict__ oHi,
                          ushort* __restrict__ oLo, int split, int mode) {
  __shared__ __align__(16) ushort Ah[4096], Wh[4096], Al[4096], Wl[4096];
  int tid = threadIdx.x, wave = tid >> 6, lane = tid & 63;
  int mm = lane & 15, qr = lane >> 4;
  int wm = (wave >> 1) * 64, wn = (wave & 1) * 64;
  int bm = blockIdx.y * 128, bn = blockIdx.x * 128;
  float4v acc[4][4] = {};
  for (int kk = 0; kk < 16; kk++) {
    __syncthreads();
    {
      const short8* ga = (const short8*)(Ahg + ((size_t)((bm >> 7) * 16 + kk)) * 4096);
      const short8* gw = (const short8*)(Whg + ((size_t)((bn >> 7) * 16 + kk)) * 4096);
      ((short8*)Ah)[tid] = ga[tid];
      ((short8*)Ah)[tid + 256] = ga[tid + 256];
      ((short8*)Wh)[tid] = gw[tid];
      ((short8*)Wh)[tid + 256] = gw[tid + 256];
      if (split) {
        const short8* ga2 = (const short8*)(Alg + ((size_t)((bm >> 7) * 16 + kk)) * 4096);
        const short8* gw2 = (const short8*)(Wlg + ((size_t)((bn >> 7) * 16 + kk)) * 4096);
        ((short8*)Al)[tid] = ga2[tid];
        ((short8*)Al)[tid + 256] = ga2[tid + 256];
        ((short8*)Wl)[tid] = gw2[tid];
        ((short8*)Wl)[tid + 256] = gw2[tid + 256];
      }
    }
    __syncthreads();
    short8 ah[4], bh[4];
    #pragma unroll
    for (int mt = 0; mt < 4; mt++)
      ah[mt] = ((short8*)Ah)[(((wm >> 4) + mt) * 4 + qr) * 16 + mm];
    #pragma unroll
    for (int nt = 0; nt < 4; nt++)
      bh[nt] = ((short8*)Wh)[(((wn >> 4) + nt) * 4 + qr) * 16 + mm];
    if (split) {
      short8 al[4], bl[4];
      #pragma unroll
      for (int mt = 0; mt < 4; mt++)
        al[mt] = ((short8*)Al)[(((wm >> 4) + mt) * 4 + qr) * 16 + mm];
      #pragma unroll
      for (int nt = 0; nt < 4; nt++)
        bl[nt] = ((short8*)Wl)[(((wn >> 4) + nt) * 4 + qr) * 16 + mm];
      #pragma unroll
      for (int mt = 0; mt < 4; mt++)
        #pragma unroll
        for (int nt = 0; nt < 4; nt++) {
          acc[mt][nt] = MFMA(al[mt], bh[nt], acc[mt][nt]);
          acc[mt][nt] = MFMA(ah[mt], bl[nt], acc[mt][nt]);
          acc[mt][nt] = MFMA(ah[mt], bh[nt], acc[mt][nt]);
        }
    } else {
      #pragma unroll
      for (int mt = 0; mt < 4; mt++)
        #pragma unroll
        for (int nt = 0; nt < 4; nt++)
          acc[mt][nt] = MFMA(ah[mt], bh[nt], acc[mt][nt]);
    }
  }
  #pragma unroll
  for (int mt = 0; mt < 4; mt++)
    #pragma unroll
    for (int nt = 0; nt < 4; nt++) {
      int n = bn + wn + nt * 16 + mm;
      float bsv = bias[n];
      #pragma unroll
      for (int reg = 0; reg < 4; reg++) {
        int m = bm + wm + mt * 16 + qr * 4 + reg;
        float v = acc[mt][nt][reg] + bsv;
        if (mode == 0) {
          if (resid) v += resid[(size_t)m * 512 + n];
          C[(size_t)m * 512 + n] = v;
        } else if (mode == 1) {
          ushort hh = f2bf(v);
          ushort ll = f2bf(v - bf2f(hh));
          int b2 = m >> 11, sq = m & 2047, t = sq >> 6, r = sq & 63;
          int h2 = n >> 6, d = n & 63;
          size_t pos = ((size_t)((b2 * 8 + h2) * 32 + t)) * 4096
                     + ((((r >> 4) * 2 + (d >> 5)) * 4 + ((d >> 3) & 3)) * 16 + (r & 15)) * 8
                     + (d & 7);
          oHi[pos] = hh; oLo[pos] = ll;
        } else {
          ushort hh = f2bf(v);
          int b2 = m >> 11, sq = m & 2047, t = sq >> 6, k = sq & 63, k8 = k >> 3;
          int h2 = n >> 6, d = n & 63;
          size_t pos = ((size_t)((b2 * 8 + h2) * 32 + t)) * 4096
                     + ((((k8 >> 2) * 4 + (d >> 4)) * 4 + (k8 & 3)) * 16 + (d & 15)) * 8
                     + (k & 7);
          oHi[pos] = hh;
        }
      }
    }
}

__global__ __launch_bounds__(256) void mfma_gemm_img3(
    const ushort* A0h, const ushort* A0l, const ushort* W0h, const ushort* W0l,
    const float* b0, const float* r0, float* C0, ushort* o0h, ushort* o0l, int s0, int m0,
    const ushort* A1h, const ushort* A1l, const ushort* W1h, const ushort* W1l,
    const float* b1, const float* r1, float* C1, ushort* o1h, ushort* o1l, int s1, int m1,
    const ushort* A2h, const ushort* A2l, const ushort* W2h, const ushort* W2l,
    const float* b2, const float* r2, float* C2, ushort* o2h, ushort* o2l, int s2, int m2) {
  if (blockIdx.z == 0)      gemm_img_body(A0h, A0l, W0h, W0l, b0, r0, C0, o0h, o0l, s0, m0);
  else if (blockIdx.z == 1) gemm_img_body(A1h, A1l, W1h, W1l, b1, r1, C1, o1h, o1l, s1, m1);
  else                      gemm_img_body(A2h, A2l, W2h, W2l, b2, r2, C2, o2h, o2l, s2, m2);
}

// ---------------- barrier-free MFMA flash attention ----------------
// 32 q-rows per block; waves partition the 32 key-tiles (8 each, interleaved);
// K/V fragments loaded register-direct from pre-imaged global arrays; exact
// flash-merge across waves at the end.
__global__ __launch_bounds__(256) void attn_mfma(
    const float* __restrict__ Qb, const ushort* __restrict__ Khig,
    const ushort* __restrict__ Klog, const ushort* __restrict__ Vimg,
    const u64* __restrict__ bits, ushort* __restrict__ Oimg) {
  int qt = blockIdx.x, h = blockIdx.y, b = blockIdx.z;
  __shared__ __align__(16) char arena[33 * 1024 + 768];
  float* LO = (float*)arena;                        // [4*32][64] (merge phase)
  float* Lm = (float*)(arena + 32 * 1024);          // [4*32]
  float* Ll = (float*)(arena + 32 * 1024 + 512);    // [4*32]
  int tid = threadIdx.x, wave = tid >> 6, lane = tid & 63;
  int mm = lane & 15, qr = lane >> 4;
  int q0 = qt * 32;
  ushort* pw = (ushort*)arena + wave * 2048;        // wave-private P (main loop)

  // Q fragments: hi/lo, mt (16-row tiles) x dc (k-chunks of 32)
  short8 aqh[2][2], aql[2][2];
  #pragma unroll
  for (int mt = 0; mt < 2; mt++) {
    const float* qp = Qb + ((size_t)(b * SEQ + q0 + mt * 16 + mm)) * 512 + h * 64 + qr * 8;
    #pragma unroll
    for (int dc = 0; dc < 2; dc++) {
      float4 v0 = ((const float4*)(qp + dc * 32))[0];
      float4 v1 = ((const float4*)(qp + dc * 32))[1];
      float xv[8] = {v0.x, v0.y, v0.z, v0.w, v1.x, v1.y, v1.z, v1.w};
      #pragma unroll
      for (int j = 0; j < 8; j++) {
        ushort hh = f2bf(xv[j]);
        aqh[mt][dc][j] = (short)hh;
        aql[mt][dc][j] = (short)f2bf(xv[j] - bf2f(hh));
      }
    }
  }
  float4v accO[2][4] = {};
  float m_i[2][4], l_i[2][4];
  #pragma unroll
  for (int mt = 0; mt < 2; mt++)
    #pragma unroll
    for (int r = 0; r < 4; r++) { m_i[mt][r] = -INFINITY; l_i[mt][r] = 0.f; }
  size_t kvbase = ((size_t)((b * 8 + h) * 32)) * 4096;
  const u64* bitp = bits + (size_t)b * 32 * 2048 + q0;

  #pragma unroll 2
  for (int it = 0; it < 8; it++) {
    int kc = it * 4 + wave;
    const short8* kh = (const short8*)(Khig + kvbase + (size_t)kc * 4096);
    const short8* kl = (const short8*)(Klog + kvbase + (size_t)kc * 4096);
    const short8* vv = (const short8*)(Vimg + kvbase + (size_t)kc * 4096);
    u64 mrow[2][4];
    #pragma unroll
    for (int mt = 0; mt < 2; mt++)
      #pragma unroll
      for (int reg = 0; reg < 4; reg++)
        mrow[mt][reg] = bitp[(size_t)kc * 2048 + mt * 16 + qr * 4 + reg];
    // QK^T (split bf16)
    float4v S[2][4];
    #pragma unroll
    for (int ct = 0; ct < 4; ct++) {
      short8 kh0 = kh[((ct * 2 + 0) * 4 + qr) * 16 + mm];
      short8 kh1 = kh[((ct * 2 + 1) * 4 + qr) * 16 + mm];
      short8 kl0 = kl[((ct * 2 + 0) * 4 + qr) * 16 + mm];
      short8 kl1 = kl[((ct * 2 + 1) * 4 + qr) * 16 + mm];
      #pragma unroll
      for (int mt = 0; mt < 2; mt++) {
        float4v s = {};
        s = MFMA(aql[mt][0], kh0, s);
        s = MFMA(aqh[mt][0], kl0, s);
        s = MFMA(aqh[mt][0], kh0, s);
        s = MFMA(aql[mt][1], kh1, s);
        s = MFMA(aqh[mt][1], kl1, s);
        s = MFMA(aqh[mt][1], kh1, s);
        S[mt][ct] = s;
      }
    }
    // V fragments
    short8 vf[2][4];
    #pragma unroll
    for (int kc2 = 0; kc2 < 2; kc2++)
      #pragma unroll
      for (int dt = 0; dt < 4; dt++)
        vf[kc2][dt] = vv[((kc2 * 4 + dt) * 4 + qr) * 16 + mm];
    // scale + mask + online softmax; P -> wave-private LDS
    #pragma unroll
    for (int mt = 0; mt < 2; mt++) {
      #pragma unroll
      for (int reg = 0; reg < 4; reg++) {
        float sv[4];
        float mx = -INFINITY;
        #pragma unroll
        for (int ct = 0; ct < 4; ct++) {
          float s = S[mt][ct][reg] * 0.125f;
          if ((mrow[mt][reg] >> (ct * 16 + mm)) & 1ull) s = NEG_MAX;
          sv[ct] = s;
          mx = fmaxf(mx, s);
        }
        #pragma unroll
        for (int o = 1; o < 16; o <<= 1) mx = fmaxf(mx, __shfl_xor(mx, o));
        float mn = fmaxf(m_i[mt][reg], mx);
        float p[4];
        float ps = 0.f;
        #pragma unroll
        for (int ct = 0; ct < 4; ct++) {
          p[ct] = __expf(sv[ct] - mn);
          ps += p[ct];
        }
        #pragma unroll
        for (int o = 1; o < 16; o <<= 1) ps += __shfl_xor(ps, o);
        float alpha = __expf(m_i[mt][reg] - mn);
        l_i[mt][reg] = l_i[mt][reg] * alpha + ps;
        m_i[mt][reg] = mn;
        #pragma unroll
        for (int dt = 0; dt < 4; dt++) accO[mt][dt][reg] *= alpha;
        int j = mm & 7;
        #pragma unroll
        for (int ct = 0; ct < 4; ct++) {
          int kc2 = ct >> 1;
          int qf = (2 * ct + (mm >> 3)) & 3;
          int blk = kc2 * 64 + qf * 16 + (qr * 4 + reg);
          blk ^= (blk >> 3) & 3;
          pw[mt * 1024 + blk * 8 + j] = f2bf(p[ct]);
        }
      }
    }
    // PV (plain bf16)
    #pragma unroll
    for (int mt = 0; mt < 2; mt++)
      #pragma unroll
      for (int kc2 = 0; kc2 < 2; kc2++) {
        int blk = kc2 * 64 + qr * 16 + mm;
        blk ^= (blk >> 3) & 3;
        short8 ap = *(const short8*)(pw + mt * 1024 + blk * 8);
        #pragma unroll
        for (int dt = 0; dt < 4; dt++)
          accO[mt][dt] = MFMA(ap, vf[kc2][dt], accO[mt][dt]);
      }
  }
  // ---- exact flash merge across the 4 waves ----
  __syncthreads();
  #pragma unroll
  for (int mt = 0; mt < 2; mt++)
    #pragma unroll
    for (int reg = 0; reg < 4; reg++) {
      int r = mt * 16 + qr * 4 + reg;
      if (mm == 0) {
        Lm[wave * 32 + r] = m_i[mt][reg];
        Ll[wave * 32 + r] = l_i[mt][reg];
      }
      #pragma unroll
      for (int dt = 0; dt < 4; dt++)
        LO[(size_t)(wave * 32 + r) * 64 + dt * 16 + mm] = accO[mt][dt][reg];
    }
  __syncthreads();
  int row = tid >> 3, c0 = (tid & 7) * 8;
  float M = Lm[row];
  #pragma unroll
  for (int w = 1; w < 4; w++) M = fmaxf(M, Lm[w * 32 + row]);
  float fw[4], l = 0.f;
  #pragma unroll
  for (int w = 0; w < 4; w++) {
    fw[w] = __expf(Lm[w * 32 + row] - M);
    l += fw[w] * Ll[w * 32 + row];
  }
  float o[8] = {};
  #pragma unroll
  for (int w = 0; w < 4; w++) {
    const float* lob = LO + (size_t)(w * 32 + row) * 64 + c0;
    #pragma unroll
    for (int c = 0; c < 8; c++) o[c] += fw[w] * lob[c];
  }
  float invl = 1.0f / l;
  short8 o8;
  #pragma unroll
  for (int c = 0; c < 8; c++) o8[c] = (short)f2bf(o[c] * invl);
  int rowg = b * SEQ + q0 + row;
  int col = h * 64 + c0;
  int mb = rowg >> 7, rr = rowg & 127, kkc = col >> 5, qrk = (col >> 3) & 3;
  *(short8*)(Oimg + ((size_t)(mb * 16 + kkc)) * 4096
             + (((rr >> 4) * 4 + qrk) * 16 + (rr & 15)) * 8) = o8;
}

// ---------------- launcher ----------------
extern "C" void kernel_launch(void* const* d_in, const int* in_sizes, int n_in,
                              void* d_out, int out_size, void* d_ws, size_t ws_size,
                              hipStream_t stream) {
  (void)in_sizes; (void)n_in; (void)out_size; (void)ws_size;
  const float* queries = (const float*)d_in[0];
  const float* keys    = (const float*)d_in[1];
  const float* values  = (const float*)d_in[2];
  const float* ln_q_g  = (const float*)d_in[3];
  const float* ln_q_b  = (const float*)d_in[4];
  const float* ln_k_g  = (const float*)d_in[5];
  const float* ln_k_b  = (const float*)d_in[6];
  const float* ln_v_g  = (const float*)d_in[7];
  const float* ln_v_b  = (const float*)d_in[8];
  const float* Wq = (const float*)d_in[9];  const float* bq = (const float*)d_in[10];
  const float* Wk = (const float*)d_in[11]; const float* bk = (const float*)d_in[12];
  const float* Wv = (const float*)d_in[13]; const float* bv = (const float*)d_in[14];
  const float* Wo = (const float*)d_in[15]; const float* bo = (const float*)d_in[16];
  const float* Ww1 = (const float*)d_in[17]; const float* bw1 = (const float*)d_in[18];
  const float* Ww2 = (const float*)d_in[19]; const float* bw2 = (const float*)d_in[20];

  char* ws = (char*)d_ws;
  const size_t MB = 1u << 20;
  float* qn      = (float*)(ws + 0 * MB);    // 8 MB; front 4 MB reused as Oimg
  float* kn      = (float*)(ws + 8 * MB);    // 8 MB
  float* vn      = (float*)(ws + 16 * MB);   // 8 MB
  float* Qb      = (float*)(ws + 24 * MB);   // 8 MB
  ushort* qnh    = (ushort*)(ws + 32 * MB);  // 4 MB each
  ushort* qnl    = (ushort*)(ws + 36 * MB);
  ushort* knh    = (ushort*)(ws + 40 * MB);
  ushort* knl    = (ushort*)(ws + 44 * MB);
  ushort* vnh    = (ushort*)(ws + 48 * MB);
  ushort* Wqh    = (ushort*)(ws + 52 * MB);  // 0.5 MB each
  ushort* Wql    = (ushort*)(ws + 52 * MB + 524288);
  ushort* Wkh    = (ushort*)(ws + 53 * MB);
  ushort* Wkl    = (ushort*)(ws + 53 * MB + 524288);
  ushort* Wvh    = (ushort*)(ws + 54 * MB);
  ushort* Woh    = (ushort*)(ws + 54 * MB + 524288);
  ushort* Kth    = (ushort*)(ws + 55 * MB);  // 4 MB
  ushort* Ktl    = (ushort*)(ws + 59 * MB);  // 4 MB
  ushort* Vt     = (ushort*)(ws + 63 * MB);  // 4 MB
  u64*    bits   = (u64*)(ws + 67 * MB);     // 1 MB
  float*  hidden = (float*)(ws + 68 * MB);   // 2 MB
  char* st = ws + 70 * MB;
  float* dm     = (float*)st; st += NROWS * 4;
  float* mag    = (float*)st; st += NROWS * 4;
  float* ch     = (float*)st; st += NROWS * 4;
  float* rowvar = (float*)st; st += NROWS * 4;
  float* impn   = (float*)st; st += NROWS * 4;
  int*   win    = (int*)st;   st += NROWS * 4;
  uint8_t* kp   = (uint8_t*)st; st += NROWS;
  uint8_t* colm = (uint8_t*)st; st += NROWS;
  float* thr    = (float*)st; st += 2 * 4;
  float* comp   = (float*)st; st += 2 * 4;
  int* cnt      = (int*)st;   st += 2 * 4;
  int* haskp    = (int*)st;   st += 2 * 4;
  int* needed   = (int*)st;   st += 2 * 4;
  ushort* Oimg = (ushort*)qn;   // qn dead after conv_img7/dmstats/hidden

  uint32_t kg0, kg1, kq0, kq1, kk0, kk1;
  tf2x32(0u, 42u, 0u, 0u, &kg0, &kg1);
  tf2x32(0u, 42u, 0u, 1u, &kq0, &kq1);
  tf2x32(0u, 42u, 0u, 2u, &kk0, &kk1);

  init_kernel<<<16, 256, 0, stream>>>(colm, cnt, haskp);
  dim3 gln(NROWS, 3);
  ln3_kernel<<<gln, 256, 0, stream>>>(queries, keys, values,
                                      ln_q_g, ln_q_b, ln_k_g, ln_k_b, ln_v_g, ln_v_b,
                                      qn, kn, vn);

  // mask-critical path (exact f32)
  dim3 g128(2, 256);
  gemm_f32<<<g128, 256, 0, stream>>>(qn, Ww1, bw1, hidden, 128, 1);
  win_kernel<<<NROWS, 128, 0, stream>>>(hidden, Ww2, bw2, win);
  dim3 gdm(SEQ, BATCH);
  dmstats_kernel<<<gdm, 256, 0, stream>>>(qn, dm, mag, ch, rowvar);
  batchstats_kernel<<<BATCH, 256, 0, stream>>>(dm, mag, ch, rowvar, impn, thr, comp);
  dim3 gkp(SEQ / 256, BATCH);
  kp_kernel<<<gkp, 256, 0, stream>>>(dm, thr, kp, haskp);
  topk_kernel<<<8, 512, 0, stream>>>(impn, colm, kg0, kg1);

  // operand images
  dim3 gc7(1024, 7);
  conv_img7<<<gc7, 256, 0, stream>>>(
      qn, qnh, qnl, NROWS,
      kn, knh, knl, NROWS,
      vn, vnh, (ushort*)nullptr, NROWS,
      Wq, Wqh, Wql, 512,
      Wk, Wkh, Wkl, 512,
      Wv, Wvh, (ushort*)nullptr, 512,
      Wo, Woh, (ushort*)nullptr, 512);

  // Q/K/V projections; K/V write attention images directly in the epilogue
  dim3 gqkv(4, 32, 3);
  mfma_gemm_img3<<<gqkv, 256, 0, stream>>>(
      qnh, qnl, Wqh, Wql, bq, nullptr, Qb, nullptr, nullptr, 1, 0,
      knh, knl, Wkh, Wkl, bk, nullptr, nullptr, Kth, Ktl, 1, 1,
      vnh, nullptr, Wvh, nullptr, bv, nullptr, nullptr, Vt, nullptr, 0, 2);

  dim3 gmb(SEQ, BATCH);
  maskbuild_kernel<<<gmb, 256, 0, stream>>>(win, kp, colm, haskp, bits, cnt);
  needed_kernel<<<1, 64, 0, stream>>>(comp, cnt, needed);
  fill_kernel<<<(2 * NRAND) / 256, 256, 0, stream>>>(bits, needed, kq0, kq1, kk0, kk1);

  dim3 gat(SEQ / 32, NHEAD, BATCH);
  attn_mfma<<<gat, 256, 0, stream>>>(Qb, Kth, Ktl, Vt, bits, Oimg);

  // output projection (plain bf16) + residual
  dim3 go(4, 32, 1);
  mfma_gemm_img3<<<go, 256, 0, stream>>>(
      Oimg, nullptr, Woh, nullptr, bo, queries, (float*)d_out, nullptr, nullptr, 0, 0,
      Oimg, nullptr, Woh, nullptr, bo, queries, (float*)d_out, nullptr, nullptr, 0, 0,
      Oimg, nullptr, Woh, nullptr, bo, queries, (float*)d_out, nullptr, nullptr, 0, 0);
}

// Round 5
// 374.127 us; speedup vs baseline: 3.3944x; 1.0756x over previous
//
#include <hip/hip_runtime.h>
#include <stdint.h>
#include <math.h>

#define DEVINL __device__ __forceinline__

constexpr int SEQ = 2048;
constexpr int DIM = 512;
constexpr int BATCH = 2;
constexpr int NROWS = BATCH * SEQ;        // 4096
constexpr int NRAND = (SEQ * SEQ) / 2;    // 2^21
constexpr float NEG_MAX = -3.402823466e38f;   // jnp.finfo(f32).min
constexpr float F32_TINY = 1.1754943508222875e-38f;

typedef float float4v __attribute__((ext_vector_type(4)));
typedef short short8 __attribute__((ext_vector_type(8)));
typedef unsigned long long u64;

DEVINL float4v MFMA(short8 a, short8 b, float4v c) {
  return __builtin_amdgcn_mfma_f32_16x16x32_bf16(a, b, c, 0, 0, 0);
}

DEVINL ushort f2bf(float x) {
  uint32_t u = __float_as_uint(x);
  return (ushort)((u + 0x7FFFu + ((u >> 16) & 1u)) >> 16);
}

// ---------------- threefry2x32 (JAX-compatible) ----------------
__host__ __device__ inline void tf2x32(uint32_t k0, uint32_t k1,
                                       uint32_t x0, uint32_t x1,
                                       uint32_t* o0, uint32_t* o1) {
  uint32_t ks2 = k0 ^ k1 ^ 0x1BD11BDAu;
  x0 += k0; x1 += k1;
#define TFR(r) { x0 += x1; x1 = (x1 << (r)) | (x1 >> (32 - (r))); x1 ^= x0; }
  TFR(13) TFR(15) TFR(26) TFR(6)
  x0 += k1; x1 += ks2 + 1u;
  TFR(17) TFR(29) TFR(16) TFR(24)
  x0 += ks2; x1 += k0 + 2u;
  TFR(13) TFR(15) TFR(26) TFR(6)
  x0 += k0; x1 += k1 + 3u;
  TFR(17) TFR(29) TFR(16) TFR(24)
  x0 += k1; x1 += ks2 + 4u;
  TFR(13) TFR(15) TFR(26) TFR(6)
  x0 += ks2; x1 += k0 + 5u;
#undef TFR
  *o0 = x0; *o1 = x1;
}

DEVINL uint32_t jax_bits32(uint32_t k0, uint32_t k1, uint32_t idx) {
  uint32_t a, b;
  tf2x32(k0, k1, 0u, idx, &a, &b);
  return a ^ b;
}

// ---------------- block reductions ----------------
DEVINL float blockReduceSum(float v) {
  __shared__ float sh[16];
  __syncthreads();
  int lane = threadIdx.x & 63, wid = threadIdx.x >> 6;
  #pragma unroll
  for (int o = 32; o > 0; o >>= 1) v += __shfl_down(v, o);
  if (lane == 0) sh[wid] = v;
  __syncthreads();
  if (threadIdx.x == 0) {
    int nw = ((int)blockDim.x + 63) >> 6;
    float s = 0.f;
    for (int i = 0; i < nw; i++) s += sh[i];
    sh[0] = s;
  }
  __syncthreads();
  return sh[0];
}

DEVINL float blockReduceMin(float v) {
  __shared__ float sh[16];
  __syncthreads();
  int lane = threadIdx.x & 63, wid = threadIdx.x >> 6;
  #pragma unroll
  for (int o = 32; o > 0; o >>= 1) v = fminf(v, __shfl_down(v, o));
  if (lane == 0) sh[wid] = v;
  __syncthreads();
  if (threadIdx.x == 0) {
    int nw = ((int)blockDim.x + 63) >> 6;
    float s = sh[0];
    for (int i = 1; i < nw; i++) s = fminf(s, sh[i]);
    sh[0] = s;
  }
  __syncthreads();
  return sh[0];
}

DEVINL float blockReduceMax(float v) {
  __shared__ float sh[16];
  __syncthreads();
  int lane = threadIdx.x & 63, wid = threadIdx.x >> 6;
  #pragma unroll
  for (int o = 32; o > 0; o >>= 1) v = fmaxf(v, __shfl_down(v, o));
  if (lane == 0) sh[wid] = v;
  __syncthreads();
  if (threadIdx.x == 0) {
    int nw = ((int)blockDim.x + 63) >> 6;
    float s = sh[0];
    for (int i = 1; i < nw; i++) s = fmaxf(s, sh[i]);
    sh[0] = s;
  }
  __syncthreads();
  return sh[0];
}

// A-image layout (GEMM A/W operand): chunk (row>>7, k>>5) of 4096 ushorts
DEVINL void store_img_scalar(ushort* img, int row, int d, float v) {
  size_t idx = ((size_t)((row >> 7) * 16 + (d >> 5))) * 4096
             + ((((row & 127) >> 4) * 4 + ((d >> 3) & 3)) * 16 + (row & 15)) * 8 + (d & 7);
  img[idx] = f2bf(v);
}

// ---------------- ln3: LayerNorm ×3 + bf16 image emit ----------------
__global__ __launch_bounds__(256) void ln3_kernel(
    const float* __restrict__ xq, const float* __restrict__ xk, const float* __restrict__ xv,
    const float* __restrict__ gq, const float* __restrict__ bq2,
    const float* __restrict__ gk, const float* __restrict__ bk2,
    const float* __restrict__ gv, const float* __restrict__ bv2,
    float* __restrict__ oq, ushort* __restrict__ iq, ushort* __restrict__ ik,
    ushort* __restrict__ iv) {
  const float *x, *g, *bb; ushort* img;
  if (blockIdx.y == 0)      { x = xq; g = gq; bb = bq2; img = iq; }
  else if (blockIdx.y == 1) { x = xk; g = gk; bb = bk2; img = ik; }
  else                      { x = xv; g = gv; bb = bv2; img = iv; }
  int row = blockIdx.x;
  const float* xr = x + (size_t)row * DIM;
  int t = threadIdx.x;
  float v0 = xr[t], v1 = xr[t + 256];
  float mu = blockReduceSum(v0 + v1) * (1.0f / 512.0f);
  float d0 = v0 - mu, d1 = v1 - mu;
  float var = blockReduceSum(d0 * d0 + d1 * d1) * (1.0f / 512.0f);
  float inv = 1.0f / sqrtf(var + 1e-5f);
  float r0 = d0 * inv * g[t] + bb[t];
  float r1 = d1 * inv * g[t + 256] + bb[t + 256];
  if (blockIdx.y == 0) {
    oq[(size_t)row * DIM + t] = r0;
    oq[(size_t)row * DIM + t + 256] = r1;
  }
  store_img_scalar(img, row, t, r0);
  store_img_scalar(img, row, t + 256, r1);
}

// ---------------- mask-critical f32 bodies (bit-exact, unchanged math) ----------------
DEVINL void gemm_f32_body(const float* __restrict__ A, const float* __restrict__ W,
                          const float* __restrict__ bias, float* __restrict__ C,
                          int bx, int by) {
  __shared__ float As[16][17];
  __shared__ float Ws[16][68];
  int bm = by * 16, bn = bx * 64;
  int tid = threadIdx.x;
  int tx = tid & 15, ty = tid >> 4;
  int lk = tid & 15, lm = tid >> 4;
  float acc[4] = {0.f, 0.f, 0.f, 0.f};
  for (int kk = 0; kk < DIM; kk += 16) {
    __syncthreads();
    As[lk][lm] = A[(size_t)(bm + lm) * DIM + kk + lk];
    #pragma unroll
    for (int i = 0; i < 4; i++)
      Ws[lk][lm + i * 16] = W[(size_t)(bn + lm + i * 16) * DIM + kk + lk];
    __syncthreads();
    #pragma unroll
    for (int k = 0; k < 16; k++) {
      float a = As[k][ty];
      float4 w4 = *(const float4*)&Ws[k][tx * 4];
      acc[0] += a * w4.x; acc[1] += a * w4.y;
      acc[2] += a * w4.z; acc[3] += a * w4.w;
    }
  }
  int m = bm + ty;
  #pragma unroll
  for (int j = 0; j < 4; j++) {
    int n = bn + tx * 4 + j;
    float v = acc[j] + bias[n];
    v = fmaxf(v, 0.f);
    C[(size_t)m * 128 + n] = v;
  }
}

DEVINL void dmstats_body(const float* __restrict__ qn, float* __restrict__ dm,
                         float* __restrict__ mag, float* __restrict__ ch,
                         float* __restrict__ rowvar, int t, int b) {
  const float* x = qn + ((size_t)b * SEQ + t) * DIM;
  int tid = threadIdx.x;
  float sx = 0, sq = 0, sdm = 0, sch = 0;
  float xs[2];
  #pragma unroll
  for (int i = 0; i < 2; i++) {
    int d = tid + i * 256;
    float xv = x[d]; xs[i] = xv;
    sx += xv; sq += xv * xv;
    float acc = 0.f;
    if (t + 1 < SEQ) { float df = fabsf(x[1 * DIM + d] - xv); acc += 0.4f * (df / 1.0f); sch += df; }
    if (t + 2 < SEQ) { float df = fabsf(x[2 * DIM + d] - xv); acc += 0.3f * (df / 2.0f); }
    if (t + 3 < SEQ) { float df = fabsf(x[3 * DIM + d] - xv); acc += 0.2f * (df / 3.0f); }
    if (t + 5 < SEQ) { float df = fabsf(x[5 * DIM + d] - xv); acc += 0.1f * (df / 5.0f); }
    sdm += acc;
  }
  float mu = blockReduceSum(sx) * (1.0f / 512.0f);
  float sv = 0;
  #pragma unroll
  for (int i = 0; i < 2; i++) { float dd = xs[i] - mu; sv += dd * dd; }
  float totsq = blockReduceSum(sq);
  float totdm = blockReduceSum(sdm);
  float totch = blockReduceSum(sch);
  float totsv = blockReduceSum(sv);
  if (tid == 0) {
    size_t idx = (size_t)b * SEQ + t;
    dm[idx] = totdm / 512.0f;
    mag[idx] = sqrtf(totsq);
    ch[idx] = (t + 1 < SEQ) ? (totch / 512.0f) : 0.f;
    rowvar[idx] = totsv / 511.0f;
  }
}

DEVINL void conv_w_hi(const float* __restrict__ src, ushort* __restrict__ dst, int gid) {
  int row = gid >> 6, c8 = gid & 63;
  const float* p = src + (size_t)row * 512 + c8 * 8;
  float4 v0 = ((const float4*)p)[0];
  float4 v1 = ((const float4*)p)[1];
  float xv[8] = {v0.x, v0.y, v0.z, v0.w, v1.x, v1.y, v1.z, v1.w};
  short8 hv;
  #pragma unroll
  for (int j = 0; j < 8; j++) hv[j] = (short)f2bf(xv[j]);
  int mb = row >> 7, rr = row & 127, kkc = c8 >> 2, qrr = c8 & 3;
  ((short8*)dst)[(mb * 16 + kkc) * 512 + ((rr >> 4) * 4 + qrr) * 16 + (rr & 15)] = hv;
}

// mega1: gemm_f32(512) | dmstats(4096) | weight conv(512) | init(1)
__global__ __launch_bounds__(256) void mega1_kernel(
    const float* qn, const float* Ww1, const float* bw1, float* hidden,
    float* dm, float* mag, float* ch, float* rowvar,
    const float* Wq, const float* Wk, const float* Wv, const float* Wo,
    ushort* Wqh, ushort* Wkh, ushort* Wvh, ushort* Woh,
    uint8_t* colm, int* cnt, int* haskp) {
  int bid = blockIdx.x;
  if (bid < 512) {
    gemm_f32_body(qn, Ww1, bw1, hidden, bid & 1, bid >> 1);
  } else if (bid < 4608) {
    int r = bid - 512;
    dmstats_body(qn, dm, mag, ch, rowvar, r & 2047, r >> 11);
  } else if (bid < 5120) {
    int r = bid - 4608;
    const float* s; ushort* d;
    switch (r >> 7) {
      case 0: s = Wq; d = Wqh; break;
      case 1: s = Wk; d = Wkh; break;
      case 2: s = Wv; d = Wvh; break;
      default: s = Wo; d = Woh; break;
    }
    conv_w_hi(s, d, (r & 127) * 256 + (int)threadIdx.x);
  } else {
    int tid = threadIdx.x;
    for (int i = tid; i < BATCH * SEQ; i += 256) colm[i] = 0;
    if (tid < BATCH) { cnt[tid] = 0; haskp[tid] = 0; }
  }
}

// mega2: win(4096, 256-thr zero-padded — bitwise-identical sum) | batchstats(2)
DEVINL void win_body(const float* __restrict__ hidden, const float* __restrict__ Ww2,
                     const float* __restrict__ bw2, int* __restrict__ win, int row) {
  int t = threadIdx.x;
  float v = (t < 128) ? hidden[(size_t)row * 128 + t] * Ww2[t] : 0.f;
  v = blockReduceSum(v);
  if (t == 0) {
    float y = v + bw2[0];
    float sig = 1.0f / (1.0f + expf(-y));
    float adj = 0.5f + sig;
    int w = (int)rintf(64.0f * adj);
    w = w < 1 ? 1 : (w > 128 ? 128 : w);
    win[row] = w;
  }
}

DEVINL void batchstats_body(const float* __restrict__ dm, const float* __restrict__ mag,
                            const float* __restrict__ ch, const float* __restrict__ rowvar,
                            float* __restrict__ impn, float* __restrict__ thr,
                            float* __restrict__ comp, int b) {
  int tid = threadIdx.x;
  float sdm = 0, srv = 0, lo = INFINITY, hi = -INFINITY;
  for (int t = tid; t < SEQ; t += 256) {
    size_t idx = (size_t)b * SEQ + t;
    sdm += dm[idx];
    srv += rowvar[idx];
    float imp = 0.5f * mag[idx] + 0.5f * ch[idx];
    lo = fminf(lo, imp); hi = fmaxf(hi, imp);
  }
  float meandm = blockReduceSum(sdm) * (1.0f / 2048.0f);
  float compv = blockReduceSum(srv) * (1.0f / 2048.0f);
  lo = blockReduceMin(lo);
  hi = blockReduceMax(hi);
  float sv = 0;
  for (int t = tid; t < SEQ; t += 256) {
    float d2 = dm[(size_t)b * SEQ + t] - meandm;
    sv += d2 * d2;
  }
  float var = blockReduceSum(sv) / 2047.0f;
  for (int t = tid; t < SEQ; t += 256) {
    size_t idx = (size_t)b * SEQ + t;
    float imp = 0.5f * mag[idx] + 0.5f * ch[idx];
    impn[idx] = (imp - lo) / (hi - lo + 1e-6f);
  }
  if (tid == 0) { thr[b] = meandm + 0.5f * sqrtf(var); comp[b] = compv; }
}

__global__ __launch_bounds__(256) void mega2_kernel(
    const float* hidden, const float* Ww2, const float* bw2, int* win,
    const float* dm, const float* mag, const float* ch, const float* rowvar,
    float* impn, float* thr, float* comp) {
  int bid = blockIdx.x;
  if (bid < 4096) win_body(hidden, Ww2, bw2, win, bid);
  else batchstats_body(dm, mag, ch, rowvar, impn, thr, comp, bid - 4096);
}

// mega3 (512 threads): kp(8) | topk(8)
__global__ __launch_bounds__(512) void mega3_kernel(
    const float* __restrict__ dm, const float* __restrict__ thr,
    uint8_t* __restrict__ kp, int* __restrict__ haskp,
    const float* __restrict__ impn, uint8_t* __restrict__ colm,
    uint32_t kg0, uint32_t kg1) {
  int bid = blockIdx.x;
  if (bid < 8) {
    int b = bid >> 2;
    int t = (bid & 3) * 512 + (int)threadIdx.x;
    const float* dmb = dm + (size_t)b * SEQ;
    float v = dmb[t];
    float tb = thr[b];
    float prev = (t > 0) ? dmb[t - 1] : -1.0f;
    float next = (t < SEQ - 1) ? dmb[t + 1] : -1.0f;
    bool k = (v > tb) && (v > prev) && (v > next);
    if (t == 0 || t == SEQ - 1) k = k || (v > tb);
    kp[(size_t)b * SEQ + t] = k ? 1 : 0;
    if (k) haskp[b] = 1;
  } else {
    int rowid = bid - 8;
    int b = rowid >> 2, layer = rowid & 3;
    int j = threadIdx.x;
    float pv = impn[(size_t)b * SEQ + layer * 512 + j];
    float ssum = blockReduceSum(pv);
    uint32_t bits2 = jax_bits32(kg0, kg1, (uint32_t)(rowid * 512 + j));
    float f = __uint_as_float((bits2 >> 9) | 0x3F800000u) - 1.0f;
    float u = fmaxf(F32_TINY, f + F32_TINY);
    float g = -logf(-logf(u));
    float score = logf(pv / (ssum + 1e-6f) + 1e-20f) + g;
    __shared__ float sc[512];
    sc[j] = score;
    __syncthreads();
    for (int pick = 0; pick < 4; pick++) {
      if (j < 64) {
        float bv = -INFINITY; int bi = 0;
        #pragma unroll
        for (int q = 0; q < 8; q++) {
          int idx = j + q * 64;
          float v = sc[idx];
          if (v > bv) { bv = v; bi = idx; }
        }
        #pragma unroll
        for (int o = 1; o < 64; o <<= 1) {
          float ov = __shfl_xor(bv, o);
          int oi = __shfl_xor(bi, o);
          if (ov > bv || (ov == bv && oi < bi)) { bv = ov; bi = oi; }
        }
        if (j == 0) {
          colm[(size_t)b * SEQ + layer * 512 + bi] = 1;
          sc[bi] = -INFINITY;
        }
      }
      __syncthreads();
    }
  }
}

DEVINL bool fbcol(int k) {
  return k == 0 || k == 511 || k == 1023 || k == 1535 || k == 2047;
}

DEVINL void maskbuild_body(const int* __restrict__ win, const uint8_t* __restrict__ kp,
                           const uint8_t* __restrict__ colm, const int* __restrict__ haskp,
                           u64* __restrict__ bits, int* __restrict__ cnt, int q, int b) {
  int w = win[(size_t)b * SEQ + q];
  int hk = haskp[b];
  bool rowk = hk ? (kp[(size_t)b * SEQ + q] != 0) : fbcol(q);
  const uint8_t* kpb = kp + (size_t)b * SEQ;
  const uint8_t* cob = colm + (size_t)b * SEQ;
  int tid = threadIdx.x, wave = tid >> 6, lane = tid & 63;
  int local = 0;
  #pragma unroll
  for (int i = 0; i < 8; i++) {
    int k = i * 256 + tid;
    bool colk = hk ? (kpb[k] != 0) : fbcol(k);
    bool mmv = ((k >= q - w) && (k <= q + w)) || rowk || colk || (cob[k] != 0);
    u64 word = __ballot(mmv);
    if (lane == 0) bits[((size_t)b * 32 + (i * 4 + wave)) * 2048 + q] = word;
    local += mmv ? 1 : 0;
  }
  float tot = blockReduceSum((float)local);
  if (tid == 0) atomicAdd(&cnt[b], (int)tot);
}

// ---------------- 64x128 plain-bf16 MFMA GEMM ----------------
// mode 0: f32 C (+resid); 1: K attn image; 2: V attn image (remapped keys); 3: Q image ×0.125
DEVINL void gemm64_body(const ushort* __restrict__ Ahg, const ushort* __restrict__ Whg,
                        const float* __restrict__ bias, const float* __restrict__ resid,
                        float* __restrict__ C, ushort* __restrict__ oImg,
                        int mode, int bx, int by) {
  __shared__ __align__(16) ushort Ah[2048], Wh[4096];
  int tid = threadIdx.x, wave = tid >> 6, lane = tid & 63;
  int mm = lane & 15, qr = lane >> 4;
  int wm = (wave >> 1) * 32, wn = (wave & 1) * 64;
  int bm = by * 64, bn = bx * 128;
  float4v acc[2][4] = {};
  for (int kk = 0; kk < 16; kk++) {
    __syncthreads();
    {
      const short8* ga = (const short8*)(Ahg + ((size_t)((bm >> 7) * 16 + kk)) * 4096
                                         + ((bm >> 6) & 1) * 2048);
      const short8* gw = (const short8*)(Whg + ((size_t)((bn >> 7) * 16 + kk)) * 4096);
      ((short8*)Ah)[tid] = ga[tid];
      ((short8*)Wh)[tid] = gw[tid];
      ((short8*)Wh)[tid + 256] = gw[tid + 256];
    }
    __syncthreads();
    short8 ah[2], bh[4];
    #pragma unroll
    for (int mt = 0; mt < 2; mt++)
      ah[mt] = ((short8*)Ah)[(((wm >> 4) + mt) * 4 + qr) * 16 + mm];
    #pragma unroll
    for (int nt = 0; nt < 4; nt++)
      bh[nt] = ((short8*)Wh)[(((wn >> 4) + nt) * 4 + qr) * 16 + mm];
    #pragma unroll
    for (int mt = 0; mt < 2; mt++)
      #pragma unroll
      for (int nt = 0; nt < 4; nt++)
        acc[mt][nt] = MFMA(ah[mt], bh[nt], acc[mt][nt]);
  }
  #pragma unroll
  for (int mt = 0; mt < 2; mt++)
    #pragma unroll
    for (int nt = 0; nt < 4; nt++) {
      int n = bn + wn + nt * 16 + mm;
      float bsv = bias[n];
      #pragma unroll
      for (int reg = 0; reg < 4; reg++) {
        int m = bm + wm + mt * 16 + qr * 4 + reg;
        float v = acc[mt][nt][reg] + bsv;
        if (mode == 0) {
          if (resid) v += resid[(size_t)m * 512 + n];
          C[(size_t)m * 512 + n] = v;
        } else if (mode == 1) {
          int b2 = m >> 11, sq = m & 2047, t = sq >> 6, r = sq & 63;
          int h2 = n >> 6, d = n & 63;
          size_t pos = ((size_t)((b2 * 8 + h2) * 32 + t)) * 4096
                     + ((((r >> 4) * 2 + (d >> 5)) * 4 + ((d >> 3) & 3)) * 16 + (r & 15)) * 8
                     + (d & 7);
          oImg[pos] = f2bf(v);
        } else if (mode == 2) {
          int b2 = m >> 11, sq = m & 2047, t = sq >> 6, kk2 = sq & 63;
          int h2 = n >> 6, d = n & 63;
          int pk = (kk2 & 15) * 4 + (kk2 >> 4);
          int kc2 = pk >> 5, qf = (pk >> 3) & 3, j = pk & 7, dt = d >> 4;
          size_t pos = ((size_t)((b2 * 8 + h2) * 32 + t)) * 4096
                     + (((kc2 * 4 + dt) * 4 + qf) * 16 + (d & 15)) * 8 + j;
          oImg[pos] = f2bf(v);
        } else {
          int b2 = m >> 11, q = m & 2047, qt = q >> 5, mt2 = (q >> 4) & 1, mmr = q & 15;
          int h2 = n >> 6, d = n & 63, dc = d >> 5, qr2 = (d >> 3) & 3, j = d & 7;
          size_t pos = ((size_t)((b2 * 8 + h2) * 64 + qt)) * 2048
                     + (((mt2 * 2 + dc) * 4 + qr2) * 16 + mmr) * 8 + j;
          oImg[pos] = f2bf(v * 0.125f);
        }
      }
    }
}

// mega4: QKV projections (768) | maskbuild (4096)
__global__ __launch_bounds__(256) void mega4_kernel(
    const ushort* qnh, const ushort* Wqh, const float* bq, ushort* Qimg,
    const ushort* knh, const ushort* Wkh, const float* bk, ushort* Kth,
    const ushort* vnh, const ushort* Wvh, const float* bv, ushort* Vt,
    const int* win, const uint8_t* kp, const uint8_t* colm, const int* haskp,
    u64* bits, int* cnt) {
  int bid = blockIdx.x;
  if (bid < 768) {
    int op = bid >> 8, r = bid & 255;
    int bx = r & 3, by = r >> 2;
    if (op == 0)      gemm64_body(qnh, Wqh, bq, nullptr, nullptr, Qimg, 3, bx, by);
    else if (op == 1) gemm64_body(knh, Wkh, bk, nullptr, nullptr, Kth, 1, bx, by);
    else              gemm64_body(vnh, Wvh, bv, nullptr, nullptr, Vt, 2, bx, by);
  } else {
    int r = bid - 768;
    maskbuild_body(win, kp, colm, haskp, bits, cnt, r & 2047, r >> 11);
  }
}

// fill (needed computed inline, bit-identical float ops)
__global__ void fill_kernel(u64* __restrict__ bits, const float* __restrict__ comp,
                            const int* __restrict__ cnt,
                            uint32_t kq0, uint32_t kq1, uint32_t kk0, uint32_t kk1) {
  int gid = blockIdx.x * blockDim.x + threadIdx.x;
  int b = gid >> 21;
  int r = gid & (NRAND - 1);
  if (b >= BATCH) return;
  float c0 = comp[0], c1 = comp[1];
  float cmin = fminf(c0, c1), cmax = fmaxf(c0, c1);
  float compb = b ? c1 : c0;
  float nc = (compb - cmin) / (cmax - cmin + 1e-6f);
  float ratio = fminf(fmaxf(0.3f * (0.5f + nc), 0.1f), 0.5f);
  float dens = (float)cnt[b] / 4194304.0f;
  float nd = ceilf((ratio - dens) * 4194304.0f);
  int needed = (int)nd;
  if (needed < 0) needed = 0;
  if (r >= needed) return;
  uint32_t flat = 4194304u + (uint32_t)gid;
  uint32_t q = jax_bits32(kq0, kq1, flat) & 2047u;
  uint32_t k = jax_bits32(kk0, kk1, flat) & 2047u;
  atomicOr(&bits[((size_t)b * 32 + (k >> 6)) * 2048 + q], 1ull << (k & 63));
}

// transpose mask bits into attn lane-mask words:
// tb[((b*64+qt)*32+kc)*32 + w], w=(mt*4+reg)*4+ct; bit[lane]=sparse(row,col)
__global__ __launch_bounds__(256) void tbits_kernel(const u64* __restrict__ bits,
                                                    u64* __restrict__ tb) {
  int bid = blockIdx.x;            // 0..127 = b*64+qt
  int b = bid >> 6, qt = bid & 63;
  int tid = threadIdx.x, wave = tid >> 6, lane = tid & 63;
  int qr = lane >> 4, mm = lane & 15;
  int q0 = qt * 32;
  for (int i = 0; i < 8; i++) {
    int kc = i * 4 + wave;
    #pragma unroll
    for (int w = 0; w < 32; w++) {
      int mt = w >> 4, reg = (w >> 2) & 3, ct = w & 3;
      int row = q0 + mt * 16 + qr * 4 + reg;
      u64 src = bits[((size_t)(b * 32 + kc)) * 2048 + row];
      u64 word = __ballot(((src >> (ct * 16 + mm)) & 1ull) != 0);
      if (lane == 0) tb[(((size_t)(b * 64 + qt)) * 32 + kc) * 32 + w] = word;
    }
  }
}

// ---------------- barrier-free MFMA flash attention (v2) ----------------
__global__ __launch_bounds__(256) void attn_mfma(
    const ushort* __restrict__ Qimg, const ushort* __restrict__ Khig,
    const ushort* __restrict__ Vimg, const u64* __restrict__ tb,
    ushort* __restrict__ Oimg) {
  int qt = blockIdx.x, h = blockIdx.y, b = blockIdx.z;
  __shared__ __align__(16) char arena[33 * 1024 + 768];
  float* LO = (float*)arena;
  float* Lm = (float*)(arena + 32 * 1024);
  float* Ll = (float*)(arena + 32 * 1024 + 512);
  int tid = threadIdx.x;
  int wave = __builtin_amdgcn_readfirstlane(tid >> 6);   // wave-uniform scalar
  int lane = tid & 63;
  int mm = lane & 15, qr = lane >> 4;
  int q0 = qt * 32;
  ushort* pw = (ushort*)arena + wave * 2048;

  short8 aq[2][2];
  {
    const short8* qp = (const short8*)(Qimg + ((size_t)((b * 8 + h) * 64 + qt)) * 2048);
    #pragma unroll
    for (int mt = 0; mt < 2; mt++)
      #pragma unroll
      for (int dc = 0; dc < 2; dc++)
        aq[mt][dc] = qp[((mt * 2 + dc) * 4 + qr) * 16 + mm];
  }
  float4v accO[2][4] = {};
  float4v accL2[2] = {};
  float m_i[2][4];
  #pragma unroll
  for (int mt = 0; mt < 2; mt++)
    #pragma unroll
    for (int r = 0; r < 4; r++) m_i[mt][r] = -INFINITY;
  size_t kvbase = ((size_t)((b * 8 + h) * 32)) * 4096;
  const u64* tbb = tb + ((size_t)(b * 64 + qt)) * 32 * 32;
  const short8 ones8 = {16256, 16256, 16256, 16256, 16256, 16256, 16256, 16256};
  float ngm = NEG_MAX;

  #pragma unroll 2
  for (int it = 0; it < 8; it++) {
    int kc = it * 4 + wave;
    const short8* kh = (const short8*)(Khig + kvbase + (size_t)kc * 4096);
    const short8* vv = (const short8*)(Vimg + kvbase + (size_t)kc * 4096);
    const u64* tw = tbb + kc * 32;
    // QK^T, single bf16 (scale pre-folded into Q image)
    float4v S[2][4];
    #pragma unroll
    for (int ct = 0; ct < 4; ct++) {
      short8 k0 = kh[((ct * 2 + 0) * 4 + qr) * 16 + mm];
      short8 k1 = kh[((ct * 2 + 1) * 4 + qr) * 16 + mm];
      #pragma unroll
      for (int mt = 0; mt < 2; mt++) {
        float4v s = {};
        s = MFMA(aq[mt][0], k0, s);
        s = MFMA(aq[mt][1], k1, s);
        S[mt][ct] = s;
      }
    }
    // masked online softmax; P packed to wave-private LDS
    #pragma unroll
    for (int mt = 0; mt < 2; mt++) {
      #pragma unroll
      for (int reg = 0; reg < 4; reg++) {
        u64 w0 = tw[(mt * 4 + reg) * 4 + 0];
        u64 w1 = tw[(mt * 4 + reg) * 4 + 1];
        u64 w2 = tw[(mt * 4 + reg) * 4 + 2];
        u64 w3 = tw[(mt * 4 + reg) * 4 + 3];
        float s0, s1, s2, s3;
        asm("v_cndmask_b32 %0, %2, %3, %1" : "=v"(s0) : "s"(w0), "v"(S[mt][0][reg]), "v"(ngm));
        asm("v_cndmask_b32 %0, %2, %3, %1" : "=v"(s1) : "s"(w1), "v"(S[mt][1][reg]), "v"(ngm));
        asm("v_cndmask_b32 %0, %2, %3, %1" : "=v"(s2) : "s"(w2), "v"(S[mt][2][reg]), "v"(ngm));
        asm("v_cndmask_b32 %0, %2, %3, %1" : "=v"(s3) : "s"(w3), "v"(S[mt][3][reg]), "v"(ngm));
        float mx = fmaxf(fmaxf(s0, s1), fmaxf(s2, s3));
        #pragma unroll
        for (int o = 1; o < 16; o <<= 1) mx = fmaxf(mx, __shfl_xor(mx, o));
        float mn = fmaxf(m_i[mt][reg], mx);
        float alpha = __expf(m_i[mt][reg] - mn);
        m_i[mt][reg] = mn;
        float p0 = __expf(s0 - mn), p1 = __expf(s1 - mn);
        float p2 = __expf(s2 - mn), p3 = __expf(s3 - mn);
        #pragma unroll
        for (int dt = 0; dt < 4; dt++) accO[mt][dt][reg] *= alpha;
        accL2[mt][reg] *= alpha;
        // truncation-pack to bf16 pairs, one ds_write_b64 per 4 values
        uint32_t lo32 = __builtin_amdgcn_perm(__float_as_uint(p1), __float_as_uint(p0), 0x07060302u);
        uint32_t hi32 = __builtin_amdgcn_perm(__float_as_uint(p3), __float_as_uint(p2), 0x07060302u);
        int blk = (mm >> 3) * 64 + ((mm >> 1) & 3) * 16 + (qr * 4 + reg);
        blk ^= (blk >> 3) & 3;
        *(u64*)(pw + mt * 1024 + blk * 8 + (mm & 1) * 4) = ((u64)hi32 << 32) | lo32;
      }
    }
    // PV + ones-column (l for free)
    #pragma unroll
    for (int mt = 0; mt < 2; mt++)
      #pragma unroll
      for (int kc2 = 0; kc2 < 2; kc2++) {
        int blk = kc2 * 64 + qr * 16 + mm;
        blk ^= (blk >> 3) & 3;
        short8 ap = *(const short8*)(pw + mt * 1024 + blk * 8);
        #pragma unroll
        for (int dt = 0; dt < 4; dt++) {
          short8 bvf = vv[((kc2 * 4 + dt) * 4 + qr) * 16 + mm];
          accO[mt][dt] = MFMA(ap, bvf, accO[mt][dt]);
        }
        accL2[mt] = MFMA(ap, ones8, accL2[mt]);
      }
  }
  // exact flash merge across the 4 waves
  __syncthreads();
  #pragma unroll
  for (int mt = 0; mt < 2; mt++)
    #pragma unroll
    for (int reg = 0; reg < 4; reg++) {
      int r = mt * 16 + qr * 4 + reg;
      if (mm == 0) {
        Lm[wave * 32 + r] = m_i[mt][reg];
        Ll[wave * 32 + r] = accL2[mt][reg];
      }
      #pragma unroll
      for (int dt = 0; dt < 4; dt++)
        LO[(size_t)(wave * 32 + r) * 64 + dt * 16 + mm] = accO[mt][dt][reg];
    }
  __syncthreads();
  int row = tid >> 3, c0 = (tid & 7) * 8;
  float M = Lm[row];
  #pragma unroll
  for (int w = 1; w < 4; w++) M = fmaxf(M, Lm[w * 32 + row]);
  float fw[4], l = 0.f;
  #pragma unroll
  for (int w = 0; w < 4; w++) {
    fw[w] = __expf(Lm[w * 32 + row] - M);
    l += fw[w] * Ll[w * 32 + row];
  }
  float o[8] = {};
  #pragma unroll
  for (int w = 0; w < 4; w++) {
    const float* lob = LO + (size_t)(w * 32 + row) * 64 + c0;
    #pragma unroll
    for (int c = 0; c < 8; c++) o[c] += fw[w] * lob[c];
  }
  float invl = 1.0f / l;
  short8 o8;
  #pragma unroll
  for (int c = 0; c < 8; c++) o8[c] = (short)f2bf(o[c] * invl);
  int rowg = b * SEQ + q0 + row;
  int col = h * 64 + c0;
  int mb = rowg >> 7, rr = rowg & 127, kkc = col >> 5, qrk = (col >> 3) & 3;
  *(short8*)(Oimg + ((size_t)(mb * 16 + kkc)) * 4096
             + (((rr >> 4) * 4 + qrk) * 16 + (rr & 15)) * 8) = o8;
}

__global__ __launch_bounds__(256) void oproj_kernel(
    const ushort* __restrict__ Oimg, const ushort* __restrict__ Woh,
    const float* __restrict__ bo, const float* __restrict__ resid,
    float* __restrict__ out) {
  gemm64_body(Oimg, Woh, bo, resid, out, nullptr, 0, blockIdx.x, blockIdx.y);
}

// ---------------- launcher ----------------
extern "C" void kernel_launch(void* const* d_in, const int* in_sizes, int n_in,
                              void* d_out, int out_size, void* d_ws, size_t ws_size,
                              hipStream_t stream) {
  (void)in_sizes; (void)n_in; (void)out_size; (void)ws_size;
  const float* queries = (const float*)d_in[0];
  const float* keys    = (const float*)d_in[1];
  const float* values  = (const float*)d_in[2];
  const float* ln_q_g  = (const float*)d_in[3];
  const float* ln_q_b  = (const float*)d_in[4];
  const float* ln_k_g  = (const float*)d_in[5];
  const float* ln_k_b  = (const float*)d_in[6];
  const float* ln_v_g  = (const float*)d_in[7];
  const float* ln_v_b  = (const float*)d_in[8];
  const float* Wq = (const float*)d_in[9];  const float* bq = (const float*)d_in[10];
  const float* Wk = (const float*)d_in[11]; const float* bk = (const float*)d_in[12];
  const float* Wv = (const float*)d_in[13]; const float* bv = (const float*)d_in[14];
  const float* Wo = (const float*)d_in[15]; const float* bo = (const float*)d_in[16];
  const float* Ww1 = (const float*)d_in[17]; const float* bw1 = (const float*)d_in[18];
  const float* Ww2 = (const float*)d_in[19]; const float* bw2 = (const float*)d_in[20];

  char* ws = (char*)d_ws;
  const size_t MB = 1u << 20;
  float*  qn   = (float*)(ws + 0 * MB);          // 8 MB (front 4 MB reused as Oimg)
  ushort* qnh  = (ushort*)(ws + 8 * MB);         // 4 MB
  ushort* knh  = (ushort*)(ws + 12 * MB);        // 4 MB
  ushort* vnh  = (ushort*)(ws + 16 * MB);        // 4 MB
  ushort* Qimg = (ushort*)(ws + 20 * MB);        // 4 MB
  ushort* Kth  = (ushort*)(ws + 24 * MB);        // 4 MB
  ushort* Vt   = (ushort*)(ws + 28 * MB);        // 4 MB
  ushort* Wqh  = (ushort*)(ws + 32 * MB);        // 0.5 MB each
  ushort* Wkh  = (ushort*)(ws + 32 * MB + 524288);
  ushort* Wvh  = (ushort*)(ws + 33 * MB);
  ushort* Woh  = (ushort*)(ws + 33 * MB + 524288);
  u64*    bits = (u64*)(ws + 34 * MB);           // 1 MB
  u64*    tb   = (u64*)(ws + 35 * MB);           // 1 MB
  float*  hidden = (float*)(ws + 36 * MB);       // 2 MB
  char* st = ws + 38 * MB;
  float* dm     = (float*)st; st += NROWS * 4;
  float* mag    = (float*)st; st += NROWS * 4;
  float* ch     = (float*)st; st += NROWS * 4;
  float* rowvar = (float*)st; st += NROWS * 4;
  float* impn   = (float*)st; st += NROWS * 4;
  int*   win    = (int*)st;   st += NROWS * 4;
  uint8_t* kp   = (uint8_t*)st; st += NROWS;
  uint8_t* colm = (uint8_t*)st; st += NROWS;
  float* thr    = (float*)st; st += 2 * 4;
  float* comp   = (float*)st; st += 2 * 4;
  int* cnt      = (int*)st;   st += 2 * 4;
  int* haskp    = (int*)st;   st += 2 * 4;
  ushort* Oimg = (ushort*)qn;   // qn dead after mega1/mega2

  uint32_t kg0, kg1, kq0, kq1, kk0, kk1;
  tf2x32(0u, 42u, 0u, 0u, &kg0, &kg1);
  tf2x32(0u, 42u, 0u, 1u, &kq0, &kq1);
  tf2x32(0u, 42u, 0u, 2u, &kk0, &kk1);

  dim3 gln(NROWS, 3);
  ln3_kernel<<<gln, 256, 0, stream>>>(queries, keys, values,
                                      ln_q_g, ln_q_b, ln_k_g, ln_k_b, ln_v_g, ln_v_b,
                                      qn, qnh, knh, vnh);

  mega1_kernel<<<5121, 256, 0, stream>>>(qn, Ww1, bw1, hidden, dm, mag, ch, rowvar,
                                         Wq, Wk, Wv, Wo, Wqh, Wkh, Wvh, Woh,
                                         colm, cnt, haskp);

  mega2_kernel<<<4098, 256, 0, stream>>>(hidden, Ww2, bw2, win,
                                         dm, mag, ch, rowvar, impn, thr, comp);

  mega3_kernel<<<16, 512, 0, stream>>>(dm, thr, kp, haskp, impn, colm, kg0, kg1);

  mega4_kernel<<<768 + 4096, 256, 0, stream>>>(qnh, Wqh, bq, Qimg,
                                               knh, Wkh, bk, Kth,
                                               vnh, Wvh, bv, Vt,
                                               win, kp, colm, haskp, bits, cnt);

  fill_kernel<<<(2 * NRAND) / 256, 256, 0, stream>>>(bits, comp, cnt, kq0, kq1, kk0, kk1);

  tbits_kernel<<<128, 256, 0, stream>>>(bits, tb);

  dim3 gat(SEQ / 32, 8, BATCH);
  attn_mfma<<<gat, 256, 0, stream>>>(Qimg, Kth, Vt, tb, Oimg);

  dim3 go(4, 64);
  oproj_kernel<<<go, 256, 0, stream>>>(Oimg, Woh, bo, queries, (float*)d_out);
}

// Round 7
// 307.254 us; speedup vs baseline: 4.1332x; 1.2176x over previous
//
#include <hip/hip_runtime.h>
#include <stdint.h>
#include <math.h>

#define DEVINL __device__ __forceinline__

constexpr int SEQ = 2048;
constexpr int DIM = 512;
constexpr int BATCH = 2;
constexpr int NROWS = BATCH * SEQ;        // 4096
constexpr int NRAND = (SEQ * SEQ) / 2;    // 2^21
constexpr float F32_TINY = 1.1754943508222875e-38f;

typedef float float4v __attribute__((ext_vector_type(4)));
typedef short short8 __attribute__((ext_vector_type(8)));
typedef unsigned long long u64;

DEVINL float4v MFMA(short8 a, short8 b, float4v c) {
  return __builtin_amdgcn_mfma_f32_16x16x32_bf16(a, b, c, 0, 0, 0);
}

DEVINL ushort f2bf(float x) {
  uint32_t u = __float_as_uint(x);
  return (ushort)((u + 0x7FFFu + ((u >> 16) & 1u)) >> 16);
}

// ---------------- threefry2x32 (JAX-compatible) ----------------
__host__ __device__ inline void tf2x32(uint32_t k0, uint32_t k1,
                                       uint32_t x0, uint32_t x1,
                                       uint32_t* o0, uint32_t* o1) {
  uint32_t ks2 = k0 ^ k1 ^ 0x1BD11BDAu;
  x0 += k0; x1 += k1;
#define TFR(r) { x0 += x1; x1 = (x1 << (r)) | (x1 >> (32 - (r))); x1 ^= x0; }
  TFR(13) TFR(15) TFR(26) TFR(6)
  x0 += k1; x1 += ks2 + 1u;
  TFR(17) TFR(29) TFR(16) TFR(24)
  x0 += ks2; x1 += k0 + 2u;
  TFR(13) TFR(15) TFR(26) TFR(6)
  x0 += k0; x1 += k1 + 3u;
  TFR(17) TFR(29) TFR(16) TFR(24)
  x0 += k1; x1 += ks2 + 4u;
  TFR(13) TFR(15) TFR(26) TFR(6)
  x0 += ks2; x1 += k0 + 5u;
#undef TFR
  *o0 = x0; *o1 = x1;
}

DEVINL uint32_t jax_bits32(uint32_t k0, uint32_t k1, uint32_t idx) {
  uint32_t a, b;
  tf2x32(k0, k1, 0u, idx, &a, &b);
  return a ^ b;
}

// ---------------- block reductions ----------------
DEVINL float blockReduceSum(float v) {
  __shared__ float sh[16];
  __syncthreads();
  int lane = threadIdx.x & 63, wid = threadIdx.x >> 6;
  #pragma unroll
  for (int o = 32; o > 0; o >>= 1) v += __shfl_down(v, o);
  if (lane == 0) sh[wid] = v;
  __syncthreads();
  if (threadIdx.x == 0) {
    int nw = ((int)blockDim.x + 63) >> 6;
    float s = 0.f;
    for (int i = 0; i < nw; i++) s += sh[i];
    sh[0] = s;
  }
  __syncthreads();
  return sh[0];
}

DEVINL float blockReduceMin(float v) {
  __shared__ float sh[16];
  __syncthreads();
  int lane = threadIdx.x & 63, wid = threadIdx.x >> 6;
  #pragma unroll
  for (int o = 32; o > 0; o >>= 1) v = fminf(v, __shfl_down(v, o));
  if (lane == 0) sh[wid] = v;
  __syncthreads();
  if (threadIdx.x == 0) {
    int nw = ((int)blockDim.x + 63) >> 6;
    float s = sh[0];
    for (int i = 1; i < nw; i++) s = fminf(s, sh[i]);
    sh[0] = s;
  }
  __syncthreads();
  return sh[0];
}

DEVINL float blockReduceMax(float v) {
  __shared__ float sh[16];
  __syncthreads();
  int lane = threadIdx.x & 63, wid = threadIdx.x >> 6;
  #pragma unroll
  for (int o = 32; o > 0; o >>= 1) v = fmaxf(v, __shfl_down(v, o));
  if (lane == 0) sh[wid] = v;
  __syncthreads();
  if (threadIdx.x == 0) {
    int nw = ((int)blockDim.x + 63) >> 6;
    float s = sh[0];
    for (int i = 1; i < nw; i++) s = fmaxf(s, sh[i]);
    sh[0] = s;
  }
  __syncthreads();
  return sh[0];
}

// A-image layout (GEMM A/W operand): chunk (row>>7, k>>5) of 4096 ushorts
DEVINL void store_img_scalar(ushort* img, int row, int d, float v) {
  size_t idx = ((size_t)((row >> 7) * 16 + (d >> 5))) * 4096
             + ((((row & 127) >> 4) * 4 + ((d >> 3) & 3)) * 16 + (row & 15)) * 8 + (d & 7);
  img[idx] = f2bf(v);
}

// ---------------- ln3: LayerNorm ×3 + bf16 image emit ----------------
__global__ __launch_bounds__(256) void ln3_kernel(
    const float* __restrict__ xq, const float* __restrict__ xk, const float* __restrict__ xv,
    const float* __restrict__ gq, const float* __restrict__ bq2,
    const float* __restrict__ gk, const float* __restrict__ bk2,
    const float* __restrict__ gv, const float* __restrict__ bv2,
    float* __restrict__ oq, ushort* __restrict__ iq, ushort* __restrict__ ik,
    ushort* __restrict__ iv) {
  const float *x, *g, *bb; ushort* img;
  if (blockIdx.y == 0)      { x = xq; g = gq; bb = bq2; img = iq; }
  else if (blockIdx.y == 1) { x = xk; g = gk; bb = bk2; img = ik; }
  else                      { x = xv; g = gv; bb = bv2; img = iv; }
  int row = blockIdx.x;
  const float* xr = x + (size_t)row * DIM;
  int t = threadIdx.x;
  float v0 = xr[t], v1 = xr[t + 256];
  float mu = blockReduceSum(v0 + v1) * (1.0f / 512.0f);
  float d0 = v0 - mu, d1 = v1 - mu;
  float var = blockReduceSum(d0 * d0 + d1 * d1) * (1.0f / 512.0f);
  float inv = 1.0f / sqrtf(var + 1e-5f);
  float r0 = d0 * inv * g[t] + bb[t];
  float r1 = d1 * inv * g[t + 256] + bb[t + 256];
  if (blockIdx.y == 0) {
    oq[(size_t)row * DIM + t] = r0;
    oq[(size_t)row * DIM + t + 256] = r1;
  }
  store_img_scalar(img, row, t, r0);
  store_img_scalar(img, row, t + 256, r1);
}

// ---------------- mask-critical f32 bodies (bit-exact, unchanged math) ----------------
DEVINL void gemm_f32_body(const float* __restrict__ A, const float* __restrict__ W,
                          const float* __restrict__ bias, float* __restrict__ C,
                          int bx, int by) {
  __shared__ float As[16][17];
  __shared__ float Ws[16][68];
  int bm = by * 16, bn = bx * 64;
  int tid = threadIdx.x;
  int tx = tid & 15, ty = tid >> 4;
  int lk = tid & 15, lm = tid >> 4;
  float acc[4] = {0.f, 0.f, 0.f, 0.f};
  for (int kk = 0; kk < DIM; kk += 16) {
    __syncthreads();
    As[lk][lm] = A[(size_t)(bm + lm) * DIM + kk + lk];
    #pragma unroll
    for (int i = 0; i < 4; i++)
      Ws[lk][lm + i * 16] = W[(size_t)(bn + lm + i * 16) * DIM + kk + lk];
    __syncthreads();
    #pragma unroll
    for (int k = 0; k < 16; k++) {
      float a = As[k][ty];
      float4 w4 = *(const float4*)&Ws[k][tx * 4];
      acc[0] += a * w4.x; acc[1] += a * w4.y;
      acc[2] += a * w4.z; acc[3] += a * w4.w;
    }
  }
  int m = bm + ty;
  #pragma unroll
  for (int j = 0; j < 4; j++) {
    int n = bn + tx * 4 + j;
    float v = acc[j] + bias[n];
    v = fmaxf(v, 0.f);
    C[(size_t)m * 128 + n] = v;
  }
}

DEVINL void dmstats_body(const float* __restrict__ qn, float* __restrict__ dm,
                         float* __restrict__ mag, float* __restrict__ ch,
                         float* __restrict__ rowvar, int t, int b) {
  const float* x = qn + ((size_t)b * SEQ + t) * DIM;
  int tid = threadIdx.x;
  float sx = 0, sq = 0, sdm = 0, sch = 0;
  float xs[2];
  #pragma unroll
  for (int i = 0; i < 2; i++) {
    int d = tid + i * 256;
    float xv = x[d]; xs[i] = xv;
    sx += xv; sq += xv * xv;
    float acc = 0.f;
    if (t + 1 < SEQ) { float df = fabsf(x[1 * DIM + d] - xv); acc += 0.4f * (df / 1.0f); sch += df; }
    if (t + 2 < SEQ) { float df = fabsf(x[2 * DIM + d] - xv); acc += 0.3f * (df / 2.0f); }
    if (t + 3 < SEQ) { float df = fabsf(x[3 * DIM + d] - xv); acc += 0.2f * (df / 3.0f); }
    if (t + 5 < SEQ) { float df = fabsf(x[5 * DIM + d] - xv); acc += 0.1f * (df / 5.0f); }
    sdm += acc;
  }
  float mu = blockReduceSum(sx) * (1.0f / 512.0f);
  float sv = 0;
  #pragma unroll
  for (int i = 0; i < 2; i++) { float dd = xs[i] - mu; sv += dd * dd; }
  float totsq = blockReduceSum(sq);
  float totdm = blockReduceSum(sdm);
  float totch = blockReduceSum(sch);
  float totsv = blockReduceSum(sv);
  if (tid == 0) {
    size_t idx = (size_t)b * SEQ + t;
    dm[idx] = totdm / 512.0f;
    mag[idx] = sqrtf(totsq);
    ch[idx] = (t + 1 < SEQ) ? (totch / 512.0f) : 0.f;
    rowvar[idx] = totsv / 511.0f;
  }
}

DEVINL void conv_w_hi(const float* __restrict__ src, ushort* __restrict__ dst, int gid) {
  int row = gid >> 6, c8 = gid & 63;
  const float* p = src + (size_t)row * 512 + c8 * 8;
  float4 v0 = ((const float4*)p)[0];
  float4 v1 = ((const float4*)p)[1];
  float xv[8] = {v0.x, v0.y, v0.z, v0.w, v1.x, v1.y, v1.z, v1.w};
  short8 hv;
  #pragma unroll
  for (int j = 0; j < 8; j++) hv[j] = (short)f2bf(xv[j]);
  int mb = row >> 7, rr = row & 127, kkc = c8 >> 2, qrr = c8 & 3;
  ((short8*)dst)[(mb * 16 + kkc) * 512 + ((rr >> 4) * 4 + qrr) * 16 + (rr & 15)] = hv;
}

// mega1: gemm_f32(512) | dmstats(4096) | weight conv(512) | init(1)
__global__ __launch_bounds__(256) void mega1_kernel(
    const float* qn, const float* Ww1, const float* bw1, float* hidden,
    float* dm, float* mag, float* ch, float* rowvar,
    const float* Wq, const float* Wk, const float* Wv, const float* Wo,
    ushort* Wqh, ushort* Wkh, ushort* Wvh, ushort* Woh,
    uint8_t* colm, int* cnt, int* haskp) {
  int bid = blockIdx.x;
  if (bid < 512) {
    gemm_f32_body(qn, Ww1, bw1, hidden, bid & 1, bid >> 1);
  } else if (bid < 4608) {
    int r = bid - 512;
    dmstats_body(qn, dm, mag, ch, rowvar, r & 2047, r >> 11);
  } else if (bid < 5120) {
    int r = bid - 4608;
    const float* s; ushort* d;
    switch (r >> 7) {
      case 0: s = Wq; d = Wqh; break;
      case 1: s = Wk; d = Wkh; break;
      case 2: s = Wv; d = Wvh; break;
      default: s = Wo; d = Woh; break;
    }
    conv_w_hi(s, d, (r & 127) * 256 + (int)threadIdx.x);
  } else {
    int tid = threadIdx.x;
    for (int i = tid; i < BATCH * SEQ; i += 256) colm[i] = 0;
    if (tid < BATCH) { cnt[tid] = 0; haskp[tid] = 0; }
  }
}

// mega2: win(4096, 256-thr zero-padded — bitwise-identical sum) | batchstats(2)
DEVINL void win_body(const float* __restrict__ hidden, const float* __restrict__ Ww2,
                     const float* __restrict__ bw2, int* __restrict__ win, int row) {
  int t = threadIdx.x;
  float v = (t < 128) ? hidden[(size_t)row * 128 + t] * Ww2[t] : 0.f;
  v = blockReduceSum(v);
  if (t == 0) {
    float y = v + bw2[0];
    float sig = 1.0f / (1.0f + expf(-y));
    float adj = 0.5f + sig;
    int w = (int)rintf(64.0f * adj);
    w = w < 1 ? 1 : (w > 128 ? 128 : w);
    win[row] = w;
  }
}

DEVINL void batchstats_body(const float* __restrict__ dm, const float* __restrict__ mag,
                            const float* __restrict__ ch, const float* __restrict__ rowvar,
                            float* __restrict__ impn, float* __restrict__ thr,
                            float* __restrict__ comp, int b) {
  int tid = threadIdx.x;
  float sdm = 0, srv = 0, lo = INFINITY, hi = -INFINITY;
  for (int t = tid; t < SEQ; t += 256) {
    size_t idx = (size_t)b * SEQ + t;
    sdm += dm[idx];
    srv += rowvar[idx];
    float imp = 0.5f * mag[idx] + 0.5f * ch[idx];
    lo = fminf(lo, imp); hi = fmaxf(hi, imp);
  }
  float meandm = blockReduceSum(sdm) * (1.0f / 2048.0f);
  float compv = blockReduceSum(srv) * (1.0f / 2048.0f);
  lo = blockReduceMin(lo);
  hi = blockReduceMax(hi);
  float sv = 0;
  for (int t = tid; t < SEQ; t += 256) {
    float d2 = dm[(size_t)b * SEQ + t] - meandm;
    sv += d2 * d2;
  }
  float var = blockReduceSum(sv) / 2047.0f;
  for (int t = tid; t < SEQ; t += 256) {
    size_t idx = (size_t)b * SEQ + t;
    float imp = 0.5f * mag[idx] + 0.5f * ch[idx];
    impn[idx] = (imp - lo) / (hi - lo + 1e-6f);
  }
  if (tid == 0) { thr[b] = meandm + 0.5f * sqrtf(var); comp[b] = compv; }
}

__global__ __launch_bounds__(256) void mega2_kernel(
    const float* hidden, const float* Ww2, const float* bw2, int* win,
    const float* dm, const float* mag, const float* ch, const float* rowvar,
    float* impn, float* thr, float* comp) {
  int bid = blockIdx.x;
  if (bid < 4096) win_body(hidden, Ww2, bw2, win, bid);
  else batchstats_body(dm, mag, ch, rowvar, impn, thr, comp, bid - 4096);
}

// mega3 (512 threads): kp(8) | topk(8)
__global__ __launch_bounds__(512) void mega3_kernel(
    const float* __restrict__ dm, const float* __restrict__ thr,
    uint8_t* __restrict__ kp, int* __restrict__ haskp,
    const float* __restrict__ impn, uint8_t* __restrict__ colm,
    uint32_t kg0, uint32_t kg1) {
  int bid = blockIdx.x;
  if (bid < 8) {
    int b = bid >> 2;
    int t = (bid & 3) * 512 + (int)threadIdx.x;
    const float* dmb = dm + (size_t)b * SEQ;
    float v = dmb[t];
    float tb = thr[b];
    float prev = (t > 0) ? dmb[t - 1] : -1.0f;
    float next = (t < SEQ - 1) ? dmb[t + 1] : -1.0f;
    bool k = (v > tb) && (v > prev) && (v > next);
    if (t == 0 || t == SEQ - 1) k = k || (v > tb);
    kp[(size_t)b * SEQ + t] = k ? 1 : 0;
    if (k) haskp[b] = 1;
  } else {
    int rowid = bid - 8;
    int b = rowid >> 2, layer = rowid & 3;
    int j = threadIdx.x;
    float pv = impn[(size_t)b * SEQ + layer * 512 + j];
    float ssum = blockReduceSum(pv);
    uint32_t bits2 = jax_bits32(kg0, kg1, (uint32_t)(rowid * 512 + j));
    float f = __uint_as_float((bits2 >> 9) | 0x3F800000u) - 1.0f;
    float u = fmaxf(F32_TINY, f + F32_TINY);
    float g = -logf(-logf(u));
    float score = logf(pv / (ssum + 1e-6f) + 1e-20f) + g;
    __shared__ float sc[512];
    sc[j] = score;
    __syncthreads();
    for (int pick = 0; pick < 4; pick++) {
      if (j < 64) {
        float bv = -INFINITY; int bi = 0;
        #pragma unroll
        for (int q = 0; q < 8; q++) {
          int idx = j + q * 64;
          float v = sc[idx];
          if (v > bv) { bv = v; bi = idx; }
        }
        #pragma unroll
        for (int o = 1; o < 64; o <<= 1) {
          float ov = __shfl_xor(bv, o);
          int oi = __shfl_xor(bi, o);
          if (ov > bv || (ov == bv && oi < bi)) { bv = ov; bi = oi; }
        }
        if (j == 0) {
          colm[(size_t)b * SEQ + layer * 512 + bi] = 1;
          sc[bi] = -INFINITY;
        }
      }
      __syncthreads();
    }
  }
}

DEVINL bool fbcol(int k) {
  return k == 0 || k == 511 || k == 1023 || k == 1535 || k == 2047;
}

DEVINL void maskbuild_body(const int* __restrict__ win, const uint8_t* __restrict__ kp,
                           const uint8_t* __restrict__ colm, const int* __restrict__ haskp,
                           u64* __restrict__ bits, int* __restrict__ cnt, int q, int b) {
  int w = win[(size_t)b * SEQ + q];
  int hk = haskp[b];
  bool rowk = hk ? (kp[(size_t)b * SEQ + q] != 0) : fbcol(q);
  const uint8_t* kpb = kp + (size_t)b * SEQ;
  const uint8_t* cob = colm + (size_t)b * SEQ;
  int tid = threadIdx.x, wave = tid >> 6, lane = tid & 63;
  int local = 0;
  #pragma unroll
  for (int i = 0; i < 8; i++) {
    int k = i * 256 + tid;
    bool colk = hk ? (kpb[k] != 0) : fbcol(k);
    bool mmv = ((k >= q - w) && (k <= q + w)) || rowk || colk || (cob[k] != 0);
    u64 word = __ballot(mmv);
    if (lane == 0) bits[((size_t)b * 32 + (i * 4 + wave)) * 2048 + q] = word;
    local += mmv ? 1 : 0;
  }
  float tot = blockReduceSum((float)local);
  if (tid == 0) atomicAdd(&cnt[b], (int)tot);
}

// ---------------- 64x128 plain-bf16 MFMA GEMM ----------------
// mode 0: f32 C (+resid); 1: K attn image; 2: V attn image (remapped keys); 3: Q image ×0.125
DEVINL void gemm64_body(const ushort* __restrict__ Ahg, const ushort* __restrict__ Whg,
                        const float* __restrict__ bias, const float* __restrict__ resid,
                        float* __restrict__ C, ushort* __restrict__ oImg,
                        int mode, int bx, int by) {
  __shared__ __align__(16) ushort Ah[2048], Wh[4096];
  int tid = threadIdx.x, wave = tid >> 6, lane = tid & 63;
  int mm = lane & 15, qr = lane >> 4;
  int wm = (wave >> 1) * 32, wn = (wave & 1) * 64;
  int bm = by * 64, bn = bx * 128;
  float4v acc[2][4] = {};
  for (int kk = 0; kk < 16; kk++) {
    __syncthreads();
    {
      const short8* ga = (const short8*)(Ahg + ((size_t)((bm >> 7) * 16 + kk)) * 4096
                                         + ((bm >> 6) & 1) * 2048);
      const short8* gw = (const short8*)(Whg + ((size_t)((bn >> 7) * 16 + kk)) * 4096);
      ((short8*)Ah)[tid] = ga[tid];
      ((short8*)Wh)[tid] = gw[tid];
      ((short8*)Wh)[tid + 256] = gw[tid + 256];
    }
    __syncthreads();
    short8 ah[2], bh[4];
    #pragma unroll
    for (int mt = 0; mt < 2; mt++)
      ah[mt] = ((short8*)Ah)[(((wm >> 4) + mt) * 4 + qr) * 16 + mm];
    #pragma unroll
    for (int nt = 0; nt < 4; nt++)
      bh[nt] = ((short8*)Wh)[(((wn >> 4) + nt) * 4 + qr) * 16 + mm];
    #pragma unroll
    for (int mt = 0; mt < 2; mt++)
      #pragma unroll
      for (int nt = 0; nt < 4; nt++)
        acc[mt][nt] = MFMA(ah[mt], bh[nt], acc[mt][nt]);
  }
  #pragma unroll
  for (int mt = 0; mt < 2; mt++)
    #pragma unroll
    for (int nt = 0; nt < 4; nt++) {
      int n = bn + wn + nt * 16 + mm;
      float bsv = bias[n];
      #pragma unroll
      for (int reg = 0; reg < 4; reg++) {
        int m = bm + wm + mt * 16 + qr * 4 + reg;
        float v = acc[mt][nt][reg] + bsv;
        if (mode == 0) {
          if (resid) v += resid[(size_t)m * 512 + n];
          C[(size_t)m * 512 + n] = v;
        } else if (mode == 1) {
          int b2 = m >> 11, sq = m & 2047, t = sq >> 6, r = sq & 63;
          int h2 = n >> 6, d = n & 63;
          size_t pos = ((size_t)((b2 * 8 + h2) * 32 + t)) * 4096
                     + ((((r >> 4) * 2 + (d >> 5)) * 4 + ((d >> 3) & 3)) * 16 + (r & 15)) * 8
                     + (d & 7);
          oImg[pos] = f2bf(v);
        } else if (mode == 2) {
          int b2 = m >> 11, sq = m & 2047, t = sq >> 6, kk2 = sq & 63;
          int h2 = n >> 6, d = n & 63;
          int pk = (kk2 & 15) * 4 + (kk2 >> 4);
          int kc2 = pk >> 5, qf = (pk >> 3) & 3, j = pk & 7, dt = d >> 4;
          size_t pos = ((size_t)((b2 * 8 + h2) * 32 + t)) * 4096
                     + (((kc2 * 4 + dt) * 4 + qf) * 16 + (d & 15)) * 8 + j;
          oImg[pos] = f2bf(v);
        } else {
          int b2 = m >> 11, q = m & 2047, qt = q >> 5, mt2 = (q >> 4) & 1, mmr = q & 15;
          int h2 = n >> 6, d = n & 63, dc = d >> 5, qr2 = (d >> 3) & 3, j = d & 7;
          size_t pos = ((size_t)((b2 * 8 + h2) * 64 + qt)) * 2048
                     + (((mt2 * 2 + dc) * 4 + qr2) * 16 + mmr) * 8 + j;
          oImg[pos] = f2bf(v * 0.125f);
        }
      }
    }
}

// mega4: QKV projections (768) | maskbuild (4096)
__global__ __launch_bounds__(256) void mega4_kernel(
    const ushort* qnh, const ushort* Wqh, const float* bq, ushort* Qimg,
    const ushort* knh, const ushort* Wkh, const float* bk, ushort* Kth,
    const ushort* vnh, const ushort* Wvh, const float* bv, ushort* Vt,
    const int* win, const uint8_t* kp, const uint8_t* colm, const int* haskp,
    u64* bits, int* cnt) {
  int bid = blockIdx.x;
  if (bid < 768) {
    int op = bid >> 8, r = bid & 255;
    int bx = r & 3, by = r >> 2;
    if (op == 0)      gemm64_body(qnh, Wqh, bq, nullptr, nullptr, Qimg, 3, bx, by);
    else if (op == 1) gemm64_body(knh, Wkh, bk, nullptr, nullptr, Kth, 1, bx, by);
    else              gemm64_body(vnh, Wvh, bv, nullptr, nullptr, Vt, 2, bx, by);
  } else {
    int r = bid - 768;
    maskbuild_body(win, kp, colm, haskp, bits, cnt, r & 2047, r >> 11);
  }
}

// fill (needed computed inline, bit-identical float ops)
__global__ void fill_kernel(u64* __restrict__ bits, const float* __restrict__ comp,
                            const int* __restrict__ cnt,
                            uint32_t kq0, uint32_t kq1, uint32_t kk0, uint32_t kk1) {
  int gid = blockIdx.x * blockDim.x + threadIdx.x;
  int b = gid >> 21;
  int r = gid & (NRAND - 1);
  if (b >= BATCH) return;
  float c0 = comp[0], c1 = comp[1];
  float cmin = fminf(c0, c1), cmax = fmaxf(c0, c1);
  float compb = b ? c1 : c0;
  float nc = (compb - cmin) / (cmax - cmin + 1e-6f);
  float ratio = fminf(fmaxf(0.3f * (0.5f + nc), 0.1f), 0.5f);
  float dens = (float)cnt[b] / 4194304.0f;
  float nd = ceilf((ratio - dens) * 4194304.0f);
  int needed = (int)nd;
  if (needed < 0) needed = 0;
  if (r >= needed) return;
  uint32_t flat = 4194304u + (uint32_t)gid;
  uint32_t q = jax_bits32(kq0, kq1, flat) & 2047u;
  uint32_t k = jax_bits32(kk0, kk1, flat) & 2047u;
  atomicOr(&bits[((size_t)b * 32 + (k >> 6)) * 2048 + q], 1ull << (k & 63));
}

// per-lane u32 mask image: tl[((b*64+qt)*32+kc)*64 + lane], bit w=(mt*4+reg)*4+ct
// = sparse(row = qt*32+mt*16+(lane>>4)*4+reg, key = kc*64+ct*16+(lane&15))
__global__ __launch_bounds__(256) void tl_kernel(const u64* __restrict__ bits,
                                                 uint32_t* __restrict__ tl) {
  int bid = blockIdx.x;            // 0..127 = b*64+qt
  int b = bid >> 6, qt = bid & 63;
  int tid = threadIdx.x;
  __shared__ u64 W[32][32];        // [kc][row-local]
  #pragma unroll
  for (int i = 0; i < 4; i++) {
    int idx = i * 256 + tid;
    int kc = idx >> 5, r = idx & 31;
    W[kc][r] = bits[((size_t)(b * 32 + kc)) * 2048 + qt * 32 + r];
  }
  __syncthreads();
  #pragma unroll
  for (int oi = 0; oi < 8; oi++) {
    int o = oi * 256 + tid;
    int kc = o >> 6, lane = o & 63;
    int qr = lane >> 4, mm = lane & 15;
    uint32_t acc = 0;
    #pragma unroll
    for (int mt = 0; mt < 2; mt++)
      #pragma unroll
      for (int reg = 0; reg < 4; reg++) {
        u64 wv = W[kc][mt * 16 + qr * 4 + reg];
        uint32_t lo = (uint32_t)wv, hi = (uint32_t)(wv >> 32);
        int base = (mt * 4 + reg) * 4;
        acc |= ((lo >> mm) & 1u) << base;
        acc |= ((lo >> (16 + mm)) & 1u) << (base + 1);
        acc |= ((hi >> mm) & 1u) << (base + 2);
        acc |= ((hi >> (16 + mm)) & 1u) << (base + 3);
      }
    tl[((size_t)(b * 64 + qt) * 32 + kc) * 64 + lane] = acc;
  }
}

// ---------------- barrier-free MFMA flash attention (v4) ----------------
// Online-max softmax restored (round-5 numerics); masking via fma(bit,-1e30,s):
// all-masked rows collapse to exactly -1e30 -> uniform softmax like the reference.
// Per-lane u32 VMEM masks (no SMEM/lgkmcnt interference); ones-column MFMA for l.
__global__ __launch_bounds__(256, 4) void attn_mfma(
    const ushort* __restrict__ Qimg, const ushort* __restrict__ Khig,
    const ushort* __restrict__ Vimg, const uint32_t* __restrict__ tl,
    ushort* __restrict__ Oimg) {
  int qt = blockIdx.x, h = blockIdx.y, b = blockIdx.z;
  __shared__ __align__(16) char arena[34 * 1024];
  float* LO = (float*)arena;                       // [4*32][64] merge
  float* Lm = (float*)(arena + 32768);             // [4*32]
  float* Ll = (float*)(arena + 32768 + 512);       // [4*32]
  int tid = threadIdx.x;
  int wave = __builtin_amdgcn_readfirstlane(tid >> 6);
  int lane = tid & 63;
  int mm = lane & 15, qr = lane >> 4;
  int q0 = qt * 32;
  ushort* pw = (ushort*)arena + wave * 2048;       // wave-private P (4 KB)

  short8 aq[2][2];
  {
    const short8* qp = (const short8*)(Qimg + ((size_t)((b * 8 + h) * 64 + qt)) * 2048);
    #pragma unroll
    for (int mt = 0; mt < 2; mt++)
      #pragma unroll
      for (int dc = 0; dc < 2; dc++)
        aq[mt][dc] = qp[((mt * 2 + dc) * 4 + qr) * 16 + mm];
  }
  float4v accO[2][4] = {};
  float4v accL2[2] = {};
  float m_i[2][4];
  #pragma unroll
  for (int mt = 0; mt < 2; mt++)
    #pragma unroll
    for (int r = 0; r < 4; r++) m_i[mt][r] = -INFINITY;
  size_t kvbase = ((size_t)((b * 8 + h) * 32)) * 4096;
  const uint32_t* tlb = tl + ((size_t)(b * 64 + qt)) * 32 * 64 + lane;
  const short8 ones8 = {16256, 16256, 16256, 16256, 16256, 16256, 16256, 16256};

  #pragma unroll 2
  for (int it = 0; it < 8; it++) {
    int kc = it * 4 + wave;
    const short8* kh = (const short8*)(Khig + kvbase + (size_t)kc * 4096);
    const short8* vv = (const short8*)(Vimg + kvbase + (size_t)kc * 4096);
    uint32_t mw = tlb[(size_t)kc * 64];
    // QK^T, single bf16 (scale pre-folded into Q image)
    float4v S[2][4];
    #pragma unroll
    for (int ct = 0; ct < 4; ct++) {
      short8 k0 = kh[((ct * 2 + 0) * 4 + qr) * 16 + mm];
      short8 k1 = kh[((ct * 2 + 1) * 4 + qr) * 16 + mm];
      #pragma unroll
      for (int mt = 0; mt < 2; mt++) {
        float4v s = {};
        s = MFMA(aq[mt][0], k0, s);
        s = MFMA(aq[mt][1], k1, s);
        S[mt][ct] = s;
      }
    }
    // online-max masked softmax; P packed to wave-private LDS
    #pragma unroll
    for (int mt = 0; mt < 2; mt++) {
      #pragma unroll
      for (int reg = 0; reg < 4; reg++) {
        int base = (mt * 4 + reg) * 4;
        float s[4];
        #pragma unroll
        for (int ct = 0; ct < 4; ct++) {
          float bitf = (float)((mw >> (base + ct)) & 1u);
          s[ct] = fmaf(bitf, -1e30f, S[mt][ct][reg]);
        }
        float mx = fmaxf(fmaxf(s[0], s[1]), fmaxf(s[2], s[3]));
        #pragma unroll
        for (int o = 1; o < 16; o <<= 1) mx = fmaxf(mx, __shfl_xor(mx, o));
        float mn = fmaxf(m_i[mt][reg], mx);
        float alpha = __expf(m_i[mt][reg] - mn);
        m_i[mt][reg] = mn;
        float p[4];
        #pragma unroll
        for (int ct = 0; ct < 4; ct++) p[ct] = __expf(s[ct] - mn);
        #pragma unroll
        for (int dt = 0; dt < 4; dt++) accO[mt][dt][reg] *= alpha;
        accL2[mt][reg] *= alpha;
        uint32_t lo32 = __builtin_amdgcn_perm(__float_as_uint(p[1]), __float_as_uint(p[0]), 0x07060302u);
        uint32_t hi32 = __builtin_amdgcn_perm(__float_as_uint(p[3]), __float_as_uint(p[2]), 0x07060302u);
        int r = qr * 4 + reg;
        int cp = (mm >> 1) ^ (r & 7);
        *(u64*)(pw + mt * 1024 + r * 64 + cp * 8 + (mm & 1) * 4) = ((u64)hi32 << 32) | lo32;
      }
    }
    // PV + ones-column (row-sum l for free)
    #pragma unroll
    for (int mt = 0; mt < 2; mt++)
      #pragma unroll
      for (int kc2 = 0; kc2 < 2; kc2++) {
        int cp = (kc2 * 4 + qr) ^ (mm & 7);
        short8 ap = *(const short8*)(pw + mt * 1024 + mm * 64 + cp * 8);
        #pragma unroll
        for (int dt = 0; dt < 4; dt++) {
          short8 bvf = vv[((kc2 * 4 + dt) * 4 + qr) * 16 + mm];
          accO[mt][dt] = MFMA(ap, bvf, accO[mt][dt]);
        }
        accL2[mt] = MFMA(ap, ones8, accL2[mt]);
      }
  }
  // exact flash merge across the 4 waves
  __syncthreads();
  #pragma unroll
  for (int mt = 0; mt < 2; mt++)
    #pragma unroll
    for (int reg = 0; reg < 4; reg++) {
      int r = mt * 16 + qr * 4 + reg;
      if (mm == 0) {
        Lm[wave * 32 + r] = m_i[mt][reg];
        Ll[wave * 32 + r] = accL2[mt][reg];
      }
      #pragma unroll
      for (int dt = 0; dt < 4; dt++)
        LO[(size_t)(wave * 32 + r) * 64 + dt * 16 + mm] = accO[mt][dt][reg];
    }
  __syncthreads();
  int row = tid >> 3, c0 = (tid & 7) * 8;
  float M = Lm[row];
  #pragma unroll
  for (int w = 1; w < 4; w++) M = fmaxf(M, Lm[w * 32 + row]);
  float fw[4], l = 0.f;
  #pragma unroll
  for (int w = 0; w < 4; w++) {
    fw[w] = __expf(Lm[w * 32 + row] - M);
    l += fw[w] * Ll[w * 32 + row];
  }
  float o[8] = {};
  #pragma unroll
  for (int w = 0; w < 4; w++) {
    const float* lob = LO + (size_t)(w * 32 + row) * 64 + c0;
    #pragma unroll
    for (int c = 0; c < 8; c++) o[c] += fw[w] * lob[c];
  }
  float invl = 1.0f / l;
  short8 o8;
  #pragma unroll
  for (int c = 0; c < 8; c++) o8[c] = (short)f2bf(o[c] * invl);
  int rowg = b * SEQ + q0 + row;
  int col = h * 64 + c0;
  int mb = rowg >> 7, rr = rowg & 127, kkc = col >> 5, qrk = (col >> 3) & 3;
  *(short8*)(Oimg + ((size_t)(mb * 16 + kkc)) * 4096
             + (((rr >> 4) * 4 + qrk) * 16 + (rr & 15)) * 8) = o8;
}

__global__ __launch_bounds__(256) void oproj_kernel(
    const ushort* __restrict__ Oimg, const ushort* __restrict__ Woh,
    const float* __restrict__ bo, const float* __restrict__ resid,
    float* __restrict__ out) {
  gemm64_body(Oimg, Woh, bo, resid, out, nullptr, 0, blockIdx.x, blockIdx.y);
}

// ---------------- launcher ----------------
extern "C" void kernel_launch(void* const* d_in, const int* in_sizes, int n_in,
                              void* d_out, int out_size, void* d_ws, size_t ws_size,
                              hipStream_t stream) {
  (void)in_sizes; (void)n_in; (void)out_size; (void)ws_size;
  const float* queries = (const float*)d_in[0];
  const float* keys    = (const float*)d_in[1];
  const float* values  = (const float*)d_in[2];
  const float* ln_q_g  = (const float*)d_in[3];
  const float* ln_q_b  = (const float*)d_in[4];
  const float* ln_k_g  = (const float*)d_in[5];
  const float* ln_k_b  = (const float*)d_in[6];
  const float* ln_v_g  = (const float*)d_in[7];
  const float* ln_v_b  = (const float*)d_in[8];
  const float* Wq = (const float*)d_in[9];  const float* bq = (const float*)d_in[10];
  const float* Wk = (const float*)d_in[11]; const float* bk = (const float*)d_in[12];
  const float* Wv = (const float*)d_in[13]; const float* bv = (const float*)d_in[14];
  const float* Wo = (const float*)d_in[15]; const float* bo = (const float*)d_in[16];
  const float* Ww1 = (const float*)d_in[17]; const float* bw1 = (const float*)d_in[18];
  const float* Ww2 = (const float*)d_in[19]; const float* bw2 = (const float*)d_in[20];

  char* ws = (char*)d_ws;
  const size_t MB = 1u << 20;
  float*  qn   = (float*)(ws + 0 * MB);          // 8 MB (front 4 MB reused as Oimg)
  ushort* qnh  = (ushort*)(ws + 8 * MB);         // 4 MB
  ushort* knh  = (ushort*)(ws + 12 * MB);        // 4 MB
  ushort* vnh  = (ushort*)(ws + 16 * MB);        // 4 MB
  ushort* Qimg = (ushort*)(ws + 20 * MB);        // 4 MB
  ushort* Kth  = (ushort*)(ws + 24 * MB);        // 4 MB
  ushort* Vt   = (ushort*)(ws + 28 * MB);        // 4 MB
  ushort* Wqh  = (ushort*)(ws + 32 * MB);        // 0.5 MB each
  ushort* Wkh  = (ushort*)(ws + 32 * MB + 524288);
  ushort* Wvh  = (ushort*)(ws + 33 * MB);
  ushort* Woh  = (ushort*)(ws + 33 * MB + 524288);
  u64*    bits = (u64*)(ws + 34 * MB);           // 1 MB
  uint32_t* tl = (uint32_t*)(ws + 35 * MB);      // 1 MB
  float*  hidden = (float*)(ws + 36 * MB);       // 2 MB
  char* st = ws + 38 * MB;
  float* dm     = (float*)st; st += NROWS * 4;
  float* mag    = (float*)st; st += NROWS * 4;
  float* ch     = (float*)st; st += NROWS * 4;
  float* rowvar = (float*)st; st += NROWS * 4;
  float* impn   = (float*)st; st += NROWS * 4;
  int*   win    = (int*)st;   st += NROWS * 4;
  uint8_t* kp   = (uint8_t*)st; st += NROWS;
  uint8_t* colm = (uint8_t*)st; st += NROWS;
  float* thr    = (float*)st; st += 2 * 4;
  float* comp   = (float*)st; st += 2 * 4;
  int* cnt      = (int*)st;   st += 2 * 4;
  int* haskp    = (int*)st;   st += 2 * 4;
  ushort* Oimg = (ushort*)qn;   // qn dead after mega1/mega2

  uint32_t kg0, kg1, kq0, kq1, kk0, kk1;
  tf2x32(0u, 42u, 0u, 0u, &kg0, &kg1);
  tf2x32(0u, 42u, 0u, 1u, &kq0, &kq1);
  tf2x32(0u, 42u, 0u, 2u, &kk0, &kk1);

  dim3 gln(NROWS, 3);
  ln3_kernel<<<gln, 256, 0, stream>>>(queries, keys, values,
                                      ln_q_g, ln_q_b, ln_k_g, ln_k_b, ln_v_g, ln_v_b,
                                      qn, qnh, knh, vnh);

  mega1_kernel<<<5121, 256, 0, stream>>>(qn, Ww1, bw1, hidden, dm, mag, ch, rowvar,
                                         Wq, Wk, Wv, Wo, Wqh, Wkh, Wvh, Woh,
                                         colm, cnt, haskp);

  mega2_kernel<<<4098, 256, 0, stream>>>(hidden, Ww2, bw2, win,
                                         dm, mag, ch, rowvar, impn, thr, comp);

  mega3_kernel<<<16, 512, 0, stream>>>(dm, thr, kp, haskp, impn, colm, kg0, kg1);

  mega4_kernel<<<768 + 4096, 256, 0, stream>>>(qnh, Wqh, bq, Qimg,
                                               knh, Wkh, bk, Kth,
                                               vnh, Wvh, bv, Vt,
                                               win, kp, colm, haskp, bits, cnt);

  fill_kernel<<<(2 * NRAND) / 256, 256, 0, stream>>>(bits, comp, cnt, kq0, kq1, kk0, kk1);

  tl_kernel<<<128, 256, 0, stream>>>(bits, tl);

  dim3 gat(SEQ / 32, 8, BATCH);
  attn_mfma<<<gat, 256, 0, stream>>>(Qimg, Kth, Vt, tl, Oimg);

  dim3 go(4, 64);
  oproj_kernel<<<go, 256, 0, stream>>>(Oimg, Woh, bo, queries, (float*)d_out);
}

// Round 8
// 303.428 us; speedup vs baseline: 4.1853x; 1.0126x over previous
//
#include <hip/hip_runtime.h>
#include <stdint.h>
#include <math.h>

#define DEVINL __device__ __forceinline__

constexpr int SEQ = 2048;
constexpr int DIM = 512;
constexpr int BATCH = 2;
constexpr int NROWS = BATCH * SEQ;        // 4096
constexpr int NRAND = (SEQ * SEQ) / 2;    // 2^21
constexpr float F32_TINY = 1.1754943508222875e-38f;

typedef float float4v __attribute__((ext_vector_type(4)));
typedef short short8 __attribute__((ext_vector_type(8)));
typedef unsigned long long u64;

DEVINL float4v MFMA(short8 a, short8 b, float4v c) {
  return __builtin_amdgcn_mfma_f32_16x16x32_bf16(a, b, c, 0, 0, 0);
}

DEVINL ushort f2bf(float x) {
  uint32_t u = __float_as_uint(x);
  return (ushort)((u + 0x7FFFu + ((u >> 16) & 1u)) >> 16);
}

// ---------------- threefry2x32 (JAX-compatible) ----------------
__host__ __device__ inline void tf2x32(uint32_t k0, uint32_t k1,
                                       uint32_t x0, uint32_t x1,
                                       uint32_t* o0, uint32_t* o1) {
  uint32_t ks2 = k0 ^ k1 ^ 0x1BD11BDAu;
  x0 += k0; x1 += k1;
#define TFR(r) { x0 += x1; x1 = (x1 << (r)) | (x1 >> (32 - (r))); x1 ^= x0; }
  TFR(13) TFR(15) TFR(26) TFR(6)
  x0 += k1; x1 += ks2 + 1u;
  TFR(17) TFR(29) TFR(16) TFR(24)
  x0 += ks2; x1 += k0 + 2u;
  TFR(13) TFR(15) TFR(26) TFR(6)
  x0 += k0; x1 += k1 + 3u;
  TFR(17) TFR(29) TFR(16) TFR(24)
  x0 += k1; x1 += ks2 + 4u;
  TFR(13) TFR(15) TFR(26) TFR(6)
  x0 += ks2; x1 += k0 + 5u;
#undef TFR
  *o0 = x0; *o1 = x1;
}

DEVINL uint32_t jax_bits32(uint32_t k0, uint32_t k1, uint32_t idx) {
  uint32_t a, b;
  tf2x32(k0, k1, 0u, idx, &a, &b);
  return a ^ b;
}

// ---------------- block reductions ----------------
DEVINL float blockReduceSum(float v) {
  __shared__ float sh[16];
  __syncthreads();
  int lane = threadIdx.x & 63, wid = threadIdx.x >> 6;
  #pragma unroll
  for (int o = 32; o > 0; o >>= 1) v += __shfl_down(v, o);
  if (lane == 0) sh[wid] = v;
  __syncthreads();
  if (threadIdx.x == 0) {
    int nw = ((int)blockDim.x + 63) >> 6;
    float s = 0.f;
    for (int i = 0; i < nw; i++) s += sh[i];
    sh[0] = s;
  }
  __syncthreads();
  return sh[0];
}

DEVINL float blockReduceMin(float v) {
  __shared__ float sh[16];
  __syncthreads();
  int lane = threadIdx.x & 63, wid = threadIdx.x >> 6;
  #pragma unroll
  for (int o = 32; o > 0; o >>= 1) v = fminf(v, __shfl_down(v, o));
  if (lane == 0) sh[wid] = v;
  __syncthreads();
  if (threadIdx.x == 0) {
    int nw = ((int)blockDim.x + 63) >> 6;
    float s = sh[0];
    for (int i = 1; i < nw; i++) s = fminf(s, sh[i]);
    sh[0] = s;
  }
  __syncthreads();
  return sh[0];
}

DEVINL float blockReduceMax(float v) {
  __shared__ float sh[16];
  __syncthreads();
  int lane = threadIdx.x & 63, wid = threadIdx.x >> 6;
  #pragma unroll
  for (int o = 32; o > 0; o >>= 1) v = fmaxf(v, __shfl_down(v, o));
  if (lane == 0) sh[wid] = v;
  __syncthreads();
  if (threadIdx.x == 0) {
    int nw = ((int)blockDim.x + 63) >> 6;
    float s = sh[0];
    for (int i = 1; i < nw; i++) s = fmaxf(s, sh[i]);
    sh[0] = s;
  }
  __syncthreads();
  return sh[0];
}

// A-image layout (GEMM A/W operand): chunk (row>>7, k>>5) of 4096 ushorts
DEVINL void store_img_scalar(ushort* img, int row, int d, float v) {
  size_t idx = ((size_t)((row >> 7) * 16 + (d >> 5))) * 4096
             + ((((row & 127) >> 4) * 4 + ((d >> 3) & 3)) * 16 + (row & 15)) * 8 + (d & 7);
  img[idx] = f2bf(v);
}

// ---------------- ln3: LayerNorm ×3 + bf16 image emit ----------------
__global__ __launch_bounds__(256) void ln3_kernel(
    const float* __restrict__ xq, const float* __restrict__ xk, const float* __restrict__ xv,
    const float* __restrict__ gq, const float* __restrict__ bq2,
    const float* __restrict__ gk, const float* __restrict__ bk2,
    const float* __restrict__ gv, const float* __restrict__ bv2,
    float* __restrict__ oq, ushort* __restrict__ iq, ushort* __restrict__ ik,
    ushort* __restrict__ iv) {
  const float *x, *g, *bb; ushort* img;
  if (blockIdx.y == 0)      { x = xq; g = gq; bb = bq2; img = iq; }
  else if (blockIdx.y == 1) { x = xk; g = gk; bb = bk2; img = ik; }
  else                      { x = xv; g = gv; bb = bv2; img = iv; }
  int row = blockIdx.x;
  const float* xr = x + (size_t)row * DIM;
  int t = threadIdx.x;
  float v0 = xr[t], v1 = xr[t + 256];
  float mu = blockReduceSum(v0 + v1) * (1.0f / 512.0f);
  float d0 = v0 - mu, d1 = v1 - mu;
  float var = blockReduceSum(d0 * d0 + d1 * d1) * (1.0f / 512.0f);
  float inv = 1.0f / sqrtf(var + 1e-5f);
  float r0 = d0 * inv * g[t] + bb[t];
  float r1 = d1 * inv * g[t + 256] + bb[t + 256];
  if (blockIdx.y == 0) {
    oq[(size_t)row * DIM + t] = r0;
    oq[(size_t)row * DIM + t + 256] = r1;
  }
  store_img_scalar(img, row, t, r0);
  store_img_scalar(img, row, t + 256, r1);
}

// ---------------- mask-critical f32 bodies (bit-exact, unchanged math) ----------------
DEVINL void gemm_f32_body(const float* __restrict__ A, const float* __restrict__ W,
                          const float* __restrict__ bias, float* __restrict__ C,
                          int bx, int by) {
  __shared__ float As[16][17];
  __shared__ float Ws[16][68];
  int bm = by * 16, bn = bx * 64;
  int tid = threadIdx.x;
  int tx = tid & 15, ty = tid >> 4;
  int lk = tid & 15, lm = tid >> 4;
  float acc[4] = {0.f, 0.f, 0.f, 0.f};
  for (int kk = 0; kk < DIM; kk += 16) {
    __syncthreads();
    As[lk][lm] = A[(size_t)(bm + lm) * DIM + kk + lk];
    #pragma unroll
    for (int i = 0; i < 4; i++)
      Ws[lk][lm + i * 16] = W[(size_t)(bn + lm + i * 16) * DIM + kk + lk];
    __syncthreads();
    #pragma unroll
    for (int k = 0; k < 16; k++) {
      float a = As[k][ty];
      float4 w4 = *(const float4*)&Ws[k][tx * 4];
      acc[0] += a * w4.x; acc[1] += a * w4.y;
      acc[2] += a * w4.z; acc[3] += a * w4.w;
    }
  }
  int m = bm + ty;
  #pragma unroll
  for (int j = 0; j < 4; j++) {
    int n = bn + tx * 4 + j;
    float v = acc[j] + bias[n];
    v = fmaxf(v, 0.f);
    C[(size_t)m * 128 + n] = v;
  }
}

DEVINL void dmstats_body(const float* __restrict__ qn, float* __restrict__ dm,
                         float* __restrict__ mag, float* __restrict__ ch,
                         float* __restrict__ rowvar, int t, int b) {
  const float* x = qn + ((size_t)b * SEQ + t) * DIM;
  int tid = threadIdx.x;
  float sx = 0, sq = 0, sdm = 0, sch = 0;
  float xs[2];
  #pragma unroll
  for (int i = 0; i < 2; i++) {
    int d = tid + i * 256;
    float xv = x[d]; xs[i] = xv;
    sx += xv; sq += xv * xv;
    float acc = 0.f;
    if (t + 1 < SEQ) { float df = fabsf(x[1 * DIM + d] - xv); acc += 0.4f * (df / 1.0f); sch += df; }
    if (t + 2 < SEQ) { float df = fabsf(x[2 * DIM + d] - xv); acc += 0.3f * (df / 2.0f); }
    if (t + 3 < SEQ) { float df = fabsf(x[3 * DIM + d] - xv); acc += 0.2f * (df / 3.0f); }
    if (t + 5 < SEQ) { float df = fabsf(x[5 * DIM + d] - xv); acc += 0.1f * (df / 5.0f); }
    sdm += acc;
  }
  float mu = blockReduceSum(sx) * (1.0f / 512.0f);
  float sv = 0;
  #pragma unroll
  for (int i = 0; i < 2; i++) { float dd = xs[i] - mu; sv += dd * dd; }
  float totsq = blockReduceSum(sq);
  float totdm = blockReduceSum(sdm);
  float totch = blockReduceSum(sch);
  float totsv = blockReduceSum(sv);
  if (tid == 0) {
    size_t idx = (size_t)b * SEQ + t;
    dm[idx] = totdm / 512.0f;
    mag[idx] = sqrtf(totsq);
    ch[idx] = (t + 1 < SEQ) ? (totch / 512.0f) : 0.f;
    rowvar[idx] = totsv / 511.0f;
  }
}

DEVINL void conv_w_hi(const float* __restrict__ src, ushort* __restrict__ dst, int gid) {
  int row = gid >> 6, c8 = gid & 63;
  const float* p = src + (size_t)row * 512 + c8 * 8;
  float4 v0 = ((const float4*)p)[0];
  float4 v1 = ((const float4*)p)[1];
  float xv[8] = {v0.x, v0.y, v0.z, v0.w, v1.x, v1.y, v1.z, v1.w};
  short8 hv;
  #pragma unroll
  for (int j = 0; j < 8; j++) hv[j] = (short)f2bf(xv[j]);
  int mb = row >> 7, rr = row & 127, kkc = c8 >> 2, qrr = c8 & 3;
  ((short8*)dst)[(mb * 16 + kkc) * 512 + ((rr >> 4) * 4 + qrr) * 16 + (rr & 15)] = hv;
}

// mega1: gemm_f32(512) | dmstats(4096) | weight conv(512) | init(1)
__global__ __launch_bounds__(256) void mega1_kernel(
    const float* qn, const float* Ww1, const float* bw1, float* hidden,
    float* dm, float* mag, float* ch, float* rowvar,
    const float* Wq, const float* Wk, const float* Wv, const float* Wo,
    ushort* Wqh, ushort* Wkh, ushort* Wvh, ushort* Woh,
    uint8_t* colm, int* cnt, int* haskp) {
  int bid = blockIdx.x;
  if (bid < 512) {
    gemm_f32_body(qn, Ww1, bw1, hidden, bid & 1, bid >> 1);
  } else if (bid < 4608) {
    int r = bid - 512;
    dmstats_body(qn, dm, mag, ch, rowvar, r & 2047, r >> 11);
  } else if (bid < 5120) {
    int r = bid - 4608;
    const float* s; ushort* d;
    switch (r >> 7) {
      case 0: s = Wq; d = Wqh; break;
      case 1: s = Wk; d = Wkh; break;
      case 2: s = Wv; d = Wvh; break;
      default: s = Wo; d = Woh; break;
    }
    conv_w_hi(s, d, (r & 127) * 256 + (int)threadIdx.x);
  } else {
    int tid = threadIdx.x;
    for (int i = tid; i < BATCH * SEQ; i += 256) colm[i] = 0;
    if (tid < BATCH) { cnt[tid] = 0; haskp[tid] = 0; }
  }
}

// mega2: win(4096, 256-thr zero-padded — bitwise-identical sum) | batchstats(2)
DEVINL void win_body(const float* __restrict__ hidden, const float* __restrict__ Ww2,
                     const float* __restrict__ bw2, int* __restrict__ win, int row) {
  int t = threadIdx.x;
  float v = (t < 128) ? hidden[(size_t)row * 128 + t] * Ww2[t] : 0.f;
  v = blockReduceSum(v);
  if (t == 0) {
    float y = v + bw2[0];
    float sig = 1.0f / (1.0f + expf(-y));
    float adj = 0.5f + sig;
    int w = (int)rintf(64.0f * adj);
    w = w < 1 ? 1 : (w > 128 ? 128 : w);
    win[row] = w;
  }
}

DEVINL void batchstats_body(const float* __restrict__ dm, const float* __restrict__ mag,
                            const float* __restrict__ ch, const float* __restrict__ rowvar,
                            float* __restrict__ impn, float* __restrict__ thr,
                            float* __restrict__ comp, int b) {
  int tid = threadIdx.x;
  float sdm = 0, srv = 0, lo = INFINITY, hi = -INFINITY;
  for (int t = tid; t < SEQ; t += 256) {
    size_t idx = (size_t)b * SEQ + t;
    sdm += dm[idx];
    srv += rowvar[idx];
    float imp = 0.5f * mag[idx] + 0.5f * ch[idx];
    lo = fminf(lo, imp); hi = fmaxf(hi, imp);
  }
  float meandm = blockReduceSum(sdm) * (1.0f / 2048.0f);
  float compv = blockReduceSum(srv) * (1.0f / 2048.0f);
  lo = blockReduceMin(lo);
  hi = blockReduceMax(hi);
  float sv = 0;
  for (int t = tid; t < SEQ; t += 256) {
    float d2 = dm[(size_t)b * SEQ + t] - meandm;
    sv += d2 * d2;
  }
  float var = blockReduceSum(sv) / 2047.0f;
  for (int t = tid; t < SEQ; t += 256) {
    size_t idx = (size_t)b * SEQ + t;
    float imp = 0.5f * mag[idx] + 0.5f * ch[idx];
    impn[idx] = (imp - lo) / (hi - lo + 1e-6f);
  }
  if (tid == 0) { thr[b] = meandm + 0.5f * sqrtf(var); comp[b] = compv; }
}

__global__ __launch_bounds__(256) void mega2_kernel(
    const float* hidden, const float* Ww2, const float* bw2, int* win,
    const float* dm, const float* mag, const float* ch, const float* rowvar,
    float* impn, float* thr, float* comp) {
  int bid = blockIdx.x;
  if (bid < 4096) win_body(hidden, Ww2, bw2, win, bid);
  else batchstats_body(dm, mag, ch, rowvar, impn, thr, comp, bid - 4096);
}

// mega3 (512 threads): kp(8) | topk(8)
__global__ __launch_bounds__(512) void mega3_kernel(
    const float* __restrict__ dm, const float* __restrict__ thr,
    uint8_t* __restrict__ kp, int* __restrict__ haskp,
    const float* __restrict__ impn, uint8_t* __restrict__ colm,
    uint32_t kg0, uint32_t kg1) {
  int bid = blockIdx.x;
  if (bid < 8) {
    int b = bid >> 2;
    int t = (bid & 3) * 512 + (int)threadIdx.x;
    const float* dmb = dm + (size_t)b * SEQ;
    float v = dmb[t];
    float tb = thr[b];
    float prev = (t > 0) ? dmb[t - 1] : -1.0f;
    float next = (t < SEQ - 1) ? dmb[t + 1] : -1.0f;
    bool k = (v > tb) && (v > prev) && (v > next);
    if (t == 0 || t == SEQ - 1) k = k || (v > tb);
    kp[(size_t)b * SEQ + t] = k ? 1 : 0;
    if (k) haskp[b] = 1;
  } else {
    int rowid = bid - 8;
    int b = rowid >> 2, layer = rowid & 3;
    int j = threadIdx.x;
    float pv = impn[(size_t)b * SEQ + layer * 512 + j];
    float ssum = blockReduceSum(pv);
    uint32_t bits2 = jax_bits32(kg0, kg1, (uint32_t)(rowid * 512 + j));
    float f = __uint_as_float((bits2 >> 9) | 0x3F800000u) - 1.0f;
    float u = fmaxf(F32_TINY, f + F32_TINY);
    float g = -logf(-logf(u));
    float score = logf(pv / (ssum + 1e-6f) + 1e-20f) + g;
    __shared__ float sc[512];
    sc[j] = score;
    __syncthreads();
    for (int pick = 0; pick < 4; pick++) {
      if (j < 64) {
        float bv = -INFINITY; int bi = 0;
        #pragma unroll
        for (int q = 0; q < 8; q++) {
          int idx = j + q * 64;
          float v = sc[idx];
          if (v > bv) { bv = v; bi = idx; }
        }
        #pragma unroll
        for (int o = 1; o < 64; o <<= 1) {
          float ov = __shfl_xor(bv, o);
          int oi = __shfl_xor(bi, o);
          if (ov > bv || (ov == bv && oi < bi)) { bv = ov; bi = oi; }
        }
        if (j == 0) {
          colm[(size_t)b * SEQ + layer * 512 + bi] = 1;
          sc[bi] = -INFINITY;
        }
      }
      __syncthreads();
    }
  }
}

DEVINL bool fbcol(int k) {
  return k == 0 || k == 511 || k == 1023 || k == 1535 || k == 2047;
}

// 16 q-rows per block -> 256 atomics total instead of 4096 (same bits, same count)
DEVINL void maskbuild_body16(const int* __restrict__ win, const uint8_t* __restrict__ kp,
                             const uint8_t* __restrict__ colm, const int* __restrict__ haskp,
                             u64* __restrict__ bits, int* __restrict__ cnt, int qg, int b) {
  int hk = haskp[b];
  const uint8_t* kpb = kp + (size_t)b * SEQ;
  const uint8_t* cob = colm + (size_t)b * SEQ;
  int tid = threadIdx.x, wave = tid >> 6, lane = tid & 63;
  int local = 0;
  for (int qq = 0; qq < 16; qq++) {
    int q = qg * 16 + qq;
    int w = win[(size_t)b * SEQ + q];
    bool rowk = hk ? (kpb[q] != 0) : fbcol(q);
    #pragma unroll
    for (int i = 0; i < 8; i++) {
      int k = i * 256 + tid;
      bool colk = hk ? (kpb[k] != 0) : fbcol(k);
      bool mmv = ((k >= q - w) && (k <= q + w)) || rowk || colk || (cob[k] != 0);
      u64 word = __ballot(mmv);
      if (lane == 0) bits[((size_t)b * 32 + (i * 4 + wave)) * 2048 + q] = word;
      local += mmv ? 1 : 0;
    }
  }
  float tot = blockReduceSum((float)local);
  if (tid == 0) atomicAdd(&cnt[b], (int)tot);
}

// ---------------- 64x128 plain-bf16 MFMA GEMM ----------------
// mode 0: f32 C (+resid); 1: K attn image; 2: V attn image (remapped keys); 3: Q image ×0.125
DEVINL void gemm64_body(const ushort* __restrict__ Ahg, const ushort* __restrict__ Whg,
                        const float* __restrict__ bias, const float* __restrict__ resid,
                        float* __restrict__ C, ushort* __restrict__ oImg,
                        int mode, int bx, int by) {
  __shared__ __align__(16) ushort Ah[2048], Wh[4096];
  int tid = threadIdx.x, wave = tid >> 6, lane = tid & 63;
  int mm = lane & 15, qr = lane >> 4;
  int wm = (wave >> 1) * 32, wn = (wave & 1) * 64;
  int bm = by * 64, bn = bx * 128;
  float4v acc[2][4] = {};
  for (int kk = 0; kk < 16; kk++) {
    __syncthreads();
    {
      const short8* ga = (const short8*)(Ahg + ((size_t)((bm >> 7) * 16 + kk)) * 4096
                                         + ((bm >> 6) & 1) * 2048);
      const short8* gw = (const short8*)(Whg + ((size_t)((bn >> 7) * 16 + kk)) * 4096);
      ((short8*)Ah)[tid] = ga[tid];
      ((short8*)Wh)[tid] = gw[tid];
      ((short8*)Wh)[tid + 256] = gw[tid + 256];
    }
    __syncthreads();
    short8 ah[2], bh[4];
    #pragma unroll
    for (int mt = 0; mt < 2; mt++)
      ah[mt] = ((short8*)Ah)[(((wm >> 4) + mt) * 4 + qr) * 16 + mm];
    #pragma unroll
    for (int nt = 0; nt < 4; nt++)
      bh[nt] = ((short8*)Wh)[(((wn >> 4) + nt) * 4 + qr) * 16 + mm];
    #pragma unroll
    for (int mt = 0; mt < 2; mt++)
      #pragma unroll
      for (int nt = 0; nt < 4; nt++)
        acc[mt][nt] = MFMA(ah[mt], bh[nt], acc[mt][nt]);
  }
  #pragma unroll
  for (int mt = 0; mt < 2; mt++)
    #pragma unroll
    for (int nt = 0; nt < 4; nt++) {
      int n = bn + wn + nt * 16 + mm;
      float bsv = bias[n];
      #pragma unroll
      for (int reg = 0; reg < 4; reg++) {
        int m = bm + wm + mt * 16 + qr * 4 + reg;
        float v = acc[mt][nt][reg] + bsv;
        if (mode == 0) {
          if (resid) v += resid[(size_t)m * 512 + n];
          C[(size_t)m * 512 + n] = v;
        } else if (mode == 1) {
          int b2 = m >> 11, sq = m & 2047, t = sq >> 6, r = sq & 63;
          int h2 = n >> 6, d = n & 63;
          size_t pos = ((size_t)((b2 * 8 + h2) * 32 + t)) * 4096
                     + ((((r >> 4) * 2 + (d >> 5)) * 4 + ((d >> 3) & 3)) * 16 + (r & 15)) * 8
                     + (d & 7);
          oImg[pos] = f2bf(v);
        } else if (mode == 2) {
          int b2 = m >> 11, sq = m & 2047, t = sq >> 6, kk2 = sq & 63;
          int h2 = n >> 6, d = n & 63;
          int pk = (kk2 & 15) * 4 + (kk2 >> 4);
          int kc2 = pk >> 5, qf = (pk >> 3) & 3, j = pk & 7, dt = d >> 4;
          size_t pos = ((size_t)((b2 * 8 + h2) * 32 + t)) * 4096
                     + (((kc2 * 4 + dt) * 4 + qf) * 16 + (d & 15)) * 8 + j;
          oImg[pos] = f2bf(v);
        } else {
          int b2 = m >> 11, q = m & 2047, qt = q >> 5, mt2 = (q >> 4) & 1, mmr = q & 15;
          int h2 = n >> 6, d = n & 63, dc = d >> 5, qr2 = (d >> 3) & 3, j = d & 7;
          size_t pos = ((size_t)((b2 * 8 + h2) * 64 + qt)) * 2048
                     + (((mt2 * 2 + dc) * 4 + qr2) * 16 + mmr) * 8 + j;
          oImg[pos] = f2bf(v * 0.125f);
        }
      }
    }
}

// mega4: QKV projections (768) | maskbuild (256, 16 rows each)
__global__ __launch_bounds__(256) void mega4_kernel(
    const ushort* qnh, const ushort* Wqh, const float* bq, ushort* Qimg,
    const ushort* knh, const ushort* Wkh, const float* bk, ushort* Kth,
    const ushort* vnh, const ushort* Wvh, const float* bv, ushort* Vt,
    const int* win, const uint8_t* kp, const uint8_t* colm, const int* haskp,
    u64* bits, int* cnt) {
  int bid = blockIdx.x;
  if (bid < 768) {
    int op = bid >> 8, r = bid & 255;
    int bx = r & 3, by = r >> 2;
    if (op == 0)      gemm64_body(qnh, Wqh, bq, nullptr, nullptr, Qimg, 3, bx, by);
    else if (op == 1) gemm64_body(knh, Wkh, bk, nullptr, nullptr, Kth, 1, bx, by);
    else              gemm64_body(vnh, Wvh, bv, nullptr, nullptr, Vt, 2, bx, by);
  } else {
    int r = bid - 768;          // 0..255 = b*128 + qg
    maskbuild_body16(win, kp, colm, haskp, bits, cnt, r & 127, r >> 7);
  }
}

// fill (needed computed inline, bit-identical float ops)
__global__ void fill_kernel(u64* __restrict__ bits, const float* __restrict__ comp,
                            const int* __restrict__ cnt,
                            uint32_t kq0, uint32_t kq1, uint32_t kk0, uint32_t kk1) {
  int gid = blockIdx.x * blockDim.x + threadIdx.x;
  int b = gid >> 21;
  int r = gid & (NRAND - 1);
  if (b >= BATCH) return;
  float c0 = comp[0], c1 = comp[1];
  float cmin = fminf(c0, c1), cmax = fmaxf(c0, c1);
  float compb = b ? c1 : c0;
  float nc = (compb - cmin) / (cmax - cmin + 1e-6f);
  float ratio = fminf(fmaxf(0.3f * (0.5f + nc), 0.1f), 0.5f);
  float dens = (float)cnt[b] / 4194304.0f;
  float nd = ceilf((ratio - dens) * 4194304.0f);
  int needed = (int)nd;
  if (needed < 0) needed = 0;
  if (r >= needed) return;
  uint32_t flat = 4194304u + (uint32_t)gid;
  uint32_t q = jax_bits32(kq0, kq1, flat) & 2047u;
  uint32_t k = jax_bits32(kk0, kk1, flat) & 2047u;
  atomicOr(&bits[((size_t)b * 32 + (k >> 6)) * 2048 + q], 1ull << (k & 63));
}

// per-lane u32 mask image: tl[((b*64+qt)*32+kc)*64 + lane], bit w=(mt*4+reg)*4+ct
// = sparse(row = qt*32+mt*16+(lane>>4)*4+reg, key = kc*64+ct*16+(lane&15))
__global__ __launch_bounds__(256) void tl_kernel(const u64* __restrict__ bits,
                                                 uint32_t* __restrict__ tl) {
  int bid = blockIdx.x;            // 0..127 = b*64+qt
  int b = bid >> 6, qt = bid & 63;
  int tid = threadIdx.x;
  __shared__ u64 W[32][32];        // [kc][row-local]
  #pragma unroll
  for (int i = 0; i < 4; i++) {
    int idx = i * 256 + tid;
    int kc = idx >> 5, r = idx & 31;
    W[kc][r] = bits[((size_t)(b * 32 + kc)) * 2048 + qt * 32 + r];
  }
  __syncthreads();
  #pragma unroll
  for (int oi = 0; oi < 8; oi++) {
    int o = oi * 256 + tid;
    int kc = o >> 6, lane = o & 63;
    int qr = lane >> 4, mm = lane & 15;
    uint32_t acc = 0;
    #pragma unroll
    for (int mt = 0; mt < 2; mt++)
      #pragma unroll
      for (int reg = 0; reg < 4; reg++) {
        u64 wv = W[kc][mt * 16 + qr * 4 + reg];
        uint32_t lo = (uint32_t)wv, hi = (uint32_t)(wv >> 32);
        int base = (mt * 4 + reg) * 4;
        acc |= ((lo >> mm) & 1u) << base;
        acc |= ((lo >> (16 + mm)) & 1u) << (base + 1);
        acc |= ((hi >> mm) & 1u) << (base + 2);
        acc |= ((hi >> (16 + mm)) & 1u) << (base + 3);
      }
    tl[((size_t)(b * 64 + qt) * 32 + kc) * 64 + lane] = acc;
  }
}

// ---------------- barrier-free MFMA flash attention (v5, XCD-swizzled) ----------------
// 1-D grid of 1024; round-robin workgroup->XCD assumed (perf heuristic only):
// xcd = L&7 serves exactly 2 (b,h) pairs -> K/V working set 1 MB, fits 4 MB L2.
__global__ __launch_bounds__(256, 4) void attn_mfma(
    const ushort* __restrict__ Qimg, const ushort* __restrict__ Khig,
    const ushort* __restrict__ Vimg, const uint32_t* __restrict__ tl,
    ushort* __restrict__ Oimg) {
  int L = blockIdx.x;
  int xcd = L & 7, j = L >> 3;
  int bh = xcd * 2 + (j >> 6);
  int qt = j & 63;
  int b = bh >> 3, h = bh & 7;
  __shared__ __align__(16) char arena[34 * 1024];
  float* LO = (float*)arena;                       // [4*32][64] merge
  float* Lm = (float*)(arena + 32768);             // [4*32]
  float* Ll = (float*)(arena + 32768 + 512);       // [4*32]
  int tid = threadIdx.x;
  int wave = __builtin_amdgcn_readfirstlane(tid >> 6);
  int lane = tid & 63;
  int mm = lane & 15, qr = lane >> 4;
  int q0 = qt * 32;
  ushort* pw = (ushort*)arena + wave * 2048;       // wave-private P (4 KB)

  short8 aq[2][2];
  {
    const short8* qp = (const short8*)(Qimg + ((size_t)((b * 8 + h) * 64 + qt)) * 2048);
    #pragma unroll
    for (int mt = 0; mt < 2; mt++)
      #pragma unroll
      for (int dc = 0; dc < 2; dc++)
        aq[mt][dc] = qp[((mt * 2 + dc) * 4 + qr) * 16 + mm];
  }
  float4v accO[2][4] = {};
  float4v accL2[2] = {};
  float m_i[2][4];
  #pragma unroll
  for (int mt = 0; mt < 2; mt++)
    #pragma unroll
    for (int r = 0; r < 4; r++) m_i[mt][r] = -INFINITY;
  size_t kvbase = ((size_t)((b * 8 + h) * 32)) * 4096;
  const uint32_t* tlb = tl + ((size_t)(b * 64 + qt)) * 32 * 64 + lane;
  const short8 ones8 = {16256, 16256, 16256, 16256, 16256, 16256, 16256, 16256};

  #pragma unroll 2
  for (int it = 0; it < 8; it++) {
    int kc = it * 4 + wave;
    const short8* kh = (const short8*)(Khig + kvbase + (size_t)kc * 4096);
    const short8* vv = (const short8*)(Vimg + kvbase + (size_t)kc * 4096);
    uint32_t mw = tlb[(size_t)kc * 64];
    // QK^T, single bf16 (scale pre-folded into Q image)
    float4v S[2][4];
    #pragma unroll
    for (int ct = 0; ct < 4; ct++) {
      short8 k0 = kh[((ct * 2 + 0) * 4 + qr) * 16 + mm];
      short8 k1 = kh[((ct * 2 + 1) * 4 + qr) * 16 + mm];
      #pragma unroll
      for (int mt = 0; mt < 2; mt++) {
        float4v s = {};
        s = MFMA(aq[mt][0], k0, s);
        s = MFMA(aq[mt][1], k1, s);
        S[mt][ct] = s;
      }
    }
    // online-max masked softmax; P packed to wave-private LDS
    #pragma unroll
    for (int mt = 0; mt < 2; mt++) {
      #pragma unroll
      for (int reg = 0; reg < 4; reg++) {
        int base = (mt * 4 + reg) * 4;
        float s[4];
        #pragma unroll
        for (int ct = 0; ct < 4; ct++) {
          float bitf = (float)((mw >> (base + ct)) & 1u);
          s[ct] = fmaf(bitf, -1e30f, S[mt][ct][reg]);
        }
        float mx = fmaxf(fmaxf(s[0], s[1]), fmaxf(s[2], s[3]));
        #pragma unroll
        for (int o = 1; o < 16; o <<= 1) mx = fmaxf(mx, __shfl_xor(mx, o));
        float mn = fmaxf(m_i[mt][reg], mx);
        float alpha = __expf(m_i[mt][reg] - mn);
        m_i[mt][reg] = mn;
        float p[4];
        #pragma unroll
        for (int ct = 0; ct < 4; ct++) p[ct] = __expf(s[ct] - mn);
        #pragma unroll
        for (int dt = 0; dt < 4; dt++) accO[mt][dt][reg] *= alpha;
        accL2[mt][reg] *= alpha;
        uint32_t lo32 = __builtin_amdgcn_perm(__float_as_uint(p[1]), __float_as_uint(p[0]), 0x07060302u);
        uint32_t hi32 = __builtin_amdgcn_perm(__float_as_uint(p[3]), __float_as_uint(p[2]), 0x07060302u);
        int r = qr * 4 + reg;
        int cp = (mm >> 1) ^ (r & 7);
        *(u64*)(pw + mt * 1024 + r * 64 + cp * 8 + (mm & 1) * 4) = ((u64)hi32 << 32) | lo32;
      }
    }
    // PV + ones-column (row-sum l for free)
    #pragma unroll
    for (int mt = 0; mt < 2; mt++)
      #pragma unroll
      for (int kc2 = 0; kc2 < 2; kc2++) {
        int cp = (kc2 * 4 + qr) ^ (mm & 7);
        short8 ap = *(const short8*)(pw + mt * 1024 + mm * 64 + cp * 8);
        #pragma unroll
        for (int dt = 0; dt < 4; dt++) {
          short8 bvf = vv[((kc2 * 4 + dt) * 4 + qr) * 16 + mm];
          accO[mt][dt] = MFMA(ap, bvf, accO[mt][dt]);
        }
        accL2[mt] = MFMA(ap, ones8, accL2[mt]);
      }
  }
  // exact flash merge across the 4 waves
  __syncthreads();
  #pragma unroll
  for (int mt = 0; mt < 2; mt++)
    #pragma unroll
    for (int reg = 0; reg < 4; reg++) {
      int r = mt * 16 + qr * 4 + reg;
      if (mm == 0) {
        Lm[wave * 32 + r] = m_i[mt][reg];
        Ll[wave * 32 + r] = accL2[mt][reg];
      }
      #pragma unroll
      for (int dt = 0; dt < 4; dt++)
        LO[(size_t)(wave * 32 + r) * 64 + dt * 16 + mm] = accO[mt][dt][reg];
    }
  __syncthreads();
  int row = tid >> 3, c0 = (tid & 7) * 8;
  float M = Lm[row];
  #pragma unroll
  for (int w = 1; w < 4; w++) M = fmaxf(M, Lm[w * 32 + row]);
  float fw[4], l = 0.f;
  #pragma unroll
  for (int w = 0; w < 4; w++) {
    fw[w] = __expf(Lm[w * 32 + row] - M);
    l += fw[w] * Ll[w * 32 + row];
  }
  float o[8] = {};
  #pragma unroll
  for (int w = 0; w < 4; w++) {
    const float* lob = LO + (size_t)(w * 32 + row) * 64 + c0;
    #pragma unroll
    for (int c = 0; c < 8; c++) o[c] += fw[w] * lob[c];
  }
  float invl = 1.0f / l;
  short8 o8;
  #pragma unroll
  for (int c = 0; c < 8; c++) o8[c] = (short)f2bf(o[c] * invl);
  int rowg = b * SEQ + q0 + row;
  int col = h * 64 + c0;
  int mb = rowg >> 7, rr = rowg & 127, kkc = col >> 5, qrk = (col >> 3) & 3;
  *(short8*)(Oimg + ((size_t)(mb * 16 + kkc)) * 4096
             + (((rr >> 4) * 4 + qrk) * 16 + (rr & 15)) * 8) = o8;
}

__global__ __launch_bounds__(256) void oproj_kernel(
    const ushort* __restrict__ Oimg, const ushort* __restrict__ Woh,
    const float* __restrict__ bo, const float* __restrict__ resid,
    float* __restrict__ out) {
  gemm64_body(Oimg, Woh, bo, resid, out, nullptr, 0, blockIdx.x, blockIdx.y);
}

// ---------------- launcher ----------------
extern "C" void kernel_launch(void* const* d_in, const int* in_sizes, int n_in,
                              void* d_out, int out_size, void* d_ws, size_t ws_size,
                              hipStream_t stream) {
  (void)in_sizes; (void)n_in; (void)out_size; (void)ws_size;
  const float* queries = (const float*)d_in[0];
  const float* keys    = (const float*)d_in[1];
  const float* values  = (const float*)d_in[2];
  const float* ln_q_g  = (const float*)d_in[3];
  const float* ln_q_b  = (const float*)d_in[4];
  const float* ln_k_g  = (const float*)d_in[5];
  const float* ln_k_b  = (const float*)d_in[6];
  const float* ln_v_g  = (const float*)d_in[7];
  const float* ln_v_b  = (const float*)d_in[8];
  const float* Wq = (const float*)d_in[9];  const float* bq = (const float*)d_in[10];
  const float* Wk = (const float*)d_in[11]; const float* bk = (const float*)d_in[12];
  const float* Wv = (const float*)d_in[13]; const float* bv = (const float*)d_in[14];
  const float* Wo = (const float*)d_in[15]; const float* bo = (const float*)d_in[16];
  const float* Ww1 = (const float*)d_in[17]; const float* bw1 = (const float*)d_in[18];
  const float* Ww2 = (const float*)d_in[19]; const float* bw2 = (const float*)d_in[20];

  char* ws = (char*)d_ws;
  const size_t MB = 1u << 20;
  float*  qn   = (float*)(ws + 0 * MB);          // 8 MB (front 4 MB reused as Oimg)
  ushort* qnh  = (ushort*)(ws + 8 * MB);         // 4 MB
  ushort* knh  = (ushort*)(ws + 12 * MB);        // 4 MB
  ushort* vnh  = (ushort*)(ws + 16 * MB);        // 4 MB
  ushort* Qimg = (ushort*)(ws + 20 * MB);        // 4 MB
  ushort* Kth  = (ushort*)(ws + 24 * MB);        // 4 MB
  ushort* Vt   = (ushort*)(ws + 28 * MB);        // 4 MB
  ushort* Wqh  = (ushort*)(ws + 32 * MB);        // 0.5 MB each
  ushort* Wkh  = (ushort*)(ws + 32 * MB + 524288);
  ushort* Wvh  = (ushort*)(ws + 33 * MB);
  ushort* Woh  = (ushort*)(ws + 33 * MB + 524288);
  u64*    bits = (u64*)(ws + 34 * MB);           // 1 MB
  uint32_t* tl = (uint32_t*)(ws + 35 * MB);      // 1 MB
  float*  hidden = (float*)(ws + 36 * MB);       // 2 MB
  char* st = ws + 38 * MB;
  float* dm     = (float*)st; st += NROWS * 4;
  float* mag    = (float*)st; st += NROWS * 4;
  float* ch     = (float*)st; st += NROWS * 4;
  float* rowvar = (float*)st; st += NROWS * 4;
  float* impn   = (float*)st; st += NROWS * 4;
  int*   win    = (int*)st;   st += NROWS * 4;
  uint8_t* kp   = (uint8_t*)st; st += NROWS;
  uint8_t* colm = (uint8_t*)st; st += NROWS;
  float* thr    = (float*)st; st += 2 * 4;
  float* comp   = (float*)st; st += 2 * 4;
  int* cnt      = (int*)st;   st += 2 * 4;
  int* haskp    = (int*)st;   st += 2 * 4;
  ushort* Oimg = (ushort*)qn;   // qn dead after mega1/mega2

  uint32_t kg0, kg1, kq0, kq1, kk0, kk1;
  tf2x32(0u, 42u, 0u, 0u, &kg0, &kg1);
  tf2x32(0u, 42u, 0u, 1u, &kq0, &kq1);
  tf2x32(0u, 42u, 0u, 2u, &kk0, &kk1);

  dim3 gln(NROWS, 3);
  ln3_kernel<<<gln, 256, 0, stream>>>(queries, keys, values,
                                      ln_q_g, ln_q_b, ln_k_g, ln_k_b, ln_v_g, ln_v_b,
                                      qn, qnh, knh, vnh);

  mega1_kernel<<<5121, 256, 0, stream>>>(qn, Ww1, bw1, hidden, dm, mag, ch, rowvar,
                                         Wq, Wk, Wv, Wo, Wqh, Wkh, Wvh, Woh,
                                         colm, cnt, haskp);

  mega2_kernel<<<4098, 256, 0, stream>>>(hidden, Ww2, bw2, win,
                                         dm, mag, ch, rowvar, impn, thr, comp);

  mega3_kernel<<<16, 512, 0, stream>>>(dm, thr, kp, haskp, impn, colm, kg0, kg1);

  mega4_kernel<<<768 + 256, 256, 0, stream>>>(qnh, Wqh, bq, Qimg,
                                              knh, Wkh, bk, Kth,
                                              vnh, Wvh, bv, Vt,
                                              win, kp, colm, haskp, bits, cnt);

  fill_kernel<<<(2 * NRAND) / 256, 256, 0, stream>>>(bits, comp, cnt, kq0, kq1, kk0, kk1);

  tl_kernel<<<128, 256, 0, stream>>>(bits, tl);

  attn_mfma<<<1024, 256, 0, stream>>>(Qimg, Kth, Vt, tl, Oimg);

  dim3 go(4, 64);
  oproj_kernel<<<go, 256, 0, stream>>>(Oimg, Woh, bo, queries, (float*)d_out);
}